// Round 1
// baseline (74795.276 us; speedup 1.0000x reference)
//
#include <hip/hip_runtime.h>

#define BM 64
#define BN 64
#define BK 16

// ---------------- fp32 tiled GEMM: C[N,Co] = A[N,K] @ B[K,Co] (+bias) ----------------
// block = 256 threads (16x16), each thread computes 4x4 outputs.
__global__ __launch_bounds__(256) void gemm_tile_kernel(
    const float* __restrict__ A, const float* __restrict__ B,
    const float* __restrict__ bias, float* __restrict__ C,
    int N, int K, int Co, int flags /* bit0: add bias */)
{
    __shared__ float As[BK][BM + 1];
    __shared__ float Bs[BK][BN + 1];
    const int tid = threadIdx.x;
    const int tx = tid & 15;
    const int ty = tid >> 4;
    const int block_n = blockIdx.x * BN;
    const int block_m = blockIdx.y * BM;

    float acc[4][4];
#pragma unroll
    for (int m = 0; m < 4; ++m)
#pragma unroll
        for (int n = 0; n < 4; ++n) acc[m][n] = 0.f;

    const int ar = tid >> 2;         // 0..63 (row within A tile)
    const int ak = (tid & 3) << 2;   // 0,4,8,12
    const int bk = tid >> 4;         // 0..15 (k within B tile)
    const int bc_ = (tid & 15) << 2; // 0..60

    for (int k0 = 0; k0 < K; k0 += BK) {
        // ---- load A tile (64 rows x 16 k), transposed into LDS ----
        {
            float4 v = make_float4(0.f, 0.f, 0.f, 0.f);
            int grow = block_m + ar;
            int gk = k0 + ak;
            if (grow < N) {
                if (gk + 3 < K) {
                    v = *reinterpret_cast<const float4*>(A + (size_t)grow * K + gk);
                } else {
                    float t0 = (gk + 0 < K) ? A[(size_t)grow * K + gk + 0] : 0.f;
                    float t1 = (gk + 1 < K) ? A[(size_t)grow * K + gk + 1] : 0.f;
                    float t2 = (gk + 2 < K) ? A[(size_t)grow * K + gk + 2] : 0.f;
                    float t3 = (gk + 3 < K) ? A[(size_t)grow * K + gk + 3] : 0.f;
                    v = make_float4(t0, t1, t2, t3);
                }
            }
            As[ak + 0][ar] = v.x;
            As[ak + 1][ar] = v.y;
            As[ak + 2][ar] = v.z;
            As[ak + 3][ar] = v.w;
        }
        // ---- load B tile (16 k x 64 cols) ----
        {
            float4 v = make_float4(0.f, 0.f, 0.f, 0.f);
            int gk = k0 + bk;
            if (gk < K) v = *reinterpret_cast<const float4*>(B + (size_t)gk * Co + block_n + bc_);
            Bs[bk][bc_ + 0] = v.x;
            Bs[bk][bc_ + 1] = v.y;
            Bs[bk][bc_ + 2] = v.z;
            Bs[bk][bc_ + 3] = v.w;
        }
        __syncthreads();

#pragma unroll
        for (int kk = 0; kk < BK; ++kk) {
            float a[4], b[4];
#pragma unroll
            for (int m = 0; m < 4; ++m) a[m] = As[kk][ty * 4 + m];
#pragma unroll
            for (int n = 0; n < 4; ++n) b[n] = Bs[kk][tx * 4 + n];
#pragma unroll
            for (int m = 0; m < 4; ++m)
#pragma unroll
                for (int n = 0; n < 4; ++n) acc[m][n] = fmaf(a[m], b[n], acc[m][n]);
        }
        __syncthreads();
    }

#pragma unroll
    for (int m = 0; m < 4; ++m) {
        int gr = block_m + ty * 4 + m;
        if (gr >= N) continue;
#pragma unroll
        for (int n = 0; n < 4; ++n) {
            int gcol = block_n + tx * 4 + n;
            float v = acc[m][n];
            if (flags & 1) v += bias[gcol];
            C[(size_t)gr * Co + gcol] = v;
        }
    }
}

// ---------------- SpMM: agg[dst] += w * support[src], one wave per edge ----------------
__global__ __launch_bounds__(256) void spmm_edge_kernel(
    const int* __restrict__ esrc, const int* __restrict__ edst,
    const float* __restrict__ ew, const float* __restrict__ support,
    float* __restrict__ agg, int n_edges)
{
    const int lane = threadIdx.x & 63;
    const int wave = threadIdx.x >> 6;
    const int waves_per_block = blockDim.x >> 6;
    long long e = (long long)blockIdx.x * waves_per_block + wave;
    const long long stride = (long long)gridDim.x * waves_per_block;
    for (; e < n_edges; e += stride) {
        int s = esrc[e];
        int d = edst[e];
        float w = ew[e];
        float4 v = *reinterpret_cast<const float4*>(support + (size_t)s * 256 + lane * 4);
        float* ap = agg + (size_t)d * 256 + lane * 4;
        atomicAdd(ap + 0, w * v.x);
        atomicAdd(ap + 1, w * v.y);
        atomicAdd(ap + 2, w * v.z);
        atomicAdd(ap + 3, w * v.w);
    }
}

// ---------------- BN stats: per-channel sum and sum of squares ----------------
__global__ __launch_bounds__(256) void bn_stats_kernel(
    const float* __restrict__ X, float* __restrict__ sums, int N)
{
    const int c = threadIdx.x; // 0..255
    float s = 0.f, s2 = 0.f;
    for (int i = blockIdx.x; i < N; i += gridDim.x) {
        float v = X[(size_t)i * 256 + c];
        s += v;
        s2 = fmaf(v, v, s2);
    }
    atomicAdd(&sums[c], s);
    atomicAdd(&sums[256 + c], s2);
}

__global__ __launch_bounds__(256) void bn_finalize_kernel(
    const float* __restrict__ sums, const float* __restrict__ g,
    const float* __restrict__ be, float* __restrict__ kp, int N)
{
    const int c = threadIdx.x;
    float invN = 1.f / (float)N;
    float mean = sums[c] * invN;
    float var = sums[256 + c] * invN - mean * mean;
    float inv = rsqrtf(var + 1e-5f);
    float sc = g[c] * inv;
    kp[c] = sc;
    kp[256 + c] = be[c] - sc * mean;
}

// ---------------- BN apply + ReLU, in place, float4 ----------------
__global__ __launch_bounds__(256) void bn_apply_kernel(
    float* __restrict__ X, const float* __restrict__ kp, long long n4)
{
    long long idx = (long long)blockIdx.x * blockDim.x + threadIdx.x;
    const long long stride = (long long)gridDim.x * blockDim.x;
    for (; idx < n4; idx += stride) {
        int c4 = (int)(idx & 63); // which float4 within the 256-wide row
        float4 v = reinterpret_cast<float4*>(X)[idx];
        float4 s = reinterpret_cast<const float4*>(kp)[c4];
        float4 t = reinterpret_cast<const float4*>(kp + 256)[c4];
        v.x = fmaxf(fmaf(v.x, s.x, t.x), 0.f);
        v.y = fmaxf(fmaf(v.y, s.y, t.y), 0.f);
        v.z = fmaxf(fmaf(v.z, s.z, t.z), 0.f);
        v.w = fmaxf(fmaf(v.w, s.w, t.w), 0.f);
        reinterpret_cast<float4*>(X)[idx] = v;
    }
}

// ---------------- output projection: out[N,40] (+)= A[N,K] @ Wc[K,40] (+ bc) ----------------
__global__ __launch_bounds__(256) void outproj_kernel(
    const float* __restrict__ A, int K, const float* __restrict__ Wc,
    const float* __restrict__ bc, float* __restrict__ out, int N,
    int flags /* 1: overwrite + bias; 2: accumulate */)
{
    long long idx = (long long)blockIdx.x * blockDim.x + threadIdx.x;
    const long long total = (long long)N * 40;
    const long long stride = (long long)gridDim.x * blockDim.x;
    for (; idx < total; idx += stride) {
        int i = (int)(idx / 40);
        int j = (int)(idx - (long long)i * 40);
        const float* a = A + (size_t)i * K;
        float acc = 0.f;
        for (int k = 0; k < K; ++k) acc = fmaf(a[k], Wc[(size_t)k * 40 + j], acc);
        if (flags & 1) acc += bc[j];
        if (flags & 2) acc += out[idx];
        out[idx] = acc;
    }
}

// ---------------- host-side orchestration ----------------
static void run_gc(const float* h, int K,
                   const float* W, const float* SW, const float* b,
                   const float* g, const float* be,
                   const int* esrc, const int* edst, const float* ew, int n_edges,
                   float* support, float* hout, float* stats,
                   int N, hipStream_t stream)
{
    dim3 gblock(256);
    dim3 ggrid(256 / BN, (N + BM - 1) / BM);
    // support = h @ W
    hipLaunchKernelGGL(gemm_tile_kernel, ggrid, gblock, 0, stream,
                       h, W, nullptr, support, N, K, 256, 0);
    // hout = h @ SW + b
    hipLaunchKernelGGL(gemm_tile_kernel, ggrid, gblock, 0, stream,
                       h, SW, b, hout, N, K, 256, 1);
    // hout += scatter-add of w * support[src] into dst rows
    hipLaunchKernelGGL(spmm_edge_kernel, dim3(8192), dim3(256), 0, stream,
                       esrc, edst, ew, support, hout, n_edges);
    // BN stats
    hipMemsetAsync(stats, 0, 512 * sizeof(float), stream);
    hipLaunchKernelGGL(bn_stats_kernel, dim3(1024), dim3(256), 0, stream, hout, stats, N);
    hipLaunchKernelGGL(bn_finalize_kernel, dim3(1), dim3(256), 0, stream, stats, g, be, stats + 512, N);
    // normalize + relu in place
    hipLaunchKernelGGL(bn_apply_kernel, dim3(2048), dim3(256), 0, stream,
                       hout, stats + 512, (long long)N * 64);
}

extern "C" void kernel_launch(void* const* d_in, const int* in_sizes, int n_in,
                              void* d_out, int out_size, void* d_ws, size_t ws_size,
                              hipStream_t stream)
{
    const float* x      = (const float*)d_in[0];
    const int*   esrc   = (const int*)d_in[1];
    const int*   edst   = (const int*)d_in[2];
    const float* ew     = (const float*)d_in[3];
    const float* W_in   = (const float*)d_in[4];   // [3,500,256]
    const float* SW_in  = (const float*)d_in[5];   // [3,500,256]
    const float* b_in   = (const float*)d_in[6];   // [3,256]
    const float* g_in   = (const float*)d_in[7];
    const float* be_in  = (const float*)d_in[8];
    const float* W_h    = (const float*)d_in[9];   // [3,256,256]
    const float* SW_h   = (const float*)d_in[10];
    const float* b_h    = (const float*)d_in[11];
    const float* g_h    = (const float*)d_in[12];
    const float* be_h   = (const float*)d_in[13];
    const float* Wc     = (const float*)d_in[14];  // [1268,40]
    const float* bc     = (const float*)d_in[15];  // [40]
    float* out = (float*)d_out;

    const int IN_F = 500;
    const int N = in_sizes[0] / IN_F;     // 100000
    const int n_edges = in_sizes[1];      // 3200000

    const size_t NH = (size_t)N * 256;
    float* S     = (float*)d_ws;          // support buffer
    float* H1    = S + NH;
    float* H2    = H1 + NH;
    float* stats = H2 + NH;               // 1024 floats (sums 512 + kscale/kshift 512)

    dim3 oblock(256);
    dim3 ogrid(8192);

    // out = x @ Wc[0:500] + bc
    hipLaunchKernelGGL(outproj_kernel, ogrid, oblock, 0, stream,
                       x, IN_F, Wc, bc, out, N, 1);

    // ---- j = 0: one input GC ----
    run_gc(x, IN_F, W_in, SW_in, b_in, g_in, be_in,
           esrc, edst, ew, n_edges, S, H1, stats, N, stream);
    hipLaunchKernelGGL(outproj_kernel, ogrid, oblock, 0, stream,
                       H1, 256, Wc + (size_t)500 * 40, nullptr, out, N, 2);

    // ---- j = 1: input GC + 1 hidden GC (W_h[0]) ----
    run_gc(x, IN_F, W_in + 1 * 500 * 256, SW_in + 1 * 500 * 256, b_in + 256, g_in + 256, be_in + 256,
           esrc, edst, ew, n_edges, S, H1, stats, N, stream);
    run_gc(H1, 256, W_h, SW_h, b_h, g_h, be_h,
           esrc, edst, ew, n_edges, S, H2, stats, N, stream);
    hipLaunchKernelGGL(outproj_kernel, ogrid, oblock, 0, stream,
                       H2, 256, Wc + (size_t)756 * 40, nullptr, out, N, 2);

    // ---- j = 2: input GC + 2 hidden GCs (W_h[1], W_h[2]) ----
    run_gc(x, IN_F, W_in + 2 * 500 * 256, SW_in + 2 * 500 * 256, b_in + 512, g_in + 512, be_in + 512,
           esrc, edst, ew, n_edges, S, H1, stats, N, stream);
    run_gc(H1, 256, W_h + 1 * 256 * 256, SW_h + 1 * 256 * 256, b_h + 256, g_h + 256, be_h + 256,
           esrc, edst, ew, n_edges, S, H2, stats, N, stream);
    run_gc(H2, 256, W_h + 2 * 256 * 256, SW_h + 2 * 256 * 256, b_h + 512, g_h + 512, be_h + 512,
           esrc, edst, ew, n_edges, S, H1, stats, N, stream);
    hipLaunchKernelGGL(outproj_kernel, ogrid, oblock, 0, stream,
                       H1, 256, Wc + (size_t)1012 * 40, nullptr, out, N, 2);
}

// Round 2
// 10999.561 us; speedup vs baseline: 6.7998x; 6.7998x over previous
//
#include <hip/hip_runtime.h>

#define BM 64
#define BN 64
#define BK 16

// ---------------- fp32 tiled GEMM: C[N,Co] = A[N,K] @ B[K,Co] (+bias) ----------------
__global__ __launch_bounds__(256) void gemm_tile_kernel(
    const float* __restrict__ A, const float* __restrict__ B,
    const float* __restrict__ bias, float* __restrict__ C,
    int N, int K, int Co, int flags /* bit0: add bias */)
{
    __shared__ float As[BK][BM + 1];
    __shared__ float Bs[BK][BN + 1];
    const int tid = threadIdx.x;
    const int tx = tid & 15;
    const int ty = tid >> 4;
    const int block_n = blockIdx.x * BN;
    const int block_m = blockIdx.y * BM;

    float acc[4][4];
#pragma unroll
    for (int m = 0; m < 4; ++m)
#pragma unroll
        for (int n = 0; n < 4; ++n) acc[m][n] = 0.f;

    const int ar = tid >> 2;
    const int ak = (tid & 3) << 2;
    const int bk = tid >> 4;
    const int bc_ = (tid & 15) << 2;

    for (int k0 = 0; k0 < K; k0 += BK) {
        {
            float4 v = make_float4(0.f, 0.f, 0.f, 0.f);
            int grow = block_m + ar;
            int gk = k0 + ak;
            if (grow < N) {
                if (gk + 3 < K) {
                    v = *reinterpret_cast<const float4*>(A + (size_t)grow * K + gk);
                } else {
                    float t0 = (gk + 0 < K) ? A[(size_t)grow * K + gk + 0] : 0.f;
                    float t1 = (gk + 1 < K) ? A[(size_t)grow * K + gk + 1] : 0.f;
                    float t2 = (gk + 2 < K) ? A[(size_t)grow * K + gk + 2] : 0.f;
                    float t3 = (gk + 3 < K) ? A[(size_t)grow * K + gk + 3] : 0.f;
                    v = make_float4(t0, t1, t2, t3);
                }
            }
            As[ak + 0][ar] = v.x;
            As[ak + 1][ar] = v.y;
            As[ak + 2][ar] = v.z;
            As[ak + 3][ar] = v.w;
        }
        {
            float4 v = make_float4(0.f, 0.f, 0.f, 0.f);
            int gk = k0 + bk;
            if (gk < K) v = *reinterpret_cast<const float4*>(B + (size_t)gk * Co + block_n + bc_);
            Bs[bk][bc_ + 0] = v.x;
            Bs[bk][bc_ + 1] = v.y;
            Bs[bk][bc_ + 2] = v.z;
            Bs[bk][bc_ + 3] = v.w;
        }
        __syncthreads();

#pragma unroll
        for (int kk = 0; kk < BK; ++kk) {
            float a[4], b[4];
#pragma unroll
            for (int m = 0; m < 4; ++m) a[m] = As[kk][ty * 4 + m];
#pragma unroll
            for (int n = 0; n < 4; ++n) b[n] = Bs[kk][tx * 4 + n];
#pragma unroll
            for (int m = 0; m < 4; ++m)
#pragma unroll
                for (int n = 0; n < 4; ++n) acc[m][n] = fmaf(a[m], b[n], acc[m][n]);
        }
        __syncthreads();
    }

#pragma unroll
    for (int m = 0; m < 4; ++m) {
        int gr = block_m + ty * 4 + m;
        if (gr >= N) continue;
#pragma unroll
        for (int n = 0; n < 4; ++n) {
            int gcol = block_n + tx * 4 + n;
            float v = acc[m][n];
            if (flags & 1) v += bias[gcol];
            C[(size_t)gr * Co + gcol] = v;
        }
    }
}

// ---------------- CSR build: histogram ----------------
__global__ __launch_bounds__(256) void hist_kernel(
    const int* __restrict__ edst, int* __restrict__ cnt, int n_edges)
{
    int idx = blockIdx.x * blockDim.x + threadIdx.x;
    const int stride = gridDim.x * blockDim.x;
    for (; idx < n_edges; idx += stride) atomicAdd(&cnt[edst[idx]], 1);
}

// ---------------- CSR build: single-block exclusive scan over n bins ----------------
__global__ __launch_bounds__(1024) void scan_kernel(
    const int* __restrict__ cnt, int* __restrict__ row_ptr,
    int* __restrict__ heads, int n)
{
    __shared__ int sums[1024];
    const int tid = threadIdx.x;
    const int per = (n + 1023) >> 10;
    const int start = tid * per;
    const int end = min(start + per, n);
    int local = 0;
    for (int i = start; i < end; ++i) local += cnt[i];
    sums[tid] = local;
    __syncthreads();
    // Hillis-Steele inclusive scan
    for (int off = 1; off < 1024; off <<= 1) {
        int v = sums[tid];
        if (tid >= off) v += sums[tid - off];
        __syncthreads();
        sums[tid] = v;
        __syncthreads();
    }
    int run = sums[tid] - local; // exclusive prefix for this chunk
    for (int i = start; i < end; ++i) {
        row_ptr[i] = run;
        heads[i] = run;
        run += cnt[i];
    }
    if (tid == 1023) row_ptr[n] = sums[1023];
}

// ---------------- CSR build: scatter edges sorted by dst ----------------
__global__ __launch_bounds__(256) void scatter_kernel(
    const int* __restrict__ esrc, const int* __restrict__ edst,
    const float* __restrict__ ew, int* __restrict__ heads,
    int* __restrict__ ssorted, float* __restrict__ wsorted, int n_edges)
{
    int idx = blockIdx.x * blockDim.x + threadIdx.x;
    const int stride = gridDim.x * blockDim.x;
    for (; idx < n_edges; idx += stride) {
        int d = edst[idx];
        int pos = atomicAdd(&heads[d], 1);
        ssorted[pos] = esrc[idx];
        wsorted[pos] = ew[idx];
    }
}

// ---------------- CSR SpMM: one wave per dst node, accumulate into hout row ----------------
__global__ __launch_bounds__(256) void spmm_csr_kernel(
    const int* __restrict__ row_ptr, const int* __restrict__ ssorted,
    const float* __restrict__ wsorted, const float* __restrict__ support,
    float* __restrict__ hout, int N)
{
    const int wave = threadIdx.x >> 6;
    const int lane = threadIdx.x & 63;
    const int node = blockIdx.x * 4 + wave;
    if (node >= N) return;
    const int beg = row_ptr[node];
    const int end = row_ptr[node + 1];
    float* op = hout + (size_t)node * 256 + lane * 4;
    float4 acc = *reinterpret_cast<float4*>(op);

    int e = beg;
    // 2-deep software pipeline on the (src, w) metadata
    if (e < end) {
        int s = ssorted[e];
        float w = wsorted[e];
        for (; e + 1 < end; ++e) {
            int s_next = ssorted[e + 1];
            float w_next = wsorted[e + 1];
            float4 v = *reinterpret_cast<const float4*>(support + (size_t)s * 256 + lane * 4);
            acc.x = fmaf(w, v.x, acc.x);
            acc.y = fmaf(w, v.y, acc.y);
            acc.z = fmaf(w, v.z, acc.z);
            acc.w = fmaf(w, v.w, acc.w);
            s = s_next;
            w = w_next;
        }
        float4 v = *reinterpret_cast<const float4*>(support + (size_t)s * 256 + lane * 4);
        acc.x = fmaf(w, v.x, acc.x);
        acc.y = fmaf(w, v.y, acc.y);
        acc.z = fmaf(w, v.z, acc.z);
        acc.w = fmaf(w, v.w, acc.w);
    }
    *reinterpret_cast<float4*>(op) = acc;
}

// ---------------- BN stats ----------------
__global__ __launch_bounds__(256) void bn_stats_kernel(
    const float* __restrict__ X, float* __restrict__ sums, int N)
{
    const int c = threadIdx.x;
    float s = 0.f, s2 = 0.f;
    for (int i = blockIdx.x; i < N; i += gridDim.x) {
        float v = X[(size_t)i * 256 + c];
        s += v;
        s2 = fmaf(v, v, s2);
    }
    atomicAdd(&sums[c], s);
    atomicAdd(&sums[256 + c], s2);
}

__global__ __launch_bounds__(256) void bn_finalize_kernel(
    const float* __restrict__ sums, const float* __restrict__ g,
    const float* __restrict__ be, float* __restrict__ kp, int N)
{
    const int c = threadIdx.x;
    float invN = 1.f / (float)N;
    float mean = sums[c] * invN;
    float var = sums[256 + c] * invN - mean * mean;
    float inv = rsqrtf(var + 1e-5f);
    float sc = g[c] * inv;
    kp[c] = sc;
    kp[256 + c] = be[c] - sc * mean;
}

__global__ __launch_bounds__(256) void bn_apply_kernel(
    float* __restrict__ X, const float* __restrict__ kp, long long n4)
{
    long long idx = (long long)blockIdx.x * blockDim.x + threadIdx.x;
    const long long stride = (long long)gridDim.x * blockDim.x;
    for (; idx < n4; idx += stride) {
        int c4 = (int)(idx & 63);
        float4 v = reinterpret_cast<float4*>(X)[idx];
        float4 s = reinterpret_cast<const float4*>(kp)[c4];
        float4 t = reinterpret_cast<const float4*>(kp + 256)[c4];
        v.x = fmaxf(fmaf(v.x, s.x, t.x), 0.f);
        v.y = fmaxf(fmaf(v.y, s.y, t.y), 0.f);
        v.z = fmaxf(fmaf(v.z, s.z, t.z), 0.f);
        v.w = fmaxf(fmaf(v.w, s.w, t.w), 0.f);
        reinterpret_cast<float4*>(X)[idx] = v;
    }
}

// ---------------- output projection ----------------
__global__ __launch_bounds__(256) void outproj_kernel(
    const float* __restrict__ A, int K, const float* __restrict__ Wc,
    const float* __restrict__ bc, float* __restrict__ out, int N,
    int flags /* 1: overwrite + bias; 2: accumulate */)
{
    long long idx = (long long)blockIdx.x * blockDim.x + threadIdx.x;
    const long long total = (long long)N * 40;
    const long long stride = (long long)gridDim.x * blockDim.x;
    for (; idx < total; idx += stride) {
        int i = (int)(idx / 40);
        int j = (int)(idx - (long long)i * 40);
        const float* a = A + (size_t)i * K;
        float acc = 0.f;
        for (int k = 0; k < K; ++k) acc = fmaf(a[k], Wc[(size_t)k * 40 + j], acc);
        if (flags & 1) acc += bc[j];
        if (flags & 2) acc += out[idx];
        out[idx] = acc;
    }
}

// ---------------- host-side orchestration ----------------
static void run_gc(const float* h, int K,
                   const float* W, const float* SW, const float* b,
                   const float* g, const float* be,
                   const int* row_ptr, const int* ssorted, const float* wsorted,
                   float* support, float* hout, float* stats,
                   int N, hipStream_t stream)
{
    dim3 gblock(256);
    dim3 ggrid(256 / BN, (N + BM - 1) / BM);
    hipLaunchKernelGGL(gemm_tile_kernel, ggrid, gblock, 0, stream,
                       h, W, nullptr, support, N, K, 256, 0);
    hipLaunchKernelGGL(gemm_tile_kernel, ggrid, gblock, 0, stream,
                       h, SW, b, hout, N, K, 256, 1);
    hipLaunchKernelGGL(spmm_csr_kernel, dim3((N + 3) / 4), dim3(256), 0, stream,
                       row_ptr, ssorted, wsorted, support, hout, N);
    hipMemsetAsync(stats, 0, 512 * sizeof(float), stream);
    hipLaunchKernelGGL(bn_stats_kernel, dim3(1024), dim3(256), 0, stream, hout, stats, N);
    hipLaunchKernelGGL(bn_finalize_kernel, dim3(1), dim3(256), 0, stream, stats, g, be, stats + 512, N);
    hipLaunchKernelGGL(bn_apply_kernel, dim3(2048), dim3(256), 0, stream,
                       hout, stats + 512, (long long)N * 64);
}

extern "C" void kernel_launch(void* const* d_in, const int* in_sizes, int n_in,
                              void* d_out, int out_size, void* d_ws, size_t ws_size,
                              hipStream_t stream)
{
    const float* x      = (const float*)d_in[0];
    const int*   esrc   = (const int*)d_in[1];
    const int*   edst   = (const int*)d_in[2];
    const float* ew     = (const float*)d_in[3];
    const float* W_in   = (const float*)d_in[4];
    const float* SW_in  = (const float*)d_in[5];
    const float* b_in   = (const float*)d_in[6];
    const float* g_in   = (const float*)d_in[7];
    const float* be_in  = (const float*)d_in[8];
    const float* W_h    = (const float*)d_in[9];
    const float* SW_h   = (const float*)d_in[10];
    const float* b_h    = (const float*)d_in[11];
    const float* g_h    = (const float*)d_in[12];
    const float* be_h   = (const float*)d_in[13];
    const float* Wc     = (const float*)d_in[14];
    const float* bc     = (const float*)d_in[15];
    float* out = (float*)d_out;

    const int IN_F = 500;
    const int N = in_sizes[0] / IN_F;     // 100000
    const int n_edges = in_sizes[1];      // 3200000

    const size_t NH = (size_t)N * 256;
    float* S     = (float*)d_ws;
    float* H1    = S + NH;
    float* H2    = H1 + NH;
    float* stats = H2 + NH;               // 1024 floats
    int*   cnt      = (int*)(stats + 1024);
    int*   row_ptr  = cnt + N;            // N+1
    int*   heads    = row_ptr + N + 1;
    int*   ssorted  = heads + N;
    float* wsorted  = (float*)(ssorted + n_edges);

    // ---- build CSR (once per launch, reused by all 6 SpMMs) ----
    hipMemsetAsync(cnt, 0, (size_t)N * sizeof(int), stream);
    hipLaunchKernelGGL(hist_kernel, dim3(4096), dim3(256), 0, stream, edst, cnt, n_edges);
    hipLaunchKernelGGL(scan_kernel, dim3(1), dim3(1024), 0, stream, cnt, row_ptr, heads, N);
    hipLaunchKernelGGL(scatter_kernel, dim3(4096), dim3(256), 0, stream,
                       esrc, edst, ew, heads, ssorted, wsorted, n_edges);

    dim3 oblock(256);
    dim3 ogrid(8192);

    // out = x @ Wc[0:500] + bc
    hipLaunchKernelGGL(outproj_kernel, ogrid, oblock, 0, stream,
                       x, IN_F, Wc, bc, out, N, 1);

    // ---- j = 0 ----
    run_gc(x, IN_F, W_in, SW_in, b_in, g_in, be_in,
           row_ptr, ssorted, wsorted, S, H1, stats, N, stream);
    hipLaunchKernelGGL(outproj_kernel, ogrid, oblock, 0, stream,
                       H1, 256, Wc + (size_t)500 * 40, nullptr, out, N, 2);

    // ---- j = 1 ----
    run_gc(x, IN_F, W_in + 1 * 500 * 256, SW_in + 1 * 500 * 256, b_in + 256, g_in + 256, be_in + 256,
           row_ptr, ssorted, wsorted, S, H1, stats, N, stream);
    run_gc(H1, 256, W_h, SW_h, b_h, g_h, be_h,
           row_ptr, ssorted, wsorted, S, H2, stats, N, stream);
    hipLaunchKernelGGL(outproj_kernel, ogrid, oblock, 0, stream,
                       H2, 256, Wc + (size_t)756 * 40, nullptr, out, N, 2);

    // ---- j = 2 ----
    run_gc(x, IN_F, W_in + 2 * 500 * 256, SW_in + 2 * 500 * 256, b_in + 512, g_in + 512, be_in + 512,
           row_ptr, ssorted, wsorted, S, H1, stats, N, stream);
    run_gc(H1, 256, W_h + 1 * 256 * 256, SW_h + 1 * 256 * 256, b_h + 256, g_h + 256, be_h + 256,
           row_ptr, ssorted, wsorted, S, H2, stats, N, stream);
    run_gc(H2, 256, W_h + 2 * 256 * 256, SW_h + 2 * 256 * 256, b_h + 512, g_h + 512, be_h + 512,
           row_ptr, ssorted, wsorted, S, H1, stats, N, stream);
    hipLaunchKernelGGL(outproj_kernel, ogrid, oblock, 0, stream,
                       H1, 256, Wc + (size_t)1012 * 40, nullptr, out, N, 2);
}

// Round 3
// 4335.597 us; speedup vs baseline: 17.2514x; 2.5370x over previous
//
#include <hip/hip_runtime.h>

typedef __attribute__((ext_vector_type(8))) short bf16x8;
typedef __attribute__((ext_vector_type(4))) float f32x4;
typedef __attribute__((ext_vector_type(4))) unsigned short u16x4;
typedef __attribute__((ext_vector_type(8))) unsigned short u16x8;

__device__ __forceinline__ float bf2f(unsigned short u) {
    union { unsigned int i; float f; } v; v.i = ((unsigned int)u) << 16; return v.f;
}
__device__ __forceinline__ unsigned short f2bf(float f) {
    union { float f; unsigned int i; } v; v.f = f;
    unsigned int b = v.i;
    b += 0x7FFFu + ((b >> 16) & 1u);   // round-to-nearest-even
    return (unsigned short)(b >> 16);
}

// ---------------- bf16 MFMA GEMM: C[N,256] = A[N,Kp] @ Bt^T (+bias) ----------------
// A: [N][Kp] bf16 row-major (zero-padded K). Bt: [256][Kp] bf16 (pre-transposed weight).
// Block 256 thr = 4 waves; tile 64 rows x 256 cols; wave w owns cols w*64..w*64+63.
__global__ __launch_bounds__(256) void gemm_mfma_kernel(
    const unsigned short* __restrict__ A, const unsigned short* __restrict__ Bt,
    const float* __restrict__ bias, void* __restrict__ Cout,
    int N, int Kp, int flags /* bit0: bias, bit1: bf16 output */)
{
    const int lane = threadIdx.x & 63;
    const int wave = threadIdx.x >> 6;
    const int l16 = lane & 15;
    const int khi = lane >> 4;
    const long long bm = (long long)blockIdx.x * 64;
    const int col0 = wave * 64;

    f32x4 acc[4][4];
#pragma unroll
    for (int m = 0; m < 4; ++m)
#pragma unroll
        for (int n = 0; n < 4; ++n) acc[m][n] = (f32x4){0.f, 0.f, 0.f, 0.f};

    const unsigned short* ap[4];
#pragma unroll
    for (int m = 0; m < 4; ++m) {
        long long r = bm + m * 16 + l16;
        if (r >= N) r = 0;  // clamp; results for OOB rows discarded at store
        ap[m] = A + (size_t)r * Kp + khi * 8;
    }
    const unsigned short* bp[4];
#pragma unroll
    for (int n = 0; n < 4; ++n)
        bp[n] = Bt + (size_t)(col0 + n * 16 + l16) * Kp + khi * 8;

    for (int k0 = 0; k0 < Kp; k0 += 32) {
        bf16x8 a[4], b[4];
#pragma unroll
        for (int m = 0; m < 4; ++m) a[m] = *reinterpret_cast<const bf16x8*>(ap[m] + k0);
#pragma unroll
        for (int n = 0; n < 4; ++n) b[n] = *reinterpret_cast<const bf16x8*>(bp[n] + k0);
#pragma unroll
        for (int m = 0; m < 4; ++m)
#pragma unroll
            for (int n = 0; n < 4; ++n)
                acc[m][n] = __builtin_amdgcn_mfma_f32_16x16x32_bf16(a[m], b[n], acc[m][n], 0, 0, 0);
    }

    float bs[4];
#pragma unroll
    for (int n = 0; n < 4; ++n) bs[n] = (flags & 1) ? bias[col0 + n * 16 + l16] : 0.f;

#pragma unroll
    for (int m = 0; m < 4; ++m) {
#pragma unroll
        for (int r = 0; r < 4; ++r) {
            long long grow = bm + m * 16 + khi * 4 + r;  // C/D: col=lane&15, row=(lane>>4)*4+reg
            if (grow >= N) continue;
#pragma unroll
            for (int n = 0; n < 4; ++n) {
                int gcol = col0 + n * 16 + l16;
                float v = acc[m][n][r] + bs[n];
                if (flags & 2) ((unsigned short*)Cout)[grow * 256 + gcol] = f2bf(v);
                else           ((float*)Cout)[grow * 256 + gcol] = v;
            }
        }
    }
}

// ---------------- weight transpose+pad+bf16: W[L][K][256] -> Wt[L][256][Kp] ----------------
__global__ __launch_bounds__(256) void transpose_w_kernel(
    const float* __restrict__ W, unsigned short* __restrict__ Wt, int K, int Kp, int L)
{
    long long total = (long long)L * 256 * Kp;
    long long idx = (long long)blockIdx.x * blockDim.x + threadIdx.x;
    const long long stride = (long long)gridDim.x * blockDim.x;
    for (; idx < total; idx += stride) {
        int l = (int)(idx / ((long long)256 * Kp));
        long long rem = idx - (long long)l * 256 * Kp;
        int c = (int)(rem / Kp);
        int k = (int)(rem - (long long)c * Kp);
        float v = (k < K) ? W[((size_t)l * K + k) * 256 + c] : 0.f;
        Wt[idx] = f2bf(v);
    }
}

// ---------------- x -> bf16 with pad 500->512 ----------------
__global__ __launch_bounds__(256) void cvt_x_kernel(
    const float* __restrict__ X, unsigned short* __restrict__ Xb, int N)
{
    long long total = (long long)N * 512;
    long long idx = (long long)blockIdx.x * blockDim.x + threadIdx.x;
    const long long stride = (long long)gridDim.x * blockDim.x;
    for (; idx < total; idx += stride) {
        long long r = idx >> 9;
        int k = (int)(idx & 511);
        float v = (k < 500) ? X[r * 500 + k] : 0.f;
        Xb[idx] = f2bf(v);
    }
}

// ---------------- CSR build ----------------
__global__ __launch_bounds__(256) void hist_kernel(
    const int* __restrict__ edst, int* __restrict__ cnt, int n_edges)
{
    int idx = blockIdx.x * blockDim.x + threadIdx.x;
    const int stride = gridDim.x * blockDim.x;
    for (; idx < n_edges; idx += stride) atomicAdd(&cnt[edst[idx]], 1);
}

__global__ __launch_bounds__(1024) void scan_kernel(
    const int* __restrict__ cnt, int* __restrict__ row_ptr,
    int* __restrict__ heads, int n)
{
    __shared__ int sums[1024];
    const int tid = threadIdx.x;
    const int per = (n + 1023) >> 10;
    const int start = tid * per;
    const int end = min(start + per, n);
    int local = 0;
    for (int i = start; i < end; ++i) local += cnt[i];
    sums[tid] = local;
    __syncthreads();
    for (int off = 1; off < 1024; off <<= 1) {
        int v = sums[tid];
        if (tid >= off) v += sums[tid - off];
        __syncthreads();
        sums[tid] = v;
        __syncthreads();
    }
    int run = sums[tid] - local;
    for (int i = start; i < end; ++i) {
        row_ptr[i] = run;
        heads[i] = run;
        run += cnt[i];
    }
    if (tid == 1023) row_ptr[n] = sums[1023];
}

__global__ __launch_bounds__(256) void scatter_kernel(
    const int* __restrict__ esrc, const int* __restrict__ edst,
    const float* __restrict__ ew, int* __restrict__ heads,
    int* __restrict__ ssorted, float* __restrict__ wsorted, int n_edges)
{
    int idx = blockIdx.x * blockDim.x + threadIdx.x;
    const int stride = gridDim.x * blockDim.x;
    for (; idx < n_edges; idx += stride) {
        int d = edst[idx];
        int pos = atomicAdd(&heads[d], 1);
        ssorted[pos] = esrc[idx];
        wsorted[pos] = ew[idx];
    }
}

// ---------------- CSR SpMM (bf16 support, bf16 H in/out, fp32 accum) ----------------
__global__ __launch_bounds__(256) void spmm_csr_kernel(
    const int* __restrict__ row_ptr, const int* __restrict__ ssorted,
    const float* __restrict__ wsorted, const unsigned short* __restrict__ S,
    unsigned short* __restrict__ H, int N)
{
    const int wave = threadIdx.x >> 6;
    const int lane = threadIdx.x & 63;
    const int node = blockIdx.x * 4 + wave;
    if (node >= N) return;
    const int beg = row_ptr[node];
    const int end = row_ptr[node + 1];
    unsigned short* hp = H + (size_t)node * 256 + lane * 4;
    u16x4 h4 = *reinterpret_cast<u16x4*>(hp);
    float a0 = bf2f(h4[0]), a1 = bf2f(h4[1]), a2 = bf2f(h4[2]), a3 = bf2f(h4[3]);

    int e = beg;
    if (e < end) {
        int s = ssorted[e];
        float w = wsorted[e];
        for (; e + 1 < end; ++e) {
            int sn = ssorted[e + 1];
            float wn = wsorted[e + 1];
            u16x4 v = *reinterpret_cast<const u16x4*>(S + (size_t)s * 256 + lane * 4);
            a0 = fmaf(w, bf2f(v[0]), a0);
            a1 = fmaf(w, bf2f(v[1]), a1);
            a2 = fmaf(w, bf2f(v[2]), a2);
            a3 = fmaf(w, bf2f(v[3]), a3);
            s = sn; w = wn;
        }
        u16x4 v = *reinterpret_cast<const u16x4*>(S + (size_t)s * 256 + lane * 4);
        a0 = fmaf(w, bf2f(v[0]), a0);
        a1 = fmaf(w, bf2f(v[1]), a1);
        a2 = fmaf(w, bf2f(v[2]), a2);
        a3 = fmaf(w, bf2f(v[3]), a3);
    }
    h4[0] = f2bf(a0); h4[1] = f2bf(a1); h4[2] = f2bf(a2); h4[3] = f2bf(a3);
    *reinterpret_cast<u16x4*>(hp) = h4;
}

// ---------------- BN stats (bf16 input) ----------------
__global__ __launch_bounds__(256) void bn_stats_kernel(
    const unsigned short* __restrict__ X, float* __restrict__ sums, int N)
{
    const int c = threadIdx.x;
    float s = 0.f, s2 = 0.f;
    for (int i = blockIdx.x; i < N; i += gridDim.x) {
        float v = bf2f(X[(size_t)i * 256 + c]);
        s += v;
        s2 = fmaf(v, v, s2);
    }
    atomicAdd(&sums[c], s);
    atomicAdd(&sums[256 + c], s2);
}

__global__ __launch_bounds__(256) void bn_finalize_kernel(
    const float* __restrict__ sums, const float* __restrict__ g,
    const float* __restrict__ be, float* __restrict__ kp, int N)
{
    const int c = threadIdx.x;
    float invN = 1.f / (float)N;
    float mean = sums[c] * invN;
    float var = sums[256 + c] * invN - mean * mean;
    float inv = rsqrtf(var + 1e-5f);
    float sc = g[c] * inv;
    kp[c] = sc;
    kp[256 + c] = be[c] - sc * mean;
}

// ---------------- BN apply + ReLU in place (bf16) ----------------
__global__ __launch_bounds__(256) void bn_apply_kernel(
    unsigned short* __restrict__ X, const float* __restrict__ kp, long long n4)
{
    long long idx = (long long)blockIdx.x * blockDim.x + threadIdx.x;
    const long long stride = (long long)gridDim.x * blockDim.x;
    for (; idx < n4; idx += stride) {
        int c4 = (int)(idx & 63);
        u16x4 v = reinterpret_cast<u16x4*>(X)[idx];
        f32x4 s = reinterpret_cast<const f32x4*>(kp)[c4];
        f32x4 t = reinterpret_cast<const f32x4*>(kp + 256)[c4];
#pragma unroll
        for (int i = 0; i < 4; ++i) {
            float f = fmaxf(fmaf(bf2f(v[i]), s[i], t[i]), 0.f);
            v[i] = f2bf(f);
        }
        reinterpret_cast<u16x4*>(X)[idx] = v;
    }
}

// ---------------- output projection: out[N,40] (+)= A_bf[N,Kp(:K)] @ Wc[K,40] ----------------
// Block 256 thr; 128 rows per block; thread = (ty=row-group of 4, tx=col-group of 5).
__global__ __launch_bounds__(256) void outproj_kernel(
    const unsigned short* __restrict__ A, int Kp, int K,
    const float* __restrict__ Wc, const float* __restrict__ bc,
    float* __restrict__ out, int N, int flags /* 1: overwrite+bias; 2: accumulate */)
{
    __shared__ float As[32][128];
    __shared__ float Ws[32][40];
    const int tid = threadIdx.x;
    const int tx = tid & 7;
    const int ty = tid >> 3;
    const long long bm = (long long)blockIdx.x * 128;

    float acc[4][5];
#pragma unroll
    for (int r = 0; r < 4; ++r)
#pragma unroll
        for (int c = 0; c < 5; ++c) acc[r][c] = 0.f;

    const int lr = tid >> 1;          // staging row 0..127
    const int ks = (tid & 1) * 16;    // staging k offset 0/16

    for (int k0 = 0; k0 < K; k0 += 32) {
        // stage A tile (bf16 -> f32, transposed)
        {
            long long r = bm + lr;
            u16x8 t0 = (u16x8)0, t1 = (u16x8)0;
            if (r < N) {
                const unsigned short* p = A + (size_t)r * Kp + k0 + ks;
                t0 = *reinterpret_cast<const u16x8*>(p);
                t1 = *reinterpret_cast<const u16x8*>(p + 8);
            }
#pragma unroll
            for (int j = 0; j < 8; ++j) {
                As[ks + j][lr] = bf2f(t0[j]);
                As[ks + 8 + j][lr] = bf2f(t1[j]);
            }
        }
        // stage Wc tile (32 x 40)
#pragma unroll
        for (int j = 0; j < 5; ++j) {
            int idx = tid * 5 + j;         // 0..1279
            int kk = idx / 40;
            int c = idx - kk * 40;
            int gk = k0 + kk;
            Ws[kk][c] = (gk < K) ? Wc[(size_t)gk * 40 + c] : 0.f;
        }
        __syncthreads();

#pragma unroll 8
        for (int kk = 0; kk < 32; ++kk) {
            float a[4], w[5];
#pragma unroll
            for (int r = 0; r < 4; ++r) a[r] = As[kk][ty * 4 + r];
#pragma unroll
            for (int c = 0; c < 5; ++c) w[c] = Ws[kk][tx * 5 + c];
#pragma unroll
            for (int r = 0; r < 4; ++r)
#pragma unroll
                for (int c = 0; c < 5; ++c) acc[r][c] = fmaf(a[r], w[c], acc[r][c]);
        }
        __syncthreads();
    }

#pragma unroll
    for (int r = 0; r < 4; ++r) {
        long long grow = bm + ty * 4 + r;
        if (grow >= N) continue;
#pragma unroll
        for (int c = 0; c < 5; ++c) {
            int gcol = tx * 5 + c;
            float v = acc[r][c];
            if (flags & 1) v += bc[gcol];
            if (flags & 2) v += out[grow * 40 + gcol];
            out[grow * 40 + gcol] = v;
        }
    }
}

// ---------------- host-side orchestration ----------------
static void run_gc(const unsigned short* h_bf, int Kp,
                   const unsigned short* Wt, const unsigned short* SWt, const float* b,
                   const float* g, const float* be,
                   const int* row_ptr, const int* ssorted, const float* wsorted,
                   unsigned short* S_bf, unsigned short* Hb, float* stats,
                   int N, hipStream_t stream)
{
    dim3 gblock(256);
    dim3 ggrid((N + 63) / 64);
    // S_bf = h @ W (bf16 out)
    hipLaunchKernelGGL(gemm_mfma_kernel, ggrid, gblock, 0, stream,
                       h_bf, Wt, (const float*)nullptr, (void*)S_bf, N, Kp, 2);
    // Hb = h @ SW + b (bf16 out)
    hipLaunchKernelGGL(gemm_mfma_kernel, ggrid, gblock, 0, stream,
                       h_bf, SWt, b, (void*)Hb, N, Kp, 1 | 2);
    // Hb += spmm(adj, S_bf)
    hipLaunchKernelGGL(spmm_csr_kernel, dim3((N + 3) / 4), dim3(256), 0, stream,
                       row_ptr, ssorted, wsorted, S_bf, Hb, N);
    // BN
    hipMemsetAsync(stats, 0, 512 * sizeof(float), stream);
    hipLaunchKernelGGL(bn_stats_kernel, dim3(1024), dim3(256), 0, stream, Hb, stats, N);
    hipLaunchKernelGGL(bn_finalize_kernel, dim3(1), dim3(256), 0, stream, stats, g, be, stats + 512, N);
    hipLaunchKernelGGL(bn_apply_kernel, dim3(2048), dim3(256), 0, stream,
                       Hb, stats + 512, (long long)N * 64);
}

extern "C" void kernel_launch(void* const* d_in, const int* in_sizes, int n_in,
                              void* d_out, int out_size, void* d_ws, size_t ws_size,
                              hipStream_t stream)
{
    const float* x      = (const float*)d_in[0];
    const int*   esrc   = (const int*)d_in[1];
    const int*   edst   = (const int*)d_in[2];
    const float* ew     = (const float*)d_in[3];
    const float* W_in   = (const float*)d_in[4];
    const float* SW_in  = (const float*)d_in[5];
    const float* b_in   = (const float*)d_in[6];
    const float* g_in   = (const float*)d_in[7];
    const float* be_in  = (const float*)d_in[8];
    const float* W_h    = (const float*)d_in[9];
    const float* SW_h   = (const float*)d_in[10];
    const float* b_h    = (const float*)d_in[11];
    const float* g_h    = (const float*)d_in[12];
    const float* be_h   = (const float*)d_in[13];
    const float* Wc     = (const float*)d_in[14];
    const float* bc     = (const float*)d_in[15];
    float* out = (float*)d_out;

    const int N = in_sizes[0] / 500;      // 100000
    const int n_edges = in_sizes[1];      // 3200000

    // ---- workspace layout (16B-aligned chunks) ----
    char* p = (char*)d_ws;
    unsigned short* x_bf = (unsigned short*)p; p += (size_t)N * 512 * 2;       // 102.4 MB
    unsigned short* S_bf = (unsigned short*)p; p += (size_t)N * 256 * 2;       // 51.2 MB
    unsigned short* H1bf = (unsigned short*)p; p += (size_t)N * 256 * 2;
    unsigned short* H2bf = (unsigned short*)p; p += (size_t)N * 256 * 2;
    unsigned short* Wt_in  = (unsigned short*)p; p += (size_t)3 * 256 * 512 * 2;
    unsigned short* SWt_in = (unsigned short*)p; p += (size_t)3 * 256 * 512 * 2;
    unsigned short* Wt_h   = (unsigned short*)p; p += (size_t)3 * 256 * 256 * 2;
    unsigned short* SWt_h  = (unsigned short*)p; p += (size_t)3 * 256 * 256 * 2;
    float* stats = (float*)p; p += 1024 * 4;
    int* cnt     = (int*)p; p += (size_t)N * 4;
    int* row_ptr = (int*)p; p += (size_t)(N + 1) * 4 + 4;
    int* heads   = (int*)p; p += (size_t)N * 4;
    int* ssorted = (int*)p; p += (size_t)n_edges * 4;
    float* wsorted = (float*)p;

    // ---- preprocessing: weights -> bf16 transposed, x -> bf16 padded, CSR ----
    hipLaunchKernelGGL(transpose_w_kernel, dim3(1024), dim3(256), 0, stream, W_in,  Wt_in,  500, 512, 3);
    hipLaunchKernelGGL(transpose_w_kernel, dim3(1024), dim3(256), 0, stream, SW_in, SWt_in, 500, 512, 3);
    hipLaunchKernelGGL(transpose_w_kernel, dim3(1024), dim3(256), 0, stream, W_h,   Wt_h,   256, 256, 3);
    hipLaunchKernelGGL(transpose_w_kernel, dim3(1024), dim3(256), 0, stream, SW_h,  SWt_h,  256, 256, 3);
    hipLaunchKernelGGL(cvt_x_kernel, dim3(4096), dim3(256), 0, stream, x, x_bf, N);

    hipMemsetAsync(cnt, 0, (size_t)N * sizeof(int), stream);
    hipLaunchKernelGGL(hist_kernel, dim3(4096), dim3(256), 0, stream, edst, cnt, n_edges);
    hipLaunchKernelGGL(scan_kernel, dim3(1), dim3(1024), 0, stream, cnt, row_ptr, heads, N);
    hipLaunchKernelGGL(scatter_kernel, dim3(4096), dim3(256), 0, stream,
                       esrc, edst, ew, heads, ssorted, wsorted, n_edges);

    dim3 oblock(256);
    dim3 ogrid((N + 127) / 128);

    // out = x @ Wc[0:500] + bc
    hipLaunchKernelGGL(outproj_kernel, ogrid, oblock, 0, stream,
                       x_bf, 512, 500, Wc, bc, out, N, 1);

    // ---- j = 0 ----
    run_gc(x_bf, 512, Wt_in, SWt_in, b_in, g_in, be_in,
           row_ptr, ssorted, wsorted, S_bf, H1bf, stats, N, stream);
    hipLaunchKernelGGL(outproj_kernel, ogrid, oblock, 0, stream,
                       H1bf, 256, 256, Wc + (size_t)500 * 40, bc, out, N, 2);

    // ---- j = 1 ----
    run_gc(x_bf, 512, Wt_in + (size_t)1 * 256 * 512, SWt_in + (size_t)1 * 256 * 512,
           b_in + 256, g_in + 256, be_in + 256,
           row_ptr, ssorted, wsorted, S_bf, H1bf, stats, N, stream);
    run_gc(H1bf, 256, Wt_h, SWt_h, b_h, g_h, be_h,
           row_ptr, ssorted, wsorted, S_bf, H2bf, stats, N, stream);
    hipLaunchKernelGGL(outproj_kernel, ogrid, oblock, 0, stream,
                       H2bf, 256, 256, Wc + (size_t)756 * 40, bc, out, N, 2);

    // ---- j = 2 ----
    run_gc(x_bf, 512, Wt_in + (size_t)2 * 256 * 512, SWt_in + (size_t)2 * 256 * 512,
           b_in + 512, g_in + 512, be_in + 512,
           row_ptr, ssorted, wsorted, S_bf, H1bf, stats, N, stream);
    run_gc(H1bf, 256, Wt_h + (size_t)1 * 256 * 256, SWt_h + (size_t)1 * 256 * 256,
           b_h + 256, g_h + 256, be_h + 256,
           row_ptr, ssorted, wsorted, S_bf, H2bf, stats, N, stream);
    run_gc(H2bf, 256, Wt_h + (size_t)2 * 256 * 256, SWt_h + (size_t)2 * 256 * 256,
           b_h + 512, g_h + 512, be_h + 512,
           row_ptr, ssorted, wsorted, S_bf, H1bf, stats, N, stream);
    hipLaunchKernelGGL(outproj_kernel, ogrid, oblock, 0, stream,
                       H1bf, 256, 256, Wc + (size_t)1012 * 40, bc, out, N, 2);
}

// Round 4
// 4163.732 us; speedup vs baseline: 17.9635x; 1.0413x over previous
//
#include <hip/hip_runtime.h>

typedef __attribute__((ext_vector_type(8))) short bf16x8;
typedef __attribute__((ext_vector_type(4))) float f32x4;
typedef __attribute__((ext_vector_type(4))) unsigned short u16x4;
typedef __attribute__((ext_vector_type(8))) unsigned short u16x8;

__device__ __forceinline__ float bf2f(unsigned short u) {
    union { unsigned int i; float f; } v; v.i = ((unsigned int)u) << 16; return v.f;
}
__device__ __forceinline__ unsigned short f2bf(float f) {
    union { float f; unsigned int i; } v; v.f = f;
    unsigned int b = v.i;
    b += 0x7FFFu + ((b >> 16) & 1u);   // round-to-nearest-even
    return (unsigned short)(b >> 16);
}

// ---------------- bf16 MFMA GEMM: C[N,256] = A[N,Kp] @ Bt^T (+bias) ----------------
// A: [N][Kp] bf16 row-major (zero-padded K). Bt: [256][Kp] bf16 (pre-transposed weight).
// Block 256 thr = 4 waves; tile 128 rows x 256 cols; wave w owns cols w*64..w*64+63.
// Two 64-row m-subtiles share each B fragment (halves Bt traffic vs 64-row tile).
__global__ __launch_bounds__(256) void gemm_mfma_kernel(
    const unsigned short* __restrict__ A, const unsigned short* __restrict__ Bt,
    const float* __restrict__ bias, void* __restrict__ Cout,
    int N, int Kp, int flags /* bit0: bias, bit1: bf16 output */)
{
    const int lane = threadIdx.x & 63;
    const int wave = threadIdx.x >> 6;
    const int l16 = lane & 15;
    const int khi = lane >> 4;
    const long long bm = (long long)blockIdx.x * 128;
    const int col0 = wave * 64;

    f32x4 acc[2][4][4];
#pragma unroll
    for (int t = 0; t < 2; ++t)
#pragma unroll
        for (int m = 0; m < 4; ++m)
#pragma unroll
            for (int n = 0; n < 4; ++n) acc[t][m][n] = (f32x4){0.f, 0.f, 0.f, 0.f};

    const unsigned short* ap[2][4];
#pragma unroll
    for (int t = 0; t < 2; ++t)
#pragma unroll
        for (int m = 0; m < 4; ++m) {
            long long r = bm + t * 64 + m * 16 + l16;
            if (r >= N) r = 0;  // clamp; OOB rows discarded at store
            ap[t][m] = A + (size_t)r * Kp + khi * 8;
        }
    const unsigned short* bp[4];
#pragma unroll
    for (int n = 0; n < 4; ++n)
        bp[n] = Bt + (size_t)(col0 + n * 16 + l16) * Kp + khi * 8;

    for (int k0 = 0; k0 < Kp; k0 += 32) {
        bf16x8 b[4];
#pragma unroll
        for (int n = 0; n < 4; ++n) b[n] = *reinterpret_cast<const bf16x8*>(bp[n] + k0);
        bf16x8 a[2][4];
#pragma unroll
        for (int t = 0; t < 2; ++t)
#pragma unroll
            for (int m = 0; m < 4; ++m) a[t][m] = *reinterpret_cast<const bf16x8*>(ap[t][m] + k0);
#pragma unroll
        for (int t = 0; t < 2; ++t)
#pragma unroll
            for (int m = 0; m < 4; ++m)
#pragma unroll
                for (int n = 0; n < 4; ++n)
                    acc[t][m][n] = __builtin_amdgcn_mfma_f32_16x16x32_bf16(a[t][m], b[n], acc[t][m][n], 0, 0, 0);
    }

    float bs[4];
#pragma unroll
    for (int n = 0; n < 4; ++n) bs[n] = (flags & 1) ? bias[col0 + n * 16 + l16] : 0.f;

#pragma unroll
    for (int t = 0; t < 2; ++t)
#pragma unroll
        for (int m = 0; m < 4; ++m)
#pragma unroll
            for (int r = 0; r < 4; ++r) {
                long long grow = bm + t * 64 + m * 16 + khi * 4 + r;  // C/D: col=lane&15, row=(lane>>4)*4+reg
                if (grow >= N) continue;
#pragma unroll
                for (int n = 0; n < 4; ++n) {
                    int gcol = col0 + n * 16 + l16;
                    float v = acc[t][m][n][r] + bs[n];
                    if (flags & 2) ((unsigned short*)Cout)[grow * 256 + gcol] = f2bf(v);
                    else           ((float*)Cout)[grow * 256 + gcol] = v;
                }
            }
}

// ---------------- weight transpose+pad+bf16: W[L][K][256] -> Wt[L][256][Kp] ----------------
__global__ __launch_bounds__(256) void transpose_w_kernel(
    const float* __restrict__ W, unsigned short* __restrict__ Wt, int K, int Kp, int L)
{
    long long total = (long long)L * 256 * Kp;
    long long idx = (long long)blockIdx.x * blockDim.x + threadIdx.x;
    const long long stride = (long long)gridDim.x * blockDim.x;
    for (; idx < total; idx += stride) {
        int l = (int)(idx / ((long long)256 * Kp));
        long long rem = idx - (long long)l * 256 * Kp;
        int c = (int)(rem / Kp);
        int k = (int)(rem - (long long)c * Kp);
        float v = (k < K) ? W[((size_t)l * K + k) * 256 + c] : 0.f;
        Wt[idx] = f2bf(v);
    }
}

// ---------------- x -> bf16 with pad 500->512 ----------------
__global__ __launch_bounds__(256) void cvt_x_kernel(
    const float* __restrict__ X, unsigned short* __restrict__ Xb, int N)
{
    long long total = (long long)N * 512;
    long long idx = (long long)blockIdx.x * blockDim.x + threadIdx.x;
    const long long stride = (long long)gridDim.x * blockDim.x;
    for (; idx < total; idx += stride) {
        long long r = idx >> 9;
        int k = (int)(idx & 511);
        float v = (k < 500) ? X[r * 500 + k] : 0.f;
        Xb[idx] = f2bf(v);
    }
}

// ---------------- CSR build ----------------
__global__ __launch_bounds__(256) void hist_kernel(
    const int* __restrict__ edst, int* __restrict__ cnt, int n_edges)
{
    int idx = blockIdx.x * blockDim.x + threadIdx.x;
    const int stride = gridDim.x * blockDim.x;
    for (; idx < n_edges; idx += stride) atomicAdd(&cnt[edst[idx]], 1);
}

__global__ __launch_bounds__(1024) void scan_kernel(
    const int* __restrict__ cnt, int* __restrict__ row_ptr,
    int* __restrict__ heads, int n)
{
    __shared__ int sums[1024];
    const int tid = threadIdx.x;
    const int per = (n + 1023) >> 10;
    const int start = tid * per;
    const int end = min(start + per, n);
    int local = 0;
    for (int i = start; i < end; ++i) local += cnt[i];
    sums[tid] = local;
    __syncthreads();
    for (int off = 1; off < 1024; off <<= 1) {
        int v = sums[tid];
        if (tid >= off) v += sums[tid - off];
        __syncthreads();
        sums[tid] = v;
        __syncthreads();
    }
    int run = sums[tid] - local;
    for (int i = start; i < end; ++i) {
        row_ptr[i] = run;
        heads[i] = run;
        run += cnt[i];
    }
    if (tid == 1023) row_ptr[n] = sums[1023];
}

// scatter edges sorted by dst; pack (src, w-bits) into one int2
__global__ __launch_bounds__(256) void scatter_kernel(
    const int* __restrict__ esrc, const int* __restrict__ edst,
    const float* __restrict__ ew, int* __restrict__ heads,
    int2* __restrict__ meta, int n_edges)
{
    int idx = blockIdx.x * blockDim.x + threadIdx.x;
    const int stride = gridDim.x * blockDim.x;
    for (; idx < n_edges; idx += stride) {
        int d = edst[idx];
        int pos = atomicAdd(&heads[d], 1);
        meta[pos] = make_int2(esrc[idx], __float_as_int(ew[idx]));
    }
}

// ---------------- CSR SpMM (bf16 support, bf16 H in/out, fp32 accum) ----------------
// One wave per dst node; 8-deep gather pipeline.
__global__ __launch_bounds__(256) void spmm_csr_kernel(
    const int* __restrict__ row_ptr, const int2* __restrict__ meta,
    const unsigned short* __restrict__ S,
    unsigned short* __restrict__ H, int N)
{
    const int wave = threadIdx.x >> 6;
    const int lane = threadIdx.x & 63;
    int node = blockIdx.x * 4 + wave;
    if (node >= N) return;
    node = __builtin_amdgcn_readfirstlane(node);  // wave-uniform -> scalar loads for metadata
    const int beg = row_ptr[node];
    const int end = row_ptr[node + 1];
    unsigned short* hp = H + (size_t)node * 256 + lane * 4;
    u16x4 h4 = *reinterpret_cast<u16x4*>(hp);
    float a0 = bf2f(h4[0]), a1 = bf2f(h4[1]), a2 = bf2f(h4[2]), a3 = bf2f(h4[3]);

    int e = beg;
    for (; e + 8 <= end; e += 8) {
        int2 m[8];
#pragma unroll
        for (int j = 0; j < 8; ++j) m[j] = meta[e + j];
        u16x4 v[8];
#pragma unroll
        for (int j = 0; j < 8; ++j)
            v[j] = *reinterpret_cast<const u16x4*>(S + (size_t)m[j].x * 256 + lane * 4);
#pragma unroll
        for (int j = 0; j < 8; ++j) {
            float w = __int_as_float(m[j].y);
            a0 = fmaf(w, bf2f(v[j][0]), a0);
            a1 = fmaf(w, bf2f(v[j][1]), a1);
            a2 = fmaf(w, bf2f(v[j][2]), a2);
            a3 = fmaf(w, bf2f(v[j][3]), a3);
        }
    }
    for (; e < end; ++e) {
        int2 m = meta[e];
        float w = __int_as_float(m.y);
        u16x4 v = *reinterpret_cast<const u16x4*>(S + (size_t)m.x * 256 + lane * 4);
        a0 = fmaf(w, bf2f(v[0]), a0);
        a1 = fmaf(w, bf2f(v[1]), a1);
        a2 = fmaf(w, bf2f(v[2]), a2);
        a3 = fmaf(w, bf2f(v[3]), a3);
    }
    h4[0] = f2bf(a0); h4[1] = f2bf(a1); h4[2] = f2bf(a2); h4[3] = f2bf(a3);
    *reinterpret_cast<u16x4*>(hp) = h4;
}

// ---------------- BN stats (bf16 input) ----------------
__global__ __launch_bounds__(256) void bn_stats_kernel(
    const unsigned short* __restrict__ X, float* __restrict__ sums, int N)
{
    const int c = threadIdx.x;
    float s = 0.f, s2 = 0.f;
    for (int i = blockIdx.x; i < N; i += gridDim.x) {
        float v = bf2f(X[(size_t)i * 256 + c]);
        s += v;
        s2 = fmaf(v, v, s2);
    }
    atomicAdd(&sums[c], s);
    atomicAdd(&sums[256 + c], s2);
}

__global__ __launch_bounds__(256) void bn_finalize_kernel(
    const float* __restrict__ sums, const float* __restrict__ g,
    const float* __restrict__ be, float* __restrict__ kp, int N)
{
    const int c = threadIdx.x;
    float invN = 1.f / (float)N;
    float mean = sums[c] * invN;
    float var = sums[256 + c] * invN - mean * mean;
    float inv = rsqrtf(var + 1e-5f);
    float sc = g[c] * inv;
    kp[c] = sc;
    kp[256 + c] = be[c] - sc * mean;
}

// ---------------- BN apply + ReLU in place (bf16) ----------------
__global__ __launch_bounds__(256) void bn_apply_kernel(
    unsigned short* __restrict__ X, const float* __restrict__ kp, long long n4)
{
    long long idx = (long long)blockIdx.x * blockDim.x + threadIdx.x;
    const long long stride = (long long)gridDim.x * blockDim.x;
    for (; idx < n4; idx += stride) {
        int c4 = (int)(idx & 63);
        u16x4 v = reinterpret_cast<u16x4*>(X)[idx];
        f32x4 s = reinterpret_cast<const f32x4*>(kp)[c4];
        f32x4 t = reinterpret_cast<const f32x4*>(kp + 256)[c4];
#pragma unroll
        for (int i = 0; i < 4; ++i) {
            float f = fmaxf(fmaf(bf2f(v[i]), s[i], t[i]), 0.f);
            v[i] = f2bf(f);
        }
        reinterpret_cast<u16x4*>(X)[idx] = v;
    }
}

// ---------------- output projection: out[N,40] (+)= A_bf[N,Kp(:K)] @ Wc[K,40] ----------------
__global__ __launch_bounds__(256) void outproj_kernel(
    const unsigned short* __restrict__ A, int Kp, int K,
    const float* __restrict__ Wc, const float* __restrict__ bc,
    float* __restrict__ out, int N, int flags /* 1: overwrite+bias; 2: accumulate */)
{
    __shared__ float As[32][128];
    __shared__ float Ws[32][40];
    const int tid = threadIdx.x;
    const int tx = tid & 7;
    const int ty = tid >> 3;
    const long long bm = (long long)blockIdx.x * 128;

    float acc[4][5];
#pragma unroll
    for (int r = 0; r < 4; ++r)
#pragma unroll
        for (int c = 0; c < 5; ++c) acc[r][c] = 0.f;

    const int lr = tid >> 1;
    const int ks = (tid & 1) * 16;

    for (int k0 = 0; k0 < K; k0 += 32) {
        {
            long long r = bm + lr;
            u16x8 t0 = (u16x8)0, t1 = (u16x8)0;
            if (r < N) {
                const unsigned short* p = A + (size_t)r * Kp + k0 + ks;
                t0 = *reinterpret_cast<const u16x8*>(p);
                t1 = *reinterpret_cast<const u16x8*>(p + 8);
            }
#pragma unroll
            for (int j = 0; j < 8; ++j) {
                As[ks + j][lr] = bf2f(t0[j]);
                As[ks + 8 + j][lr] = bf2f(t1[j]);
            }
        }
#pragma unroll
        for (int j = 0; j < 5; ++j) {
            int idx = tid * 5 + j;
            int kk = idx / 40;
            int c = idx - kk * 40;
            int gk = k0 + kk;
            Ws[kk][c] = (gk < K) ? Wc[(size_t)gk * 40 + c] : 0.f;
        }
        __syncthreads();

#pragma unroll 8
        for (int kk = 0; kk < 32; ++kk) {
            float a[4], w[5];
#pragma unroll
            for (int r = 0; r < 4; ++r) a[r] = As[kk][ty * 4 + r];
#pragma unroll
            for (int c = 0; c < 5; ++c) w[c] = Ws[kk][tx * 5 + c];
#pragma unroll
            for (int r = 0; r < 4; ++r)
#pragma unroll
                for (int c = 0; c < 5; ++c) acc[r][c] = fmaf(a[r], w[c], acc[r][c]);
        }
        __syncthreads();
    }

#pragma unroll
    for (int r = 0; r < 4; ++r) {
        long long grow = bm + ty * 4 + r;
        if (grow >= N) continue;
#pragma unroll
        for (int c = 0; c < 5; ++c) {
            int gcol = tx * 5 + c;
            float v = acc[r][c];
            if (flags & 1) v += bc[gcol];
            if (flags & 2) v += out[grow * 40 + gcol];
            out[grow * 40 + gcol] = v;
        }
    }
}

// ---------------- host-side orchestration ----------------
static void run_gc(const unsigned short* h_bf, int Kp,
                   const unsigned short* Wt, const unsigned short* SWt, const float* b,
                   const float* g, const float* be,
                   const int* row_ptr, const int2* meta,
                   unsigned short* S_bf, unsigned short* Hb, float* stats,
                   int N, hipStream_t stream)
{
    dim3 gblock(256);
    dim3 ggrid((N + 127) / 128);
    hipLaunchKernelGGL(gemm_mfma_kernel, ggrid, gblock, 0, stream,
                       h_bf, Wt, (const float*)nullptr, (void*)S_bf, N, Kp, 2);
    hipLaunchKernelGGL(gemm_mfma_kernel, ggrid, gblock, 0, stream,
                       h_bf, SWt, b, (void*)Hb, N, Kp, 1 | 2);
    hipLaunchKernelGGL(spmm_csr_kernel, dim3((N + 3) / 4), dim3(256), 0, stream,
                       row_ptr, meta, S_bf, Hb, N);
    hipMemsetAsync(stats, 0, 512 * sizeof(float), stream);
    hipLaunchKernelGGL(bn_stats_kernel, dim3(1024), dim3(256), 0, stream, Hb, stats, N);
    hipLaunchKernelGGL(bn_finalize_kernel, dim3(1), dim3(256), 0, stream, stats, g, be, stats + 512, N);
    hipLaunchKernelGGL(bn_apply_kernel, dim3(2048), dim3(256), 0, stream,
                       Hb, stats + 512, (long long)N * 64);
}

extern "C" void kernel_launch(void* const* d_in, const int* in_sizes, int n_in,
                              void* d_out, int out_size, void* d_ws, size_t ws_size,
                              hipStream_t stream)
{
    const float* x      = (const float*)d_in[0];
    const int*   esrc   = (const int*)d_in[1];
    const int*   edst   = (const int*)d_in[2];
    const float* ew     = (const float*)d_in[3];
    const float* W_in   = (const float*)d_in[4];
    const float* SW_in  = (const float*)d_in[5];
    const float* b_in   = (const float*)d_in[6];
    const float* g_in   = (const float*)d_in[7];
    const float* be_in  = (const float*)d_in[8];
    const float* W_h    = (const float*)d_in[9];
    const float* SW_h   = (const float*)d_in[10];
    const float* b_h    = (const float*)d_in[11];
    const float* g_h    = (const float*)d_in[12];
    const float* be_h   = (const float*)d_in[13];
    const float* Wc     = (const float*)d_in[14];
    const float* bc     = (const float*)d_in[15];
    float* out = (float*)d_out;

    const int N = in_sizes[0] / 500;      // 100000
    const int n_edges = in_sizes[1];      // 3200000

    // ---- workspace layout ----
    char* p = (char*)d_ws;
    unsigned short* x_bf = (unsigned short*)p; p += (size_t)N * 512 * 2;
    unsigned short* S_bf = (unsigned short*)p; p += (size_t)N * 256 * 2;
    unsigned short* H1bf = (unsigned short*)p; p += (size_t)N * 256 * 2;
    unsigned short* H2bf = (unsigned short*)p; p += (size_t)N * 256 * 2;
    unsigned short* Wt_in  = (unsigned short*)p; p += (size_t)3 * 256 * 512 * 2;
    unsigned short* SWt_in = (unsigned short*)p; p += (size_t)3 * 256 * 512 * 2;
    unsigned short* Wt_h   = (unsigned short*)p; p += (size_t)3 * 256 * 256 * 2;
    unsigned short* SWt_h  = (unsigned short*)p; p += (size_t)3 * 256 * 256 * 2;
    float* stats = (float*)p; p += 1024 * 4;
    int* cnt     = (int*)p; p += (size_t)N * 4;
    int* row_ptr = (int*)p; p += (size_t)(N + 1) * 4 + 4;
    int* heads   = (int*)p; p += (size_t)N * 4;
    int2* meta   = (int2*)p;

    // ---- preprocessing ----
    hipLaunchKernelGGL(transpose_w_kernel, dim3(1024), dim3(256), 0, stream, W_in,  Wt_in,  500, 512, 3);
    hipLaunchKernelGGL(transpose_w_kernel, dim3(1024), dim3(256), 0, stream, SW_in, SWt_in, 500, 512, 3);
    hipLaunchKernelGGL(transpose_w_kernel, dim3(1024), dim3(256), 0, stream, W_h,   Wt_h,   256, 256, 3);
    hipLaunchKernelGGL(transpose_w_kernel, dim3(1024), dim3(256), 0, stream, SW_h,  SWt_h,  256, 256, 3);
    hipLaunchKernelGGL(cvt_x_kernel, dim3(4096), dim3(256), 0, stream, x, x_bf, N);

    hipMemsetAsync(cnt, 0, (size_t)N * sizeof(int), stream);
    hipLaunchKernelGGL(hist_kernel, dim3(4096), dim3(256), 0, stream, edst, cnt, n_edges);
    hipLaunchKernelGGL(scan_kernel, dim3(1), dim3(1024), 0, stream, cnt, row_ptr, heads, N);
    hipLaunchKernelGGL(scatter_kernel, dim3(4096), dim3(256), 0, stream,
                       esrc, edst, ew, heads, meta, n_edges);

    dim3 oblock(256);
    dim3 ogrid((N + 127) / 128);

    hipLaunchKernelGGL(outproj_kernel, ogrid, oblock, 0, stream,
                       x_bf, 512, 500, Wc, bc, out, N, 1);

    // ---- j = 0 ----
    run_gc(x_bf, 512, Wt_in, SWt_in, b_in, g_in, be_in,
           row_ptr, meta, S_bf, H1bf, stats, N, stream);
    hipLaunchKernelGGL(outproj_kernel, ogrid, oblock, 0, stream,
                       H1bf, 256, 256, Wc + (size_t)500 * 40, bc, out, N, 2);

    // ---- j = 1 ----
    run_gc(x_bf, 512, Wt_in + (size_t)1 * 256 * 512, SWt_in + (size_t)1 * 256 * 512,
           b_in + 256, g_in + 256, be_in + 256,
           row_ptr, meta, S_bf, H1bf, stats, N, stream);
    run_gc(H1bf, 256, Wt_h, SWt_h, b_h, g_h, be_h,
           row_ptr, meta, S_bf, H2bf, stats, N, stream);
    hipLaunchKernelGGL(outproj_kernel, ogrid, oblock, 0, stream,
                       H2bf, 256, 256, Wc + (size_t)756 * 40, bc, out, N, 2);

    // ---- j = 2 ----
    run_gc(x_bf, 512, Wt_in + (size_t)2 * 256 * 512, SWt_in + (size_t)2 * 256 * 512,
           b_in + 512, g_in + 512, be_in + 512,
           row_ptr, meta, S_bf, H1bf, stats, N, stream);
    run_gc(H1bf, 256, Wt_h + (size_t)1 * 256 * 256, SWt_h + (size_t)1 * 256 * 256,
           b_h + 256, g_h + 256, be_h + 256,
           row_ptr, meta, S_bf, H2bf, stats, N, stream);
    run_gc(H2bf, 256, Wt_h + (size_t)2 * 256 * 256, SWt_h + (size_t)2 * 256 * 256,
           b_h + 512, g_h + 512, be_h + 512,
           row_ptr, meta, S_bf, H1bf, stats, N, stream);
    hipLaunchKernelGGL(outproj_kernel, ogrid, oblock, 0, stream,
                       H1bf, 256, 256, Wc + (size_t)1012 * 40, bc, out, N, 2);
}

// Round 5
// 3346.944 us; speedup vs baseline: 22.3473x; 1.2440x over previous
//
#include <hip/hip_runtime.h>

typedef __attribute__((ext_vector_type(8))) short bf16x8;
typedef __attribute__((ext_vector_type(4))) float f32x4;
typedef __attribute__((ext_vector_type(4))) unsigned short u16x4;
typedef __attribute__((ext_vector_type(8))) unsigned short u16x8;

__device__ __forceinline__ float bf2f(unsigned short u) {
    union { unsigned int i; float f; } v; v.i = ((unsigned int)u) << 16; return v.f;
}
__device__ __forceinline__ unsigned short f2bf(float f) {
    union { float f; unsigned int i; } v; v.f = f;
    unsigned int b = v.i;
    b += 0x7FFFu + ((b >> 16) & 1u);   // round-to-nearest-even
    return (unsigned short)(b >> 16);
}

// ---------------- fused weight transpose: W,SW [L][K][256] -> Wf[L][256][2*Kp] bf16 ----------------
// Wf[l][c][k] = W[l][k][c] for k<Kp (0-padded K..Kp), = SW[l][k-Kp][c] for k>=Kp.
__global__ __launch_bounds__(256) void transpose_fused_kernel(
    const float* __restrict__ W, const float* __restrict__ SW,
    unsigned short* __restrict__ Wf, int K, int Kp, int L)
{
    long long total = (long long)L * 256 * 2 * Kp;
    long long idx = (long long)blockIdx.x * blockDim.x + threadIdx.x;
    const long long stride = (long long)gridDim.x * blockDim.x;
    for (; idx < total; idx += stride) {
        int l = (int)(idx / ((long long)256 * 2 * Kp));
        long long rem = idx - (long long)l * 256 * 2 * Kp;
        int c = (int)(rem / (2 * Kp));
        int kk = (int)(rem - (long long)c * 2 * Kp);
        const float* src = (kk < Kp) ? W : SW;
        int k = (kk < Kp) ? kk : kk - Kp;
        float v = (k < K) ? src[((size_t)l * K + k) * 256 + c] : 0.f;
        Wf[idx] = f2bf(v);
    }
}

// ---------------- fused cvt_x + outproj: writes x_bf[N,512] and out = x@Wc[0:500] + bc ----------------
__global__ __launch_bounds__(256) void cvtx_outproj_kernel(
    const float* __restrict__ X, unsigned short* __restrict__ Xb,
    const float* __restrict__ Wc, const float* __restrict__ bc,
    float* __restrict__ out, int N)
{
    __shared__ float As[32][128];
    __shared__ float Ws[32][40];
    const int tid = threadIdx.x;
    const int tx = tid & 7;
    const int ty = tid >> 3;
    const long long bm = (long long)blockIdx.x * 128;

    float acc[4][5];
#pragma unroll
    for (int r = 0; r < 4; ++r)
#pragma unroll
        for (int c = 0; c < 5; ++c) acc[r][c] = 0.f;

    const int lr = tid >> 1;
    const int ks = (tid & 1) * 16;

    for (int k0 = 0; k0 < 512; k0 += 32) {
        long long r = bm + lr;
        float v[16];
#pragma unroll
        for (int j = 0; j < 16; ++j) v[j] = 0.f;
        if (r < N) {
#pragma unroll
            for (int c4 = 0; c4 < 4; ++c4) {
                int gk = k0 + ks + c4 * 4;
                if (gk < 500) {
                    float4 q = *reinterpret_cast<const float4*>(X + (size_t)r * 500 + gk);
                    v[c4 * 4 + 0] = q.x; v[c4 * 4 + 1] = q.y;
                    v[c4 * 4 + 2] = q.z; v[c4 * 4 + 3] = q.w;
                }
            }
        }
#pragma unroll
        for (int j = 0; j < 16; ++j) As[ks + j][lr] = v[j];
        if (r < N) {
            u16x8 o0, o1;
#pragma unroll
            for (int j = 0; j < 8; ++j) { o0[j] = f2bf(v[j]); o1[j] = f2bf(v[8 + j]); }
            unsigned short* xp = Xb + (size_t)r * 512 + k0 + ks;
            *reinterpret_cast<u16x8*>(xp) = o0;
            *reinterpret_cast<u16x8*>(xp + 8) = o1;
        }
#pragma unroll
        for (int j = 0; j < 5; ++j) {
            int idx = tid * 5 + j;
            int kk = idx / 40;
            int c = idx - kk * 40;
            int gk = k0 + kk;
            Ws[kk][c] = (gk < 500) ? Wc[(size_t)gk * 40 + c] : 0.f;
        }
        __syncthreads();
#pragma unroll 8
        for (int kk = 0; kk < 32; ++kk) {
            float a[4], w[5];
#pragma unroll
            for (int r2 = 0; r2 < 4; ++r2) a[r2] = As[kk][ty * 4 + r2];
#pragma unroll
            for (int c = 0; c < 5; ++c) w[c] = Ws[kk][tx * 5 + c];
#pragma unroll
            for (int r2 = 0; r2 < 4; ++r2)
#pragma unroll
                for (int c = 0; c < 5; ++c) acc[r2][c] = fmaf(a[r2], w[c], acc[r2][c]);
        }
        __syncthreads();
    }

#pragma unroll
    for (int r = 0; r < 4; ++r) {
        long long grow = bm + ty * 4 + r;
        if (grow >= N) continue;
#pragma unroll
        for (int c = 0; c < 5; ++c) {
            int gcol = tx * 5 + c;
            out[grow * 40 + gcol] = acc[r][c] + bc[gcol];
        }
    }
}

// ---------------- CSR build ----------------
__global__ __launch_bounds__(256) void hist_kernel(
    const int* __restrict__ edst, int* __restrict__ cnt, int n_edges)
{
    int idx = blockIdx.x * blockDim.x + threadIdx.x;
    const int stride = gridDim.x * blockDim.x;
    for (; idx < n_edges; idx += stride) atomicAdd(&cnt[edst[idx]], 1);
}

__global__ __launch_bounds__(1024) void scan_kernel(
    const int* __restrict__ cnt, int* __restrict__ row_ptr,
    int* __restrict__ heads, int n)
{
    __shared__ int sums[1024];
    const int tid = threadIdx.x;
    const int per = (n + 1023) >> 10;
    const int start = tid * per;
    const int end = min(start + per, n);
    int local = 0;
    for (int i = start; i < end; ++i) local += cnt[i];
    sums[tid] = local;
    __syncthreads();
    for (int off = 1; off < 1024; off <<= 1) {
        int v = sums[tid];
        if (tid >= off) v += sums[tid - off];
        __syncthreads();
        sums[tid] = v;
        __syncthreads();
    }
    int run = sums[tid] - local;
    for (int i = start; i < end; ++i) {
        row_ptr[i] = run;
        heads[i] = run;
        run += cnt[i];
    }
    if (tid == 1023) row_ptr[n] = sums[1023];
}

__global__ __launch_bounds__(256) void scatter_kernel(
    const int* __restrict__ esrc, const int* __restrict__ edst,
    const float* __restrict__ ew, int* __restrict__ heads,
    int2* __restrict__ meta, int n_edges)
{
    int idx = blockIdx.x * blockDim.x + threadIdx.x;
    const int stride = gridDim.x * blockDim.x;
    for (; idx < n_edges; idx += stride) {
        int d = edst[idx];
        int pos = atomicAdd(&heads[d], 1);
        meta[pos] = make_int2(esrc[idx], __float_as_int(ew[idx]));
    }
}

// ---------------- SpMM 256-wide: O[dst] = sum_e w * S[src], fresh write ----------------
__global__ __launch_bounds__(256) void spmm256_kernel(
    const int* __restrict__ row_ptr, const int2* __restrict__ meta,
    const unsigned short* __restrict__ S, unsigned short* __restrict__ O, int N)
{
    const int wave = threadIdx.x >> 6;
    const int lane = threadIdx.x & 63;
    int node = blockIdx.x * 4 + wave;
    if (node >= N) return;
    node = __builtin_amdgcn_readfirstlane(node);
    const int beg = row_ptr[node];
    const int end = row_ptr[node + 1];
    float a0 = 0.f, a1 = 0.f, a2 = 0.f, a3 = 0.f;

    int e = beg;
    for (; e + 8 <= end; e += 8) {
        int2 m[8];
#pragma unroll
        for (int j = 0; j < 8; ++j) m[j] = meta[e + j];
        u16x4 v[8];
#pragma unroll
        for (int j = 0; j < 8; ++j)
            v[j] = *reinterpret_cast<const u16x4*>(S + (size_t)m[j].x * 256 + lane * 4);
#pragma unroll
        for (int j = 0; j < 8; ++j) {
            float w = __int_as_float(m[j].y);
            a0 = fmaf(w, bf2f(v[j][0]), a0);
            a1 = fmaf(w, bf2f(v[j][1]), a1);
            a2 = fmaf(w, bf2f(v[j][2]), a2);
            a3 = fmaf(w, bf2f(v[j][3]), a3);
        }
    }
    for (; e < end; ++e) {
        int2 m = meta[e];
        float w = __int_as_float(m.y);
        u16x4 v = *reinterpret_cast<const u16x4*>(S + (size_t)m.x * 256 + lane * 4);
        a0 = fmaf(w, bf2f(v[0]), a0);
        a1 = fmaf(w, bf2f(v[1]), a1);
        a2 = fmaf(w, bf2f(v[2]), a2);
        a3 = fmaf(w, bf2f(v[3]), a3);
    }
    u16x4 o;
    o[0] = f2bf(a0); o[1] = f2bf(a1); o[2] = f2bf(a2); o[3] = f2bf(a3);
    *reinterpret_cast<u16x4*>(O + (size_t)node * 256 + lane * 4) = o;
}

// ---------------- SpMM 512-wide (for Xa = A @ x_bf) ----------------
__global__ __launch_bounds__(256) void spmm512_kernel(
    const int* __restrict__ row_ptr, const int2* __restrict__ meta,
    const unsigned short* __restrict__ S, unsigned short* __restrict__ O, int N)
{
    const int wave = threadIdx.x >> 6;
    const int lane = threadIdx.x & 63;
    int node = blockIdx.x * 4 + wave;
    if (node >= N) return;
    node = __builtin_amdgcn_readfirstlane(node);
    const int beg = row_ptr[node];
    const int end = row_ptr[node + 1];
    const int coff = lane * 8;
    float a[8];
#pragma unroll
    for (int i = 0; i < 8; ++i) a[i] = 0.f;

    int e = beg;
    for (; e + 4 <= end; e += 4) {
        int2 m[4];
#pragma unroll
        for (int j = 0; j < 4; ++j) m[j] = meta[e + j];
        u16x8 v[4];
#pragma unroll
        for (int j = 0; j < 4; ++j)
            v[j] = *reinterpret_cast<const u16x8*>(S + (size_t)m[j].x * 512 + coff);
#pragma unroll
        for (int j = 0; j < 4; ++j) {
            float w = __int_as_float(m[j].y);
#pragma unroll
            for (int i = 0; i < 8; ++i) a[i] = fmaf(w, bf2f(v[j][i]), a[i]);
        }
    }
    for (; e < end; ++e) {
        int2 m = meta[e];
        float w = __int_as_float(m.y);
        u16x8 v = *reinterpret_cast<const u16x8*>(S + (size_t)m.x * 512 + coff);
#pragma unroll
        for (int i = 0; i < 8; ++i) a[i] = fmaf(w, bf2f(v[i]), a[i]);
    }
    u16x8 o;
#pragma unroll
    for (int i = 0; i < 8; ++i) o[i] = f2bf(a[i]);
    *reinterpret_cast<u16x8*>(O + (size_t)node * 512 + coff) = o;
}

// ---------------- fused MFMA GEMM: C[N,256] = [A1|A2] @ Btf^T + bias, + BN column stats ----------------
// A1:[N,K1], A2:[N,K2] bf16; Btf: [256][K1+K2] bf16. Tile 128x256, 4 waves.
__global__ __launch_bounds__(256) void gemm_fused_kernel(
    const unsigned short* __restrict__ A1, const unsigned short* __restrict__ A2,
    const unsigned short* __restrict__ Btf, const float* __restrict__ bias,
    unsigned short* __restrict__ Cout, float* __restrict__ stats,
    int N, int K1, int K2)
{
    const int lane = threadIdx.x & 63;
    const int wave = threadIdx.x >> 6;
    const int l16 = lane & 15;
    const int khi = lane >> 4;
    const long long bm = (long long)blockIdx.x * 128;
    const int col0 = wave * 64;
    const int KT = K1 + K2;

    f32x4 acc[2][4][4];
#pragma unroll
    for (int t = 0; t < 2; ++t)
#pragma unroll
        for (int m = 0; m < 4; ++m)
#pragma unroll
            for (int n = 0; n < 4; ++n) acc[t][m][n] = (f32x4){0.f, 0.f, 0.f, 0.f};

    const unsigned short* bp[4];
#pragma unroll
    for (int n = 0; n < 4; ++n)
        bp[n] = Btf + (size_t)(col0 + n * 16 + l16) * KT + khi * 8;

    // ---- segment 1: A1, k in [0,K1) ----
    {
        const unsigned short* ap[2][4];
#pragma unroll
        for (int t = 0; t < 2; ++t)
#pragma unroll
            for (int m = 0; m < 4; ++m) {
                long long r = bm + t * 64 + m * 16 + l16;
                if (r >= N) r = 0;
                ap[t][m] = A1 + (size_t)r * K1 + khi * 8;
            }
        for (int k0 = 0; k0 < K1; k0 += 32) {
            bf16x8 b[4];
#pragma unroll
            for (int n = 0; n < 4; ++n) b[n] = *reinterpret_cast<const bf16x8*>(bp[n] + k0);
            bf16x8 a[2][4];
#pragma unroll
            for (int t = 0; t < 2; ++t)
#pragma unroll
                for (int m = 0; m < 4; ++m) a[t][m] = *reinterpret_cast<const bf16x8*>(ap[t][m] + k0);
#pragma unroll
            for (int t = 0; t < 2; ++t)
#pragma unroll
                for (int m = 0; m < 4; ++m)
#pragma unroll
                    for (int n = 0; n < 4; ++n)
                        acc[t][m][n] = __builtin_amdgcn_mfma_f32_16x16x32_bf16(a[t][m], b[n], acc[t][m][n], 0, 0, 0);
        }
    }
    // ---- segment 2: A2, k in [K1, K1+K2) ----
    {
        const unsigned short* ap[2][4];
#pragma unroll
        for (int t = 0; t < 2; ++t)
#pragma unroll
            for (int m = 0; m < 4; ++m) {
                long long r = bm + t * 64 + m * 16 + l16;
                if (r >= N) r = 0;
                ap[t][m] = A2 + (size_t)r * K2 + khi * 8;
            }
        for (int k0 = 0; k0 < K2; k0 += 32) {
            bf16x8 b[4];
#pragma unroll
            for (int n = 0; n < 4; ++n) b[n] = *reinterpret_cast<const bf16x8*>(bp[n] + K1 + k0);
            bf16x8 a[2][4];
#pragma unroll
            for (int t = 0; t < 2; ++t)
#pragma unroll
                for (int m = 0; m < 4; ++m) a[t][m] = *reinterpret_cast<const bf16x8*>(ap[t][m] + k0);
#pragma unroll
            for (int t = 0; t < 2; ++t)
#pragma unroll
                for (int m = 0; m < 4; ++m)
#pragma unroll
                    for (int n = 0; n < 4; ++n)
                        acc[t][m][n] = __builtin_amdgcn_mfma_f32_16x16x32_bf16(a[t][m], b[n], acc[t][m][n], 0, 0, 0);
        }
    }

    float bs[4];
#pragma unroll
    for (int n = 0; n < 4; ++n) bs[n] = bias[col0 + n * 16 + l16];

    float s[4], s2[4];
#pragma unroll
    for (int n = 0; n < 4; ++n) { s[n] = 0.f; s2[n] = 0.f; }

#pragma unroll
    for (int t = 0; t < 2; ++t)
#pragma unroll
        for (int m = 0; m < 4; ++m)
#pragma unroll
            for (int r = 0; r < 4; ++r) {
                long long grow = bm + t * 64 + m * 16 + khi * 4 + r;
                if (grow >= N) continue;
#pragma unroll
                for (int n = 0; n < 4; ++n) {
                    int gcol = col0 + n * 16 + l16;
                    float v = acc[t][m][n][r] + bs[n];
                    Cout[grow * 256 + gcol] = f2bf(v);
                    s[n] += v;
                    s2[n] = fmaf(v, v, s2[n]);
                }
            }

    // reduce (sum, sumsq) across the 4 khi lanes sharing each column, then atomics
#pragma unroll
    for (int n = 0; n < 4; ++n) {
        float a = s[n], b2 = s2[n];
        a += __shfl_xor(a, 16); a += __shfl_xor(a, 32);
        b2 += __shfl_xor(b2, 16); b2 += __shfl_xor(b2, 32);
        if (khi == 0) {
            int c = col0 + n * 16 + l16;
            atomicAdd(&stats[c], a);
            atomicAdd(&stats[256 + c], b2);
        }
    }
}

// ---------------- BN finalize: stats -> (scale, shift) in kp ----------------
__global__ __launch_bounds__(256) void bn_finalize_kernel(
    const float* __restrict__ sums, const float* __restrict__ g,
    const float* __restrict__ be, float* __restrict__ kp, int N)
{
    const int c = threadIdx.x;
    float invN = 1.f / (float)N;
    float mean = sums[c] * invN;
    float var = sums[256 + c] * invN - mean * mean;
    float inv = rsqrtf(var + 1e-5f);
    float sc = g[c] * inv;
    kp[c] = sc;
    kp[256 + c] = be[c] - sc * mean;
}

// ---------------- BN apply + ReLU in place (intermediate features) ----------------
__global__ __launch_bounds__(256) void bn_apply_kernel(
    unsigned short* __restrict__ X, const float* __restrict__ kp, long long n4)
{
    long long idx = (long long)blockIdx.x * blockDim.x + threadIdx.x;
    const long long stride = (long long)gridDim.x * blockDim.x;
    for (; idx < n4; idx += stride) {
        int c4 = (int)(idx & 63);
        u16x4 v = reinterpret_cast<u16x4*>(X)[idx];
        f32x4 s = reinterpret_cast<const f32x4*>(kp)[c4];
        f32x4 t = reinterpret_cast<const f32x4*>(kp + 256)[c4];
#pragma unroll
        for (int i = 0; i < 4; ++i) {
            float f = fmaxf(fmaf(bf2f(v[i]), s[i], t[i]), 0.f);
            v[i] = f2bf(f);
        }
        reinterpret_cast<u16x4*>(X)[idx] = v;
    }
}

// ---------------- fused BN apply + outproj (final features; no H writeback) ----------------
// out[N,40] += relu(bn(H)) @ Wc_chunk[256,40]
__global__ __launch_bounds__(256) void bnapply_outproj_kernel(
    const unsigned short* __restrict__ H, const float* __restrict__ kp,
    const float* __restrict__ Wc, float* __restrict__ out, int N)
{
    __shared__ float As[32][128];
    __shared__ float Ws[32][40];
    const int tid = threadIdx.x;
    const int tx = tid & 7;
    const int ty = tid >> 3;
    const long long bm = (long long)blockIdx.x * 128;

    float acc[4][5];
#pragma unroll
    for (int r = 0; r < 4; ++r)
#pragma unroll
        for (int c = 0; c < 5; ++c) acc[r][c] = 0.f;

    const int lr = tid >> 1;
    const int ks = (tid & 1) * 16;

    for (int k0 = 0; k0 < 256; k0 += 32) {
        {
            long long r = bm + lr;
            u16x8 t0 = (u16x8)0, t1 = (u16x8)0;
            if (r < N) {
                const unsigned short* p = H + (size_t)r * 256 + k0 + ks;
                t0 = *reinterpret_cast<const u16x8*>(p);
                t1 = *reinterpret_cast<const u16x8*>(p + 8);
            }
#pragma unroll
            for (int j = 0; j < 8; ++j) {
                int c0 = k0 + ks + j;
                int c1 = k0 + ks + 8 + j;
                As[ks + j][lr]     = fmaxf(fmaf(bf2f(t0[j]), kp[c0], kp[256 + c0]), 0.f);
                As[ks + 8 + j][lr] = fmaxf(fmaf(bf2f(t1[j]), kp[c1], kp[256 + c1]), 0.f);
            }
        }
#pragma unroll
        for (int j = 0; j < 5; ++j) {
            int idx = tid * 5 + j;
            int kk = idx / 40;
            int c = idx - kk * 40;
            Ws[kk][c] = Wc[(size_t)(k0 + kk) * 40 + c];
        }
        __syncthreads();
#pragma unroll 8
        for (int kk = 0; kk < 32; ++kk) {
            float a[4], w[5];
#pragma unroll
            for (int r = 0; r < 4; ++r) a[r] = As[kk][ty * 4 + r];
#pragma unroll
            for (int c = 0; c < 5; ++c) w[c] = Ws[kk][tx * 5 + c];
#pragma unroll
            for (int r = 0; r < 4; ++r)
#pragma unroll
                for (int c = 0; c < 5; ++c) acc[r][c] = fmaf(a[r], w[c], acc[r][c]);
        }
        __syncthreads();
    }

#pragma unroll
    for (int r = 0; r < 4; ++r) {
        long long grow = bm + ty * 4 + r;
        if (grow >= N) continue;
#pragma unroll
        for (int c = 0; c < 5; ++c) {
            int gcol = tx * 5 + c;
            out[grow * 40 + gcol] += acc[r][c];
        }
    }
}

// ---------------- host-side orchestration ----------------
extern "C" void kernel_launch(void* const* d_in, const int* in_sizes, int n_in,
                              void* d_out, int out_size, void* d_ws, size_t ws_size,
                              hipStream_t stream)
{
    const float* x      = (const float*)d_in[0];
    const int*   esrc   = (const int*)d_in[1];
    const int*   edst   = (const int*)d_in[2];
    const float* ew     = (const float*)d_in[3];
    const float* W_in   = (const float*)d_in[4];
    const float* SW_in  = (const float*)d_in[5];
    const float* b_in   = (const float*)d_in[6];
    const float* g_in   = (const float*)d_in[7];
    const float* be_in  = (const float*)d_in[8];
    const float* W_h    = (const float*)d_in[9];
    const float* SW_h   = (const float*)d_in[10];
    const float* b_h    = (const float*)d_in[11];
    const float* g_h    = (const float*)d_in[12];
    const float* be_h   = (const float*)d_in[13];
    const float* Wc     = (const float*)d_in[14];
    const float* bc     = (const float*)d_in[15];
    float* out = (float*)d_out;

    const int N = in_sizes[0] / 500;      // 100000
    const int n_edges = in_sizes[1];      // 3200000

    // ---- workspace layout ----
    char* p = (char*)d_ws;
    unsigned short* x_bf = (unsigned short*)p; p += (size_t)N * 512 * 2;        // 102.4 MB
    unsigned short* Xa   = (unsigned short*)p; p += (size_t)N * 512 * 2;        // 102.4 MB
    unsigned short* Ha   = (unsigned short*)p; p += (size_t)N * 256 * 2;        // 51.2 MB
    unsigned short* H1   = (unsigned short*)p; p += (size_t)N * 256 * 2;
    unsigned short* H2   = (unsigned short*)p; p += (size_t)N * 256 * 2;
    unsigned short* Wf_in = (unsigned short*)p; p += (size_t)3 * 256 * 1024 * 2; // [3][256][1024]
    unsigned short* Wf_h  = (unsigned short*)p; p += (size_t)3 * 256 * 512 * 2;  // [3][256][512]
    float* stats = (float*)p; p += (size_t)6 * 1024 * 4;                         // 6 slots x (512 sums + 512 kp)
    int* cnt     = (int*)p; p += (size_t)N * 4;
    int* row_ptr = (int*)p; p += (size_t)(N + 1) * 4 + 4;
    int* heads   = (int*)p; p += (size_t)N * 4;
    int2* meta   = (int2*)p;

    // ---- preprocessing ----
    hipMemsetAsync(stats, 0, 6 * 1024 * sizeof(float), stream);
    hipLaunchKernelGGL(transpose_fused_kernel, dim3(2048), dim3(256), 0, stream,
                       W_in, SW_in, Wf_in, 500, 512, 3);
    hipLaunchKernelGGL(transpose_fused_kernel, dim3(1024), dim3(256), 0, stream,
                       W_h, SW_h, Wf_h, 256, 256, 3);

    hipMemsetAsync(cnt, 0, (size_t)N * sizeof(int), stream);
    hipLaunchKernelGGL(hist_kernel, dim3(4096), dim3(256), 0, stream, edst, cnt, n_edges);
    hipLaunchKernelGGL(scan_kernel, dim3(1), dim3(1024), 0, stream, cnt, row_ptr, heads, N);
    hipLaunchKernelGGL(scatter_kernel, dim3(4096), dim3(256), 0, stream,
                       esrc, edst, ew, heads, meta, n_edges);

    dim3 oblock(256);
    dim3 ogrid((N + 127) / 128);

    // x -> x_bf  AND  out = x @ Wc[0:500] + bc
    hipLaunchKernelGGL(cvtx_outproj_kernel, ogrid, oblock, 0, stream,
                       x, x_bf, Wc, bc, out, N);

    // Xa = A @ x_bf  (shared across all 3 input layers)
    hipLaunchKernelGGL(spmm512_kernel, dim3((N + 3) / 4), dim3(256), 0, stream,
                       row_ptr, meta, x_bf, Xa, N);

    dim3 ggrid((N + 127) / 128);
    float* st;

    // ---- j = 0: input GC -> H1 (final feature) ----
    st = stats + 0 * 1024;
    hipLaunchKernelGGL(gemm_fused_kernel, ggrid, oblock, 0, stream,
                       Xa, x_bf, Wf_in, b_in, H1, st, N, 512, 512);
    hipLaunchKernelGGL(bn_finalize_kernel, dim3(1), dim3(256), 0, stream, st, g_in, be_in, st + 512, N);
    hipLaunchKernelGGL(bnapply_outproj_kernel, ogrid, oblock, 0, stream,
                       H1, st + 512, Wc + (size_t)500 * 40, out, N);

    // ---- j = 1: input GC -> H1 (intermediate), hidden GC -> H2 (final) ----
    st = stats + 1 * 1024;
    hipLaunchKernelGGL(gemm_fused_kernel, ggrid, oblock, 0, stream,
                       Xa, x_bf, Wf_in + (size_t)1 * 256 * 1024, b_in + 256, H1, st, N, 512, 512);
    hipLaunchKernelGGL(bn_finalize_kernel, dim3(1), dim3(256), 0, stream, st, g_in + 256, be_in + 256, st + 512, N);
    hipLaunchKernelGGL(bn_apply_kernel, dim3(2048), dim3(256), 0, stream, H1, st + 512, (long long)N * 64);

    hipLaunchKernelGGL(spmm256_kernel, dim3((N + 3) / 4), dim3(256), 0, stream,
                       row_ptr, meta, H1, Ha, N);
    st = stats + 2 * 1024;
    hipLaunchKernelGGL(gemm_fused_kernel, ggrid, oblock, 0, stream,
                       Ha, H1, Wf_h, b_h, H2, st, N, 256, 256);
    hipLaunchKernelGGL(bn_finalize_kernel, dim3(1), dim3(256), 0, stream, st, g_h, be_h, st + 512, N);
    hipLaunchKernelGGL(bnapply_outproj_kernel, ogrid, oblock, 0, stream,
                       H2, st + 512, Wc + (size_t)756 * 40, out, N);

    // ---- j = 2: input GC -> H1, hidden GC -> H2, hidden GC -> H1 (final) ----
    st = stats + 3 * 1024;
    hipLaunchKernelGGL(gemm_fused_kernel, ggrid, oblock, 0, stream,
                       Xa, x_bf, Wf_in + (size_t)2 * 256 * 1024, b_in + 512, H1, st, N, 512, 512);
    hipLaunchKernelGGL(bn_finalize_kernel, dim3(1), dim3(256), 0, stream, st, g_in + 512, be_in + 512, st + 512, N);
    hipLaunchKernelGGL(bn_apply_kernel, dim3(2048), dim3(256), 0, stream, H1, st + 512, (long long)N * 64);

    hipLaunchKernelGGL(spmm256_kernel, dim3((N + 3) / 4), dim3(256), 0, stream,
                       row_ptr, meta, H1, Ha, N);
    st = stats + 4 * 1024;
    hipLaunchKernelGGL(gemm_fused_kernel, ggrid, oblock, 0, stream,
                       Ha, H1, Wf_h + (size_t)1 * 256 * 512, b_h + 256, H2, st, N, 256, 256);
    hipLaunchKernelGGL(bn_finalize_kernel, dim3(1), dim3(256), 0, stream, st, g_h + 256, be_h + 256, st + 512, N);
    hipLaunchKernelGGL(bn_apply_kernel, dim3(2048), dim3(256), 0, stream, H2, st + 512, (long long)N * 64);

    hipLaunchKernelGGL(spmm256_kernel, dim3((N + 3) / 4), dim3(256), 0, stream,
                       row_ptr, meta, H2, Ha, N);
    st = stats + 5 * 1024;
    hipLaunchKernelGGL(gemm_fused_kernel, ggrid, oblock, 0, stream,
                       Ha, H2, Wf_h + (size_t)2 * 256 * 512, b_h + 512, H1, st, N, 256, 256);
    hipLaunchKernelGGL(bn_finalize_kernel, dim3(1), dim3(256), 0, stream, st, g_h + 512, be_h + 512, st + 512, N);
    hipLaunchKernelGGL(bnapply_outproj_kernel, ogrid, oblock, 0, stream,
                       H1, st + 512, Wc + (size_t)1012 * 40, out, N);
}

// Round 6
// 3244.840 us; speedup vs baseline: 23.0505x; 1.0315x over previous
//
#include <hip/hip_runtime.h>

typedef __attribute__((ext_vector_type(8))) short bf16x8;
typedef __attribute__((ext_vector_type(4))) float f32x4;
typedef __attribute__((ext_vector_type(4))) unsigned short u16x4;
typedef __attribute__((ext_vector_type(8))) unsigned short u16x8;

__device__ __forceinline__ float bf2f(unsigned short u) {
    union { unsigned int i; float f; } v; v.i = ((unsigned int)u) << 16; return v.f;
}
__device__ __forceinline__ unsigned short f2bf(float f) {
    union { float f; unsigned int i; } v; v.f = f;
    unsigned int b = v.i;
    b += 0x7FFFu + ((b >> 16) & 1u);   // round-to-nearest-even
    return (unsigned short)(b >> 16);
}

// ---------------- fused weight transpose: W,SW [L][K][256] -> Wf[L][256][2*Kp] bf16 ----------------
__global__ __launch_bounds__(256) void transpose_fused_kernel(
    const float* __restrict__ W, const float* __restrict__ SW,
    unsigned short* __restrict__ Wf, int K, int Kp, int L)
{
    long long total = (long long)L * 256 * 2 * Kp;
    long long idx = (long long)blockIdx.x * blockDim.x + threadIdx.x;
    const long long stride = (long long)gridDim.x * blockDim.x;
    for (; idx < total; idx += stride) {
        int l = (int)(idx / ((long long)256 * 2 * Kp));
        long long rem = idx - (long long)l * 256 * 2 * Kp;
        int c = (int)(rem / (2 * Kp));
        int kk = (int)(rem - (long long)c * 2 * Kp);
        const float* src = (kk < Kp) ? W : SW;
        int k = (kk < Kp) ? kk : kk - Kp;
        float v = (k < K) ? src[((size_t)l * K + k) * 256 + c] : 0.f;
        Wf[idx] = f2bf(v);
    }
}

// ---------------- Wc[1268][40] fp32 -> Wcb[48][1280] bf16 (segment-mapped, padded) ----------------
__global__ __launch_bounds__(256) void transpose_wc_kernel(
    const float* __restrict__ Wc, unsigned short* __restrict__ Wcb)
{
    int idx = blockIdx.x * blockDim.x + threadIdx.x;
    if (idx >= 48 * 1280) return;
    int c = idx / 1280;
    int kk = idx - c * 1280;
    int src = -1;
    if (kk < 512)       { if (kk < 500) src = kk; }
    else if (kk < 768)  src = 500 + (kk - 512);
    else if (kk < 1024) src = 756 + (kk - 768);
    else                src = 1012 + (kk - 1024);
    float v = (c < 40 && src >= 0) ? Wc[(size_t)src * 40 + c] : 0.f;
    Wcb[idx] = f2bf(v);
}

// ---------------- x -> bf16 with pad 500->512 (streaming) ----------------
__global__ __launch_bounds__(256) void cvtx_kernel(
    const float* __restrict__ X, unsigned short* __restrict__ Xb, int N)
{
    long long total = (long long)N * 64;  // u16x8 groups
    long long idx = (long long)blockIdx.x * blockDim.x + threadIdx.x;
    const long long stride = (long long)gridDim.x * blockDim.x;
    for (; idx < total; idx += stride) {
        long long row = idx >> 6;
        int g = (int)(idx & 63);
        int k0 = g * 8;
        float v[8];
        if (k0 + 8 <= 500) {
            float4 q0 = *reinterpret_cast<const float4*>(X + row * 500 + k0);
            float4 q1 = *reinterpret_cast<const float4*>(X + row * 500 + k0 + 4);
            v[0] = q0.x; v[1] = q0.y; v[2] = q0.z; v[3] = q0.w;
            v[4] = q1.x; v[5] = q1.y; v[6] = q1.z; v[7] = q1.w;
        } else {
#pragma unroll
            for (int j = 0; j < 8; ++j) v[j] = (k0 + j < 500) ? X[row * 500 + k0 + j] : 0.f;
        }
        u16x8 o;
#pragma unroll
        for (int j = 0; j < 8; ++j) o[j] = f2bf(v[j]);
        *reinterpret_cast<u16x8*>(Xb + row * 512 + k0) = o;
    }
}

// ---------------- CSR build ----------------
__global__ __launch_bounds__(256) void hist_kernel(
    const int* __restrict__ edst, int* __restrict__ cnt, int n_edges)
{
    int idx = blockIdx.x * blockDim.x + threadIdx.x;
    const int stride = gridDim.x * blockDim.x;
    for (; idx < n_edges; idx += stride) atomicAdd(&cnt[edst[idx]], 1);
}

__global__ __launch_bounds__(1024) void scan_kernel(
    const int* __restrict__ cnt, int* __restrict__ row_ptr,
    int* __restrict__ heads, int n)
{
    __shared__ int sums[1024];
    const int tid = threadIdx.x;
    const int per = (n + 1023) >> 10;
    const int start = tid * per;
    const int end = min(start + per, n);
    int local = 0;
    for (int i = start; i < end; ++i) local += cnt[i];
    sums[tid] = local;
    __syncthreads();
    for (int off = 1; off < 1024; off <<= 1) {
        int v = sums[tid];
        if (tid >= off) v += sums[tid - off];
        __syncthreads();
        sums[tid] = v;
        __syncthreads();
    }
    int run = sums[tid] - local;
    for (int i = start; i < end; ++i) {
        row_ptr[i] = run;
        heads[i] = run;
        run += cnt[i];
    }
    if (tid == 1023) row_ptr[n] = sums[1023];
}

__global__ __launch_bounds__(256) void scatter_kernel(
    const int* __restrict__ esrc, const int* __restrict__ edst,
    const float* __restrict__ ew, int* __restrict__ heads,
    int2* __restrict__ meta, int n_edges)
{
    int idx = blockIdx.x * blockDim.x + threadIdx.x;
    const int stride = gridDim.x * blockDim.x;
    for (; idx < n_edges; idx += stride) {
        int d = edst[idx];
        int pos = atomicAdd(&heads[d], 1);
        meta[pos] = make_int2(esrc[idx], __float_as_int(ew[idx]));
    }
}

// ---------------- SpMM 256-wide ----------------
__global__ __launch_bounds__(256) void spmm256_kernel(
    const int* __restrict__ row_ptr, const int2* __restrict__ meta,
    const unsigned short* __restrict__ S, unsigned short* __restrict__ O, int N)
{
    const int wave = threadIdx.x >> 6;
    const int lane = threadIdx.x & 63;
    int node = blockIdx.x * 4 + wave;
    if (node >= N) return;
    node = __builtin_amdgcn_readfirstlane(node);
    const int beg = row_ptr[node];
    const int end = row_ptr[node + 1];
    float a0 = 0.f, a1 = 0.f, a2 = 0.f, a3 = 0.f;

    int e = beg;
    for (; e + 8 <= end; e += 8) {
        int2 m[8];
#pragma unroll
        for (int j = 0; j < 8; ++j) m[j] = meta[e + j];
        u16x4 v[8];
#pragma unroll
        for (int j = 0; j < 8; ++j)
            v[j] = *reinterpret_cast<const u16x4*>(S + (size_t)m[j].x * 256 + lane * 4);
#pragma unroll
        for (int j = 0; j < 8; ++j) {
            float w = __int_as_float(m[j].y);
            a0 = fmaf(w, bf2f(v[j][0]), a0);
            a1 = fmaf(w, bf2f(v[j][1]), a1);
            a2 = fmaf(w, bf2f(v[j][2]), a2);
            a3 = fmaf(w, bf2f(v[j][3]), a3);
        }
    }
    for (; e < end; ++e) {
        int2 m = meta[e];
        float w = __int_as_float(m.y);
        u16x4 v = *reinterpret_cast<const u16x4*>(S + (size_t)m.x * 256 + lane * 4);
        a0 = fmaf(w, bf2f(v[0]), a0);
        a1 = fmaf(w, bf2f(v[1]), a1);
        a2 = fmaf(w, bf2f(v[2]), a2);
        a3 = fmaf(w, bf2f(v[3]), a3);
    }
    u16x4 o;
    o[0] = f2bf(a0); o[1] = f2bf(a1); o[2] = f2bf(a2); o[3] = f2bf(a3);
    *reinterpret_cast<u16x4*>(O + (size_t)node * 256 + lane * 4) = o;
}

// ---------------- SpMM 512-wide ----------------
__global__ __launch_bounds__(256) void spmm512_kernel(
    const int* __restrict__ row_ptr, const int2* __restrict__ meta,
    const unsigned short* __restrict__ S, unsigned short* __restrict__ O, int N)
{
    const int wave = threadIdx.x >> 6;
    const int lane = threadIdx.x & 63;
    int node = blockIdx.x * 4 + wave;
    if (node >= N) return;
    node = __builtin_amdgcn_readfirstlane(node);
    const int beg = row_ptr[node];
    const int end = row_ptr[node + 1];
    const int coff = lane * 8;
    float a[8];
#pragma unroll
    for (int i = 0; i < 8; ++i) a[i] = 0.f;

    int e = beg;
    for (; e + 4 <= end; e += 4) {
        int2 m[4];
#pragma unroll
        for (int j = 0; j < 4; ++j) m[j] = meta[e + j];
        u16x8 v[4];
#pragma unroll
        for (int j = 0; j < 4; ++j)
            v[j] = *reinterpret_cast<const u16x8*>(S + (size_t)m[j].x * 512 + coff);
#pragma unroll
        for (int j = 0; j < 4; ++j) {
            float w = __int_as_float(m[j].y);
#pragma unroll
            for (int i = 0; i < 8; ++i) a[i] = fmaf(w, bf2f(v[j][i]), a[i]);
        }
    }
    for (; e < end; ++e) {
        int2 m = meta[e];
        float w = __int_as_float(m.y);
        u16x8 v = *reinterpret_cast<const u16x8*>(S + (size_t)m.x * 512 + coff);
#pragma unroll
        for (int i = 0; i < 8; ++i) a[i] = fmaf(w, bf2f(v[i]), a[i]);
    }
    u16x8 o;
#pragma unroll
    for (int i = 0; i < 8; ++i) o[i] = f2bf(a[i]);
    *reinterpret_cast<u16x8*>(O + (size_t)node * 512 + coff) = o;
}

// ---------------- fused MFMA GEMM (compile-time K): C = [A1|A2] @ Btf^T + bias, + BN stats ----------------
template<int K1, int K2>
__global__ __launch_bounds__(256) void gemm_fused_kernel(
    const unsigned short* __restrict__ A1, const unsigned short* __restrict__ A2,
    const unsigned short* __restrict__ Btf, const float* __restrict__ bias,
    unsigned short* __restrict__ Cout, float* __restrict__ stats, int N)
{
    const int lane = threadIdx.x & 63;
    const int wave = threadIdx.x >> 6;
    const int l16 = lane & 15;
    const int khi = lane >> 4;
    const long long bm = (long long)blockIdx.x * 128;
    const int col0 = wave * 64;
    constexpr int KT = K1 + K2;

    f32x4 acc[2][4][4];
#pragma unroll
    for (int t = 0; t < 2; ++t)
#pragma unroll
        for (int m = 0; m < 4; ++m)
#pragma unroll
            for (int n = 0; n < 4; ++n) acc[t][m][n] = (f32x4){0.f, 0.f, 0.f, 0.f};

    const unsigned short* bp[4];
#pragma unroll
    for (int n = 0; n < 4; ++n)
        bp[n] = Btf + (size_t)(col0 + n * 16 + l16) * KT + khi * 8;

    {
        const unsigned short* ap[2][4];
#pragma unroll
        for (int t = 0; t < 2; ++t)
#pragma unroll
            for (int m = 0; m < 4; ++m) {
                long long r = bm + t * 64 + m * 16 + l16;
                if (r >= N) r = 0;
                ap[t][m] = A1 + (size_t)r * K1 + khi * 8;
            }
        for (int k0 = 0; k0 < K1; k0 += 32) {
            bf16x8 b[4];
#pragma unroll
            for (int n = 0; n < 4; ++n) b[n] = *reinterpret_cast<const bf16x8*>(bp[n] + k0);
            bf16x8 a[2][4];
#pragma unroll
            for (int t = 0; t < 2; ++t)
#pragma unroll
                for (int m = 0; m < 4; ++m) a[t][m] = *reinterpret_cast<const bf16x8*>(ap[t][m] + k0);
#pragma unroll
            for (int t = 0; t < 2; ++t)
#pragma unroll
                for (int m = 0; m < 4; ++m)
#pragma unroll
                    for (int n = 0; n < 4; ++n)
                        acc[t][m][n] = __builtin_amdgcn_mfma_f32_16x16x32_bf16(a[t][m], b[n], acc[t][m][n], 0, 0, 0);
        }
    }
    {
        const unsigned short* ap[2][4];
#pragma unroll
        for (int t = 0; t < 2; ++t)
#pragma unroll
            for (int m = 0; m < 4; ++m) {
                long long r = bm + t * 64 + m * 16 + l16;
                if (r >= N) r = 0;
                ap[t][m] = A2 + (size_t)r * K2 + khi * 8;
            }
        for (int k0 = 0; k0 < K2; k0 += 32) {
            bf16x8 b[4];
#pragma unroll
            for (int n = 0; n < 4; ++n) b[n] = *reinterpret_cast<const bf16x8*>(bp[n] + K1 + k0);
            bf16x8 a[2][4];
#pragma unroll
            for (int t = 0; t < 2; ++t)
#pragma unroll
                for (int m = 0; m < 4; ++m) a[t][m] = *reinterpret_cast<const bf16x8*>(ap[t][m] + k0);
#pragma unroll
            for (int t = 0; t < 2; ++t)
#pragma unroll
                for (int m = 0; m < 4; ++m)
#pragma unroll
                    for (int n = 0; n < 4; ++n)
                        acc[t][m][n] = __builtin_amdgcn_mfma_f32_16x16x32_bf16(a[t][m], b[n], acc[t][m][n], 0, 0, 0);
        }
    }

    float bs[4];
#pragma unroll
    for (int n = 0; n < 4; ++n) bs[n] = bias[col0 + n * 16 + l16];

    float s[4], s2[4];
#pragma unroll
    for (int n = 0; n < 4; ++n) { s[n] = 0.f; s2[n] = 0.f; }

#pragma unroll
    for (int t = 0; t < 2; ++t)
#pragma unroll
        for (int m = 0; m < 4; ++m)
#pragma unroll
            for (int r = 0; r < 4; ++r) {
                long long grow = bm + t * 64 + m * 16 + khi * 4 + r;
                if (grow >= N) continue;
#pragma unroll
                for (int n = 0; n < 4; ++n) {
                    int gcol = col0 + n * 16 + l16;
                    float v = acc[t][m][n][r] + bs[n];
                    Cout[grow * 256 + gcol] = f2bf(v);
                    s[n] += v;
                    s2[n] = fmaf(v, v, s2[n]);
                }
            }

#pragma unroll
    for (int n = 0; n < 4; ++n) {
        float a = s[n], b2 = s2[n];
        a += __shfl_xor(a, 16); a += __shfl_xor(a, 32);
        b2 += __shfl_xor(b2, 16); b2 += __shfl_xor(b2, 32);
        if (khi == 0) {
            int c = col0 + n * 16 + l16;
            atomicAdd(&stats[c], a);
            atomicAdd(&stats[256 + c], b2);
        }
    }
}

// ---------------- BN finalize ----------------
__global__ __launch_bounds__(256) void bn_finalize_kernel(
    const float* __restrict__ sums, const float* __restrict__ g,
    const float* __restrict__ be, float* __restrict__ kp, int N)
{
    const int c = threadIdx.x;
    float invN = 1.f / (float)N;
    float mean = sums[c] * invN;
    float var = sums[256 + c] * invN - mean * mean;
    float inv = rsqrtf(var + 1e-5f);
    float sc = g[c] * inv;
    kp[c] = sc;
    kp[256 + c] = be[c] - sc * mean;
}

// ---------------- BN apply + ReLU in place (intermediate features) ----------------
__global__ __launch_bounds__(256) void bn_apply_kernel(
    unsigned short* __restrict__ X, const float* __restrict__ kp, long long n4)
{
    long long idx = (long long)blockIdx.x * blockDim.x + threadIdx.x;
    const long long stride = (long long)gridDim.x * blockDim.x;
    for (; idx < n4; idx += stride) {
        int c4 = (int)(idx & 63);
        u16x4 v = reinterpret_cast<u16x4*>(X)[idx];
        f32x4 s = reinterpret_cast<const f32x4*>(kp)[c4];
        f32x4 t = reinterpret_cast<const f32x4*>(kp + 256)[c4];
#pragma unroll
        for (int i = 0; i < 4; ++i) {
            float f = fmaxf(fmaf(bf2f(v[i]), s[i], t[i]), 0.f);
            v[i] = f2bf(f);
        }
        reinterpret_cast<u16x4*>(X)[idx] = v;
    }
}

// ---------------- final MFMA outproj: out[N,40] = [x|bn(F0)|bn(F1)|bn(F2)] @ Wcb^T + bc ----------------
// Wcb: [48][1280] bf16. Block 256 thr = 4 waves; wave handles 32 rows x 48 cols.
template<int KS, bool BN>
__device__ __forceinline__ void outproj_seg(
    const unsigned short* __restrict__ seg, const float* __restrict__ kp,
    const unsigned short* __restrict__ Wcb, int bOff,
    long long r0, long long r1, int l16, int khi, f32x4 acc[2][3])
{
    const unsigned short* a0p = seg + (size_t)r0 * KS + khi * 8;
    const unsigned short* a1p = seg + (size_t)r1 * KS + khi * 8;
#pragma unroll
    for (int k0 = 0; k0 < KS; k0 += 32) {
        bf16x8 a[2];
        a[0] = *reinterpret_cast<const bf16x8*>(a0p + k0);
        a[1] = *reinterpret_cast<const bf16x8*>(a1p + k0);
        if (BN) {
            int ch0 = k0 + khi * 8;
            f32x4 s0 = *reinterpret_cast<const f32x4*>(kp + ch0);
            f32x4 s1 = *reinterpret_cast<const f32x4*>(kp + ch0 + 4);
            f32x4 t0 = *reinterpret_cast<const f32x4*>(kp + 256 + ch0);
            f32x4 t1 = *reinterpret_cast<const f32x4*>(kp + 256 + ch0 + 4);
#pragma unroll
            for (int m = 0; m < 2; ++m) {
                u16x8 raw;
                __builtin_memcpy(&raw, &a[m], 16);
                u16x8 ov;
#pragma unroll
                for (int j = 0; j < 4; ++j) {
                    ov[j]     = f2bf(fmaxf(fmaf(bf2f(raw[j]),     s0[j], t0[j]), 0.f));
                    ov[4 + j] = f2bf(fmaxf(fmaf(bf2f(raw[4 + j]), s1[j], t1[j]), 0.f));
                }
                __builtin_memcpy(&a[m], &ov, 16);
            }
        }
        bf16x8 b[3];
#pragma unroll
        for (int nt = 0; nt < 3; ++nt)
            b[nt] = *reinterpret_cast<const bf16x8*>(Wcb + (size_t)(nt * 16 + l16) * 1280 + bOff + k0 + khi * 8);
#pragma unroll
        for (int m = 0; m < 2; ++m)
#pragma unroll
            for (int nt = 0; nt < 3; ++nt)
                acc[m][nt] = __builtin_amdgcn_mfma_f32_16x16x32_bf16(a[m], b[nt], acc[m][nt], 0, 0, 0);
    }
}

__global__ __launch_bounds__(256) void outproj_mfma_kernel(
    const unsigned short* __restrict__ x_bf,
    const unsigned short* __restrict__ F0, const float* __restrict__ kp0,
    const unsigned short* __restrict__ F1, const float* __restrict__ kp1,
    const unsigned short* __restrict__ F2, const float* __restrict__ kp2,
    const unsigned short* __restrict__ Wcb, const float* __restrict__ bc,
    float* __restrict__ out, int N)
{
    const int lane = threadIdx.x & 63;
    const int wave = threadIdx.x >> 6;
    const int l16 = lane & 15;
    const int khi = lane >> 4;
    const long long bm = (long long)blockIdx.x * 128 + wave * 32;

    long long r0 = bm + l16;        if (r0 >= N) r0 = 0;
    long long r1 = bm + 16 + l16;   if (r1 >= N) r1 = 0;

    f32x4 acc[2][3];
#pragma unroll
    for (int m = 0; m < 2; ++m)
#pragma unroll
        for (int nt = 0; nt < 3; ++nt) acc[m][nt] = (f32x4){0.f, 0.f, 0.f, 0.f};

    outproj_seg<512, false>(x_bf, nullptr, Wcb, 0,    r0, r1, l16, khi, acc);
    outproj_seg<256, true >(F0,   kp0,     Wcb, 512,  r0, r1, l16, khi, acc);
    outproj_seg<256, true >(F1,   kp1,     Wcb, 768,  r0, r1, l16, khi, acc);
    outproj_seg<256, true >(F2,   kp2,     Wcb, 1024, r0, r1, l16, khi, acc);

#pragma unroll
    for (int m = 0; m < 2; ++m)
#pragma unroll
        for (int nt = 0; nt < 3; ++nt)
#pragma unroll
            for (int r = 0; r < 4; ++r) {
                long long grow = bm + m * 16 + khi * 4 + r;
                int gcol = nt * 16 + l16;
                if (grow < N && gcol < 40)
                    out[grow * 40 + gcol] = acc[m][nt][r] + bc[gcol];
            }
}

// ---------------- host-side orchestration ----------------
extern "C" void kernel_launch(void* const* d_in, const int* in_sizes, int n_in,
                              void* d_out, int out_size, void* d_ws, size_t ws_size,
                              hipStream_t stream)
{
    const float* x      = (const float*)d_in[0];
    const int*   esrc   = (const int*)d_in[1];
    const int*   edst   = (const int*)d_in[2];
    const float* ew     = (const float*)d_in[3];
    const float* W_in   = (const float*)d_in[4];
    const float* SW_in  = (const float*)d_in[5];
    const float* b_in   = (const float*)d_in[6];
    const float* g_in   = (const float*)d_in[7];
    const float* be_in  = (const float*)d_in[8];
    const float* W_h    = (const float*)d_in[9];
    const float* SW_h   = (const float*)d_in[10];
    const float* b_h    = (const float*)d_in[11];
    const float* g_h    = (const float*)d_in[12];
    const float* be_h   = (const float*)d_in[13];
    const float* Wc     = (const float*)d_in[14];
    const float* bc     = (const float*)d_in[15];
    float* out = (float*)d_out;

    const int N = in_sizes[0] / 500;      // 100000
    const int n_edges = in_sizes[1];      // 3200000

    // ---- workspace layout ----
    char* p = (char*)d_ws;
    unsigned short* x_bf = (unsigned short*)p; p += (size_t)N * 512 * 2;        // 102.4 MB
    unsigned short* Xa   = (unsigned short*)p; p += (size_t)N * 512 * 2;        // 102.4 MB (F2 aliases)
    unsigned short* Ha   = (unsigned short*)p; p += (size_t)N * 256 * 2;
    unsigned short* H1   = (unsigned short*)p; p += (size_t)N * 256 * 2;
    unsigned short* H2   = (unsigned short*)p; p += (size_t)N * 256 * 2;
    unsigned short* F0   = (unsigned short*)p; p += (size_t)N * 256 * 2;
    unsigned short* F1   = (unsigned short*)p; p += (size_t)N * 256 * 2;
    unsigned short* F2   = Xa;  // alias: Xa's last read precedes F2's write
    unsigned short* Wf_in = (unsigned short*)p; p += (size_t)3 * 256 * 1024 * 2;
    unsigned short* Wf_h  = (unsigned short*)p; p += (size_t)3 * 256 * 512 * 2;
    unsigned short* Wcb   = (unsigned short*)p; p += (size_t)48 * 1280 * 2;
    float* stats = (float*)p; p += (size_t)6 * 1024 * 4;
    int* cnt     = (int*)p; p += (size_t)N * 4;
    int* row_ptr = (int*)p; p += (size_t)(N + 1) * 4 + 4;
    int* heads   = (int*)p; p += (size_t)N * 4;
    int2* meta   = (int2*)p;

    // ---- preprocessing ----
    hipMemsetAsync(stats, 0, 6 * 1024 * sizeof(float), stream);
    hipLaunchKernelGGL(transpose_fused_kernel, dim3(2048), dim3(256), 0, stream,
                       W_in, SW_in, Wf_in, 500, 512, 3);
    hipLaunchKernelGGL(transpose_fused_kernel, dim3(1024), dim3(256), 0, stream,
                       W_h, SW_h, Wf_h, 256, 256, 3);
    hipLaunchKernelGGL(transpose_wc_kernel, dim3(240), dim3(256), 0, stream, Wc, Wcb);

    hipMemsetAsync(cnt, 0, (size_t)N * sizeof(int), stream);
    hipLaunchKernelGGL(hist_kernel, dim3(4096), dim3(256), 0, stream, edst, cnt, n_edges);
    hipLaunchKernelGGL(scan_kernel, dim3(1), dim3(1024), 0, stream, cnt, row_ptr, heads, N);
    hipLaunchKernelGGL(scatter_kernel, dim3(4096), dim3(256), 0, stream,
                       esrc, edst, ew, heads, meta, n_edges);

    hipLaunchKernelGGL(cvtx_kernel, dim3(4096), dim3(256), 0, stream, x, x_bf, N);

    // Xa = A @ x_bf (shared across 3 input layers)
    hipLaunchKernelGGL(spmm512_kernel, dim3((N + 3) / 4), dim3(256), 0, stream,
                       row_ptr, meta, x_bf, Xa, N);

    dim3 blk(256);
    dim3 ggrid((N + 127) / 128);
    dim3 sgrid((N + 3) / 4);
    float* st;

    // ---- j = 0: input GC -> F0 (pre-BN final feature) ----
    st = stats + 0 * 1024;
    hipLaunchKernelGGL((gemm_fused_kernel<512, 512>), ggrid, blk, 0, stream,
                       Xa, x_bf, Wf_in, b_in, F0, st, N);
    hipLaunchKernelGGL(bn_finalize_kernel, dim3(1), dim3(256), 0, stream, st, g_in, be_in, st + 512, N);

    // ---- j = 1 ----
    st = stats + 1 * 1024;
    hipLaunchKernelGGL((gemm_fused_kernel<512, 512>), ggrid, blk, 0, stream,
                       Xa, x_bf, Wf_in + (size_t)1 * 256 * 1024, b_in + 256, H1, st, N);
    hipLaunchKernelGGL(bn_finalize_kernel, dim3(1), dim3(256), 0, stream, st, g_in + 256, be_in + 256, st + 512, N);
    hipLaunchKernelGGL(bn_apply_kernel, dim3(2048), dim3(256), 0, stream, H1, st + 512, (long long)N * 64);
    hipLaunchKernelGGL(spmm256_kernel, sgrid, blk, 0, stream, row_ptr, meta, H1, Ha, N);
    st = stats + 2 * 1024;
    hipLaunchKernelGGL((gemm_fused_kernel<256, 256>), ggrid, blk, 0, stream,
                       Ha, H1, Wf_h, b_h, F1, st, N);
    hipLaunchKernelGGL(bn_finalize_kernel, dim3(1), dim3(256), 0, stream, st, g_h, be_h, st + 512, N);

    // ---- j = 2 ----
    st = stats + 3 * 1024;
    hipLaunchKernelGGL((gemm_fused_kernel<512, 512>), ggrid, blk, 0, stream,
                       Xa, x_bf, Wf_in + (size_t)2 * 256 * 1024, b_in + 512, H1, st, N);
    hipLaunchKernelGGL(bn_finalize_kernel, dim3(1), dim3(256), 0, stream, st, g_in + 512, be_in + 512, st + 512, N);
    hipLaunchKernelGGL(bn_apply_kernel, dim3(2048), dim3(256), 0, stream, H1, st + 512, (long long)N * 64);
    hipLaunchKernelGGL(spmm256_kernel, sgrid, blk, 0, stream, row_ptr, meta, H1, Ha, N);
    st = stats + 4 * 1024;
    hipLaunchKernelGGL((gemm_fused_kernel<256, 256>), ggrid, blk, 0, stream,
                       Ha, H1, Wf_h + (size_t)1 * 256 * 512, b_h + 256, H2, st, N);
    hipLaunchKernelGGL(bn_finalize_kernel, dim3(1), dim3(256), 0, stream, st, g_h + 256, be_h + 256, st + 512, N);
    hipLaunchKernelGGL(bn_apply_kernel, dim3(2048), dim3(256), 0, stream, H2, st + 512, (long long)N * 64);
    hipLaunchKernelGGL(spmm256_kernel, sgrid, blk, 0, stream, row_ptr, meta, H2, Ha, N);
    st = stats + 5 * 1024;
    hipLaunchKernelGGL((gemm_fused_kernel<256, 256>), ggrid, blk, 0, stream,
                       Ha, H2, Wf_h + (size_t)2 * 256 * 512, b_h + 512, F2, st, N);
    hipLaunchKernelGGL(bn_finalize_kernel, dim3(1), dim3(256), 0, stream, st, g_h + 512, be_h + 512, st + 512, N);

    // ---- final: out = [x | bn(F0) | bn(F1) | bn(F2)] @ Wcb^T + bc ----
    hipLaunchKernelGGL(outproj_mfma_kernel, ggrid, blk, 0, stream,
                       x_bf,
                       F0, stats + 0 * 1024 + 512,
                       F1, stats + 2 * 1024 + 512,
                       F2, stats + 5 * 1024 + 512,
                       Wcb, bc, out, N);
}

// Round 7
// 3029.070 us; speedup vs baseline: 24.6925x; 1.0712x over previous
//
#include <hip/hip_runtime.h>

typedef __attribute__((ext_vector_type(8))) short bf16x8;
typedef __attribute__((ext_vector_type(4))) float f32x4;
typedef __attribute__((ext_vector_type(4))) unsigned short u16x4;
typedef __attribute__((ext_vector_type(8))) unsigned short u16x8;

__device__ __forceinline__ float bf2f(unsigned short u) {
    union { unsigned int i; float f; } v; v.i = ((unsigned int)u) << 16; return v.f;
}
__device__ __forceinline__ unsigned short f2bf(float f) {
    union { float f; unsigned int i; } v; v.f = f;
    unsigned int b = v.i;
    b += 0x7FFFu + ((b >> 16) & 1u);   // round-to-nearest-even
    return (unsigned short)(b >> 16);
}

// ---------------- fused weight transpose: W,SW [L][K][256] -> Wf[L][256][2*Kp] bf16 ----------------
__global__ __launch_bounds__(256) void transpose_fused_kernel(
    const float* __restrict__ W, const float* __restrict__ SW,
    unsigned short* __restrict__ Wf, int K, int Kp, int L)
{
    long long total = (long long)L * 256 * 2 * Kp;
    long long idx = (long long)blockIdx.x * blockDim.x + threadIdx.x;
    const long long stride = (long long)gridDim.x * blockDim.x;
    for (; idx < total; idx += stride) {
        int l = (int)(idx / ((long long)256 * 2 * Kp));
        long long rem = idx - (long long)l * 256 * 2 * Kp;
        int c = (int)(rem / (2 * Kp));
        int kk = (int)(rem - (long long)c * 2 * Kp);
        const float* src = (kk < Kp) ? W : SW;
        int k = (kk < Kp) ? kk : kk - Kp;
        float v = (k < K) ? src[((size_t)l * K + k) * 256 + c] : 0.f;
        Wf[idx] = f2bf(v);
    }
}

// ---------------- Wc[1268][40] fp32 -> Wcb[48][1280] bf16 (segment-mapped, padded) ----------------
__global__ __launch_bounds__(256) void transpose_wc_kernel(
    const float* __restrict__ Wc, unsigned short* __restrict__ Wcb)
{
    int idx = blockIdx.x * blockDim.x + threadIdx.x;
    if (idx >= 48 * 1280) return;
    int c = idx / 1280;
    int kk = idx - c * 1280;
    int src = -1;
    if (kk < 512)       { if (kk < 500) src = kk; }
    else if (kk < 768)  src = 500 + (kk - 512);
    else if (kk < 1024) src = 756 + (kk - 768);
    else                src = 1012 + (kk - 1024);
    float v = (c < 40 && src >= 0) ? Wc[(size_t)src * 40 + c] : 0.f;
    Wcb[idx] = f2bf(v);
}

// ---------------- x -> bf16 with pad 500->512 (streaming) ----------------
__global__ __launch_bounds__(256) void cvtx_kernel(
    const float* __restrict__ X, unsigned short* __restrict__ Xb, int N)
{
    long long total = (long long)N * 64;  // u16x8 groups
    long long idx = (long long)blockIdx.x * blockDim.x + threadIdx.x;
    const long long stride = (long long)gridDim.x * blockDim.x;
    for (; idx < total; idx += stride) {
        long long row = idx >> 6;
        int g = (int)(idx & 63);
        int k0 = g * 8;
        float v[8];
        if (k0 + 8 <= 500) {
            float4 q0 = *reinterpret_cast<const float4*>(X + row * 500 + k0);
            float4 q1 = *reinterpret_cast<const float4*>(X + row * 500 + k0 + 4);
            v[0] = q0.x; v[1] = q0.y; v[2] = q0.z; v[3] = q0.w;
            v[4] = q1.x; v[5] = q1.y; v[6] = q1.z; v[7] = q1.w;
        } else {
#pragma unroll
            for (int j = 0; j < 8; ++j) v[j] = (k0 + j < 500) ? X[row * 500 + k0 + j] : 0.f;
        }
        u16x8 o;
#pragma unroll
        for (int j = 0; j < 8; ++j) o[j] = f2bf(v[j]);
        *reinterpret_cast<u16x8*>(Xb + row * 512 + k0) = o;
    }
}

// ---------------- CSR build ----------------
__global__ __launch_bounds__(256) void hist_kernel(
    const int* __restrict__ edst, int* __restrict__ cnt, int n_edges)
{
    int idx = blockIdx.x * blockDim.x + threadIdx.x;
    const int stride = gridDim.x * blockDim.x;
    for (; idx < n_edges; idx += stride) atomicAdd(&cnt[edst[idx]], 1);
}

// 3-phase scan: (1) per-block inclusive scan of 256 cnts, (2) scan block sums, (3) add offsets
__global__ __launch_bounds__(256) void scan1_kernel(
    const int* __restrict__ cnt, int* __restrict__ excl,
    int* __restrict__ blocksums, int n)
{
    __shared__ int s[256];
    const int tid = threadIdx.x;
    const int i = blockIdx.x * 256 + tid;
    int v = (i < n) ? cnt[i] : 0;
    s[tid] = v;
    __syncthreads();
#pragma unroll
    for (int off = 1; off < 256; off <<= 1) {
        int t = s[tid];
        if (tid >= off) t += s[tid - off];
        __syncthreads();
        s[tid] = t;
        __syncthreads();
    }
    if (i < n) excl[i] = s[tid] - v;
    if (tid == 255) blocksums[blockIdx.x] = s[255];
}

__global__ __launch_bounds__(512) void scan2_kernel(int* __restrict__ blocksums, int nb)
{
    __shared__ int s[512];
    const int tid = threadIdx.x;
    int v = (tid < nb) ? blocksums[tid] : 0;
    s[tid] = v;
    __syncthreads();
#pragma unroll
    for (int off = 1; off < 512; off <<= 1) {
        int t = s[tid];
        if (tid >= off) t += s[tid - off];
        __syncthreads();
        s[tid] = t;
        __syncthreads();
    }
    if (tid < nb) blocksums[tid] = s[tid] - v;  // exclusive
}

__global__ __launch_bounds__(256) void scan3_kernel(
    const int* __restrict__ excl, const int* __restrict__ blocksums,
    int* __restrict__ row_ptr, int* __restrict__ heads, int n, int n_edges)
{
    const int i = blockIdx.x * 256 + threadIdx.x;
    if (i < n) {
        int v = excl[i] + blocksums[i >> 8];
        row_ptr[i] = v;
        heads[i] = v;
    }
    if (i == 0) row_ptr[n] = n_edges;
}

__global__ __launch_bounds__(256) void scatter_kernel(
    const int* __restrict__ esrc, const int* __restrict__ edst,
    const float* __restrict__ ew, int* __restrict__ heads,
    int2* __restrict__ meta, int n_edges)
{
    int idx = blockIdx.x * blockDim.x + threadIdx.x;
    const int stride = gridDim.x * blockDim.x;
    for (; idx < n_edges; idx += stride) {
        int d = edst[idx];
        int pos = atomicAdd(&heads[d], 1);
        meta[pos] = make_int2(esrc[idx], __float_as_int(ew[idx]));
    }
}

// ---------------- SpMM 256-wide: one wave per node, 12-deep pipeline ----------------
__global__ __launch_bounds__(256) void spmm256_kernel(
    const int* __restrict__ row_ptr, const int2* __restrict__ meta,
    const unsigned short* __restrict__ S, unsigned short* __restrict__ O, int N)
{
    const int wave = threadIdx.x >> 6;
    const int lane = threadIdx.x & 63;
    int node = blockIdx.x * 4 + wave;
    if (node >= N) return;
    node = __builtin_amdgcn_readfirstlane(node);
    const int beg = row_ptr[node];
    const int end = row_ptr[node + 1];
    float a0 = 0.f, a1 = 0.f, a2 = 0.f, a3 = 0.f;

    int e = beg;
    for (; e + 12 <= end; e += 12) {
        int2 m[12];
#pragma unroll
        for (int j = 0; j < 12; ++j) m[j] = meta[e + j];
        u16x4 v[12];
#pragma unroll
        for (int j = 0; j < 12; ++j)
            v[j] = *reinterpret_cast<const u16x4*>(S + (size_t)m[j].x * 256 + lane * 4);
#pragma unroll
        for (int j = 0; j < 12; ++j) {
            float w = __int_as_float(m[j].y);
            a0 = fmaf(w, bf2f(v[j][0]), a0);
            a1 = fmaf(w, bf2f(v[j][1]), a1);
            a2 = fmaf(w, bf2f(v[j][2]), a2);
            a3 = fmaf(w, bf2f(v[j][3]), a3);
        }
    }
    for (; e + 4 <= end; e += 4) {
        int2 m[4];
#pragma unroll
        for (int j = 0; j < 4; ++j) m[j] = meta[e + j];
        u16x4 v[4];
#pragma unroll
        for (int j = 0; j < 4; ++j)
            v[j] = *reinterpret_cast<const u16x4*>(S + (size_t)m[j].x * 256 + lane * 4);
#pragma unroll
        for (int j = 0; j < 4; ++j) {
            float w = __int_as_float(m[j].y);
            a0 = fmaf(w, bf2f(v[j][0]), a0);
            a1 = fmaf(w, bf2f(v[j][1]), a1);
            a2 = fmaf(w, bf2f(v[j][2]), a2);
            a3 = fmaf(w, bf2f(v[j][3]), a3);
        }
    }
    for (; e < end; ++e) {
        int2 m = meta[e];
        float w = __int_as_float(m.y);
        u16x4 v = *reinterpret_cast<const u16x4*>(S + (size_t)m.x * 256 + lane * 4);
        a0 = fmaf(w, bf2f(v[0]), a0);
        a1 = fmaf(w, bf2f(v[1]), a1);
        a2 = fmaf(w, bf2f(v[2]), a2);
        a3 = fmaf(w, bf2f(v[3]), a3);
    }
    u16x4 o;
    o[0] = f2bf(a0); o[1] = f2bf(a1); o[2] = f2bf(a2); o[3] = f2bf(a3);
    *reinterpret_cast<u16x4*>(O + (size_t)node * 256 + lane * 4) = o;
}

// ---------------- SpMM 512-wide: TWO waves per node (half-row each), 8-deep pipeline ----------------
__global__ __launch_bounds__(512) void spmm512_kernel(
    const int* __restrict__ row_ptr, const int2* __restrict__ meta,
    const unsigned short* __restrict__ S, unsigned short* __restrict__ O, int N)
{
    const int wv = threadIdx.x >> 6;      // 0..7
    const int lane = threadIdx.x & 63;
    const int half = wv & 1;
    int node = blockIdx.x * 4 + (wv >> 1);
    if (node >= N) return;
    node = __builtin_amdgcn_readfirstlane(node);
    const int beg = row_ptr[node];
    const int end = row_ptr[node + 1];
    const int coff = half * 256 + lane * 4;   // element offset into 512-wide row
    float a0 = 0.f, a1 = 0.f, a2 = 0.f, a3 = 0.f;

    int e = beg;
    for (; e + 8 <= end; e += 8) {
        int2 m[8];
#pragma unroll
        for (int j = 0; j < 8; ++j) m[j] = meta[e + j];
        u16x4 v[8];
#pragma unroll
        for (int j = 0; j < 8; ++j)
            v[j] = *reinterpret_cast<const u16x4*>(S + (size_t)m[j].x * 512 + coff);
#pragma unroll
        for (int j = 0; j < 8; ++j) {
            float w = __int_as_float(m[j].y);
            a0 = fmaf(w, bf2f(v[j][0]), a0);
            a1 = fmaf(w, bf2f(v[j][1]), a1);
            a2 = fmaf(w, bf2f(v[j][2]), a2);
            a3 = fmaf(w, bf2f(v[j][3]), a3);
        }
    }
    for (; e + 2 <= end; e += 2) {
        int2 m0 = meta[e], m1 = meta[e + 1];
        u16x4 v0 = *reinterpret_cast<const u16x4*>(S + (size_t)m0.x * 512 + coff);
        u16x4 v1 = *reinterpret_cast<const u16x4*>(S + (size_t)m1.x * 512 + coff);
        float w0 = __int_as_float(m0.y), w1 = __int_as_float(m1.y);
        a0 = fmaf(w0, bf2f(v0[0]), a0); a1 = fmaf(w0, bf2f(v0[1]), a1);
        a2 = fmaf(w0, bf2f(v0[2]), a2); a3 = fmaf(w0, bf2f(v0[3]), a3);
        a0 = fmaf(w1, bf2f(v1[0]), a0); a1 = fmaf(w1, bf2f(v1[1]), a1);
        a2 = fmaf(w1, bf2f(v1[2]), a2); a3 = fmaf(w1, bf2f(v1[3]), a3);
    }
    for (; e < end; ++e) {
        int2 m = meta[e];
        float w = __int_as_float(m.y);
        u16x4 v = *reinterpret_cast<const u16x4*>(S + (size_t)m.x * 512 + coff);
        a0 = fmaf(w, bf2f(v[0]), a0);
        a1 = fmaf(w, bf2f(v[1]), a1);
        a2 = fmaf(w, bf2f(v[2]), a2);
        a3 = fmaf(w, bf2f(v[3]), a3);
    }
    u16x4 o;
    o[0] = f2bf(a0); o[1] = f2bf(a1); o[2] = f2bf(a2); o[3] = f2bf(a3);
    *reinterpret_cast<u16x4*>(O + (size_t)node * 512 + coff) = o;
}

// ---------------- fused MFMA GEMM (compile-time K): C = [A1|A2] @ Btf^T + bias, + BN stats ----------------
template<int K1, int K2>
__global__ __launch_bounds__(256) void gemm_fused_kernel(
    const unsigned short* __restrict__ A1, const unsigned short* __restrict__ A2,
    const unsigned short* __restrict__ Btf, const float* __restrict__ bias,
    unsigned short* __restrict__ Cout, float* __restrict__ stats, int N)
{
    const int lane = threadIdx.x & 63;
    const int wave = threadIdx.x >> 6;
    const int l16 = lane & 15;
    const int khi = lane >> 4;
    const long long bm = (long long)blockIdx.x * 128;
    const int col0 = wave * 64;
    constexpr int KT = K1 + K2;

    f32x4 acc[2][4][4];
#pragma unroll
    for (int t = 0; t < 2; ++t)
#pragma unroll
        for (int m = 0; m < 4; ++m)
#pragma unroll
            for (int n = 0; n < 4; ++n) acc[t][m][n] = (f32x4){0.f, 0.f, 0.f, 0.f};

    const unsigned short* bp[4];
#pragma unroll
    for (int n = 0; n < 4; ++n)
        bp[n] = Btf + (size_t)(col0 + n * 16 + l16) * KT + khi * 8;

    {
        const unsigned short* ap[2][4];
#pragma unroll
        for (int t = 0; t < 2; ++t)
#pragma unroll
            for (int m = 0; m < 4; ++m) {
                long long r = bm + t * 64 + m * 16 + l16;
                if (r >= N) r = 0;
                ap[t][m] = A1 + (size_t)r * K1 + khi * 8;
            }
        for (int k0 = 0; k0 < K1; k0 += 32) {
            bf16x8 b[4];
#pragma unroll
            for (int n = 0; n < 4; ++n) b[n] = *reinterpret_cast<const bf16x8*>(bp[n] + k0);
            bf16x8 a[2][4];
#pragma unroll
            for (int t = 0; t < 2; ++t)
#pragma unroll
                for (int m = 0; m < 4; ++m) a[t][m] = *reinterpret_cast<const bf16x8*>(ap[t][m] + k0);
#pragma unroll
            for (int t = 0; t < 2; ++t)
#pragma unroll
                for (int m = 0; m < 4; ++m)
#pragma unroll
                    for (int n = 0; n < 4; ++n)
                        acc[t][m][n] = __builtin_amdgcn_mfma_f32_16x16x32_bf16(a[t][m], b[n], acc[t][m][n], 0, 0, 0);
        }
    }
    {
        const unsigned short* ap[2][4];
#pragma unroll
        for (int t = 0; t < 2; ++t)
#pragma unroll
            for (int m = 0; m < 4; ++m) {
                long long r = bm + t * 64 + m * 16 + l16;
                if (r >= N) r = 0;
                ap[t][m] = A2 + (size_t)r * K2 + khi * 8;
            }
        for (int k0 = 0; k0 < K2; k0 += 32) {
            bf16x8 b[4];
#pragma unroll
            for (int n = 0; n < 4; ++n) b[n] = *reinterpret_cast<const bf16x8*>(bp[n] + K1 + k0);
            bf16x8 a[2][4];
#pragma unroll
            for (int t = 0; t < 2; ++t)
#pragma unroll
                for (int m = 0; m < 4; ++m) a[t][m] = *reinterpret_cast<const bf16x8*>(ap[t][m] + k0);
#pragma unroll
            for (int t = 0; t < 2; ++t)
#pragma unroll
                for (int m = 0; m < 4; ++m)
#pragma unroll
                    for (int n = 0; n < 4; ++n)
                        acc[t][m][n] = __builtin_amdgcn_mfma_f32_16x16x32_bf16(a[t][m], b[n], acc[t][m][n], 0, 0, 0);
        }
    }

    float bs[4];
#pragma unroll
    for (int n = 0; n < 4; ++n) bs[n] = bias[col0 + n * 16 + l16];

    float s[4], s2[4];
#pragma unroll
    for (int n = 0; n < 4; ++n) { s[n] = 0.f; s2[n] = 0.f; }

#pragma unroll
    for (int t = 0; t < 2; ++t)
#pragma unroll
        for (int m = 0; m < 4; ++m)
#pragma unroll
            for (int r = 0; r < 4; ++r) {
                long long grow = bm + t * 64 + m * 16 + khi * 4 + r;
                if (grow >= N) continue;
#pragma unroll
                for (int n = 0; n < 4; ++n) {
                    int gcol = col0 + n * 16 + l16;
                    float v = acc[t][m][n][r] + bs[n];
                    Cout[grow * 256 + gcol] = f2bf(v);
                    s[n] += v;
                    s2[n] = fmaf(v, v, s2[n]);
                }
            }

#pragma unroll
    for (int n = 0; n < 4; ++n) {
        float a = s[n], b2 = s2[n];
        a += __shfl_xor(a, 16); a += __shfl_xor(a, 32);
        b2 += __shfl_xor(b2, 16); b2 += __shfl_xor(b2, 32);
        if (khi == 0) {
            int c = col0 + n * 16 + l16;
            atomicAdd(&stats[c], a);
            atomicAdd(&stats[256 + c], b2);
        }
    }
}

// ---------------- BN finalize ----------------
__global__ __launch_bounds__(256) void bn_finalize_kernel(
    const float* __restrict__ sums, const float* __restrict__ g,
    const float* __restrict__ be, float* __restrict__ kp, int N)
{
    const int c = threadIdx.x;
    float invN = 1.f / (float)N;
    float mean = sums[c] * invN;
    float var = sums[256 + c] * invN - mean * mean;
    float inv = rsqrtf(var + 1e-5f);
    float sc = g[c] * inv;
    kp[c] = sc;
    kp[256 + c] = be[c] - sc * mean;
}

// ---------------- BN apply + ReLU in place (intermediate features) ----------------
__global__ __launch_bounds__(256) void bn_apply_kernel(
    unsigned short* __restrict__ X, const float* __restrict__ kp, long long n4)
{
    long long idx = (long long)blockIdx.x * blockDim.x + threadIdx.x;
    const long long stride = (long long)gridDim.x * blockDim.x;
    for (; idx < n4; idx += stride) {
        int c4 = (int)(idx & 63);
        u16x4 v = reinterpret_cast<u16x4*>(X)[idx];
        f32x4 s = reinterpret_cast<const f32x4*>(kp)[c4];
        f32x4 t = reinterpret_cast<const f32x4*>(kp + 256)[c4];
#pragma unroll
        for (int i = 0; i < 4; ++i) {
            float f = fmaxf(fmaf(bf2f(v[i]), s[i], t[i]), 0.f);
            v[i] = f2bf(f);
        }
        reinterpret_cast<u16x4*>(X)[idx] = v;
    }
}

// ---------------- final MFMA outproj: out[N,40] = [x|bn(F0)|bn(F1)|bn(F2)] @ Wcb^T + bc ----------------
template<int KS, bool BN>
__device__ __forceinline__ void outproj_seg(
    const unsigned short* __restrict__ seg, const float* __restrict__ kp,
    const unsigned short* __restrict__ Wcb, int bOff,
    long long r0, long long r1, int l16, int khi, f32x4 acc[2][3])
{
    const unsigned short* a0p = seg + (size_t)r0 * KS + khi * 8;
    const unsigned short* a1p = seg + (size_t)r1 * KS + khi * 8;
#pragma unroll
    for (int k0 = 0; k0 < KS; k0 += 32) {
        bf16x8 a[2];
        a[0] = *reinterpret_cast<const bf16x8*>(a0p + k0);
        a[1] = *reinterpret_cast<const bf16x8*>(a1p + k0);
        if (BN) {
            int ch0 = k0 + khi * 8;
            f32x4 s0 = *reinterpret_cast<const f32x4*>(kp + ch0);
            f32x4 s1 = *reinterpret_cast<const f32x4*>(kp + ch0 + 4);
            f32x4 t0 = *reinterpret_cast<const f32x4*>(kp + 256 + ch0);
            f32x4 t1 = *reinterpret_cast<const f32x4*>(kp + 256 + ch0 + 4);
#pragma unroll
            for (int m = 0; m < 2; ++m) {
                u16x8 raw;
                __builtin_memcpy(&raw, &a[m], 16);
                u16x8 ov;
#pragma unroll
                for (int j = 0; j < 4; ++j) {
                    ov[j]     = f2bf(fmaxf(fmaf(bf2f(raw[j]),     s0[j], t0[j]), 0.f));
                    ov[4 + j] = f2bf(fmaxf(fmaf(bf2f(raw[4 + j]), s1[j], t1[j]), 0.f));
                }
                __builtin_memcpy(&a[m], &ov, 16);
            }
        }
        bf16x8 b[3];
#pragma unroll
        for (int nt = 0; nt < 3; ++nt)
            b[nt] = *reinterpret_cast<const bf16x8*>(Wcb + (size_t)(nt * 16 + l16) * 1280 + bOff + k0 + khi * 8);
#pragma unroll
        for (int m = 0; m < 2; ++m)
#pragma unroll
            for (int nt = 0; nt < 3; ++nt)
                acc[m][nt] = __builtin_amdgcn_mfma_f32_16x16x32_bf16(a[m], b[nt], acc[m][nt], 0, 0, 0);
    }
}

__global__ __launch_bounds__(256) void outproj_mfma_kernel(
    const unsigned short* __restrict__ x_bf,
    const unsigned short* __restrict__ F0, const float* __restrict__ kp0,
    const unsigned short* __restrict__ F1, const float* __restrict__ kp1,
    const unsigned short* __restrict__ F2, const float* __restrict__ kp2,
    const unsigned short* __restrict__ Wcb, const float* __restrict__ bc,
    float* __restrict__ out, int N)
{
    const int lane = threadIdx.x & 63;
    const int wave = threadIdx.x >> 6;
    const int l16 = lane & 15;
    const int khi = lane >> 4;
    const long long bm = (long long)blockIdx.x * 128 + wave * 32;

    long long r0 = bm + l16;        if (r0 >= N) r0 = 0;
    long long r1 = bm + 16 + l16;   if (r1 >= N) r1 = 0;

    f32x4 acc[2][3];
#pragma unroll
    for (int m = 0; m < 2; ++m)
#pragma unroll
        for (int nt = 0; nt < 3; ++nt) acc[m][nt] = (f32x4){0.f, 0.f, 0.f, 0.f};

    outproj_seg<512, false>(x_bf, nullptr, Wcb, 0,    r0, r1, l16, khi, acc);
    outproj_seg<256, true >(F0,   kp0,     Wcb, 512,  r0, r1, l16, khi, acc);
    outproj_seg<256, true >(F1,   kp1,     Wcb, 768,  r0, r1, l16, khi, acc);
    outproj_seg<256, true >(F2,   kp2,     Wcb, 1024, r0, r1, l16, khi, acc);

#pragma unroll
    for (int m = 0; m < 2; ++m)
#pragma unroll
        for (int nt = 0; nt < 3; ++nt)
#pragma unroll
            for (int r = 0; r < 4; ++r) {
                long long grow = bm + m * 16 + khi * 4 + r;
                int gcol = nt * 16 + l16;
                if (grow < N && gcol < 40)
                    out[grow * 40 + gcol] = acc[m][nt][r] + bc[gcol];
            }
}

// ---------------- host-side orchestration ----------------
extern "C" void kernel_launch(void* const* d_in, const int* in_sizes, int n_in,
                              void* d_out, int out_size, void* d_ws, size_t ws_size,
                              hipStream_t stream)
{
    const float* x      = (const float*)d_in[0];
    const int*   esrc   = (const int*)d_in[1];
    const int*   edst   = (const int*)d_in[2];
    const float* ew     = (const float*)d_in[3];
    const float* W_in   = (const float*)d_in[4];
    const float* SW_in  = (const float*)d_in[5];
    const float* b_in   = (const float*)d_in[6];
    const float* g_in   = (const float*)d_in[7];
    const float* be_in  = (const float*)d_in[8];
    const float* W_h    = (const float*)d_in[9];
    const float* SW_h   = (const float*)d_in[10];
    const float* b_h    = (const float*)d_in[11];
    const float* g_h    = (const float*)d_in[12];
    const float* be_h   = (const float*)d_in[13];
    const float* Wc     = (const float*)d_in[14];
    const float* bc     = (const float*)d_in[15];
    float* out = (float*)d_out;

    const int N = in_sizes[0] / 500;      // 100000
    const int n_edges = in_sizes[1];      // 3200000
    const int nb = (N + 255) / 256;       // scan blocks

    // ---- workspace layout ----
    char* p = (char*)d_ws;
    unsigned short* x_bf = (unsigned short*)p; p += (size_t)N * 512 * 2;
    unsigned short* Xa   = (unsigned short*)p; p += (size_t)N * 512 * 2;        // F2 aliases
    unsigned short* Ha   = (unsigned short*)p; p += (size_t)N * 256 * 2;
    unsigned short* H1   = (unsigned short*)p; p += (size_t)N * 256 * 2;
    unsigned short* H2   = (unsigned short*)p; p += (size_t)N * 256 * 2;
    unsigned short* F0   = (unsigned short*)p; p += (size_t)N * 256 * 2;
    unsigned short* F1   = (unsigned short*)p; p += (size_t)N * 256 * 2;
    unsigned short* F2   = Xa;  // alias: Xa's last read precedes F2's write
    unsigned short* Wf_in = (unsigned short*)p; p += (size_t)3 * 256 * 1024 * 2;
    unsigned short* Wf_h  = (unsigned short*)p; p += (size_t)3 * 256 * 512 * 2;
    unsigned short* Wcb   = (unsigned short*)p; p += (size_t)48 * 1280 * 2;
    float* stats = (float*)p; p += (size_t)6 * 1024 * 4;
    int* cnt     = (int*)p; p += (size_t)N * 4;                                  // adjacent to stats
    int* excl    = (int*)p; p += (size_t)N * 4;
    int* blocksums = (int*)p; p += 2048 * 4;
    int* row_ptr = (int*)p; p += (size_t)(N + 1) * 4 + 4;
    int* heads   = (int*)p; p += (size_t)N * 4;
    int2* meta   = (int2*)p;

    // ---- preprocessing ----
    // single memset covers stats (24 KB) + cnt (N*4), which are adjacent
    hipMemsetAsync(stats, 0, (size_t)6 * 1024 * sizeof(float) + (size_t)N * sizeof(int), stream);
    hipLaunchKernelGGL(transpose_fused_kernel, dim3(2048), dim3(256), 0, stream,
                       W_in, SW_in, Wf_in, 500, 512, 3);
    hipLaunchKernelGGL(transpose_fused_kernel, dim3(1024), dim3(256), 0, stream,
                       W_h, SW_h, Wf_h, 256, 256, 3);
    hipLaunchKernelGGL(transpose_wc_kernel, dim3(240), dim3(256), 0, stream, Wc, Wcb);

    hipLaunchKernelGGL(hist_kernel, dim3(4096), dim3(256), 0, stream, edst, cnt, n_edges);
    hipLaunchKernelGGL(scan1_kernel, dim3(nb), dim3(256), 0, stream, cnt, excl, blocksums, N);
    hipLaunchKernelGGL(scan2_kernel, dim3(1), dim3(512), 0, stream, blocksums, nb);
    hipLaunchKernelGGL(scan3_kernel, dim3(nb), dim3(256), 0, stream,
                       excl, blocksums, row_ptr, heads, N, n_edges);
    hipLaunchKernelGGL(scatter_kernel, dim3(4096), dim3(256), 0, stream,
                       esrc, edst, ew, heads, meta, n_edges);

    hipLaunchKernelGGL(cvtx_kernel, dim3(4096), dim3(256), 0, stream, x, x_bf, N);

    // Xa = A @ x_bf (shared across 3 input layers); 2 waves per node
    hipLaunchKernelGGL(spmm512_kernel, dim3((N + 3) / 4), dim3(512), 0, stream,
                       row_ptr, meta, x_bf, Xa, N);

    dim3 blk(256);
    dim3 ggrid((N + 127) / 128);
    dim3 sgrid((N + 3) / 4);
    float* st;

    // ---- j = 0: input GC -> F0 (pre-BN final feature) ----
    st = stats + 0 * 1024;
    hipLaunchKernelGGL((gemm_fused_kernel<512, 512>), ggrid, blk, 0, stream,
                       Xa, x_bf, Wf_in, b_in, F0, st, N);
    hipLaunchKernelGGL(bn_finalize_kernel, dim3(1), dim3(256), 0, stream, st, g_in, be_in, st + 512, N);

    // ---- j = 1 ----
    st = stats + 1 * 1024;
    hipLaunchKernelGGL((gemm_fused_kernel<512, 512>), ggrid, blk, 0, stream,
                       Xa, x_bf, Wf_in + (size_t)1 * 256 * 1024, b_in + 256, H1, st, N);
    hipLaunchKernelGGL(bn_finalize_kernel, dim3(1), dim3(256), 0, stream, st, g_in + 256, be_in + 256, st + 512, N);
    hipLaunchKernelGGL(bn_apply_kernel, dim3(2048), dim3(256), 0, stream, H1, st + 512, (long long)N * 64);
    hipLaunchKernelGGL(spmm256_kernel, sgrid, blk, 0, stream, row_ptr, meta, H1, Ha, N);
    st = stats + 2 * 1024;
    hipLaunchKernelGGL((gemm_fused_kernel<256, 256>), ggrid, blk, 0, stream,
                       Ha, H1, Wf_h, b_h, F1, st, N);
    hipLaunchKernelGGL(bn_finalize_kernel, dim3(1), dim3(256), 0, stream, st, g_h, be_h, st + 512, N);

    // ---- j = 2 ----
    st = stats + 3 * 1024;
    hipLaunchKernelGGL((gemm_fused_kernel<512, 512>), ggrid, blk, 0, stream,
                       Xa, x_bf, Wf_in + (size_t)2 * 256 * 1024, b_in + 512, H1, st, N);
    hipLaunchKernelGGL(bn_finalize_kernel, dim3(1), dim3(256), 0, stream, st, g_in + 512, be_in + 512, st + 512, N);
    hipLaunchKernelGGL(bn_apply_kernel, dim3(2048), dim3(256), 0, stream, H1, st + 512, (long long)N * 64);
    hipLaunchKernelGGL(spmm256_kernel, sgrid, blk, 0, stream, row_ptr, meta, H1, Ha, N);
    st = stats + 4 * 1024;
    hipLaunchKernelGGL((gemm_fused_kernel<256, 256>), ggrid, blk, 0, stream,
                       Ha, H1, Wf_h + (size_t)1 * 256 * 512, b_h + 256, H2, st, N);
    hipLaunchKernelGGL(bn_finalize_kernel, dim3(1), dim3(256), 0, stream, st, g_h + 256, be_h + 256, st + 512, N);
    hipLaunchKernelGGL(bn_apply_kernel, dim3(2048), dim3(256), 0, stream, H2, st + 512, (long long)N * 64);
    hipLaunchKernelGGL(spmm256_kernel, sgrid, blk, 0, stream, row_ptr, meta, H2, Ha, N);
    st = stats + 5 * 1024;
    hipLaunchKernelGGL((gemm_fused_kernel<256, 256>), ggrid, blk, 0, stream,
                       Ha, H2, Wf_h + (size_t)2 * 256 * 512, b_h + 512, F2, st, N);
    hipLaunchKernelGGL(bn_finalize_kernel, dim3(1), dim3(256), 0, stream, st, g_h + 512, be_h + 512, st + 512, N);

    // ---- final: out = [x | bn(F0) | bn(F1) | bn(F2)] @ Wcb^T + bc ----
    hipLaunchKernelGGL(outproj_mfma_kernel, ggrid, blk, 0, stream,
                       x_bf,
                       F0, stats + 0 * 1024 + 512,
                       F1, stats + 2 * 1024 + 512,
                       F2, stats + 5 * 1024 + 512,
                       Wcb, bc, out, N);
}

// Round 8
// 2899.511 us; speedup vs baseline: 25.7958x; 1.0447x over previous
//
#include <hip/hip_runtime.h>

typedef __attribute__((ext_vector_type(8))) short bf16x8;
typedef __attribute__((ext_vector_type(4))) float f32x4;
typedef __attribute__((ext_vector_type(4))) unsigned short u16x4;
typedef __attribute__((ext_vector_type(8))) unsigned short u16x8;

__device__ __forceinline__ float bf2f(unsigned short u) {
    union { unsigned int i; float f; } v; v.i = ((unsigned int)u) << 16; return v.f;
}
__device__ __forceinline__ unsigned short f2bf(float f) {
    union { float f; unsigned int i; } v; v.f = f;
    unsigned int b = v.i;
    b += 0x7FFFu + ((b >> 16) & 1u);   // round-to-nearest-even
    return (unsigned short)(b >> 16);
}

// ---------------- fused weight transpose: W,SW [L][K][256] -> Wf[L][256][2*Kp] bf16 ----------------
__global__ __launch_bounds__(256) void transpose_fused_kernel(
    const float* __restrict__ W, const float* __restrict__ SW,
    unsigned short* __restrict__ Wf, int K, int Kp, int L)
{
    long long total = (long long)L * 256 * 2 * Kp;
    long long idx = (long long)blockIdx.x * blockDim.x + threadIdx.x;
    const long long stride = (long long)gridDim.x * blockDim.x;
    for (; idx < total; idx += stride) {
        int l = (int)(idx / ((long long)256 * 2 * Kp));
        long long rem = idx - (long long)l * 256 * 2 * Kp;
        int c = (int)(rem / (2 * Kp));
        int kk = (int)(rem - (long long)c * 2 * Kp);
        const float* src = (kk < Kp) ? W : SW;
        int k = (kk < Kp) ? kk : kk - Kp;
        float v = (k < K) ? src[((size_t)l * K + k) * 256 + c] : 0.f;
        Wf[idx] = f2bf(v);
    }
}

// ---------------- Wc[1268][40] fp32 -> Wcb[48][1280] bf16 (segment-mapped, padded) ----------------
__global__ __launch_bounds__(256) void transpose_wc_kernel(
    const float* __restrict__ Wc, unsigned short* __restrict__ Wcb)
{
    int idx = blockIdx.x * blockDim.x + threadIdx.x;
    if (idx >= 48 * 1280) return;
    int c = idx / 1280;
    int kk = idx - c * 1280;
    int src = -1;
    if (kk < 512)       { if (kk < 500) src = kk; }
    else if (kk < 768)  src = 500 + (kk - 512);
    else if (kk < 1024) src = 756 + (kk - 768);
    else                src = 1012 + (kk - 1024);
    float v = (c < 40 && src >= 0) ? Wc[(size_t)src * 40 + c] : 0.f;
    Wcb[idx] = f2bf(v);
}

// ---------------- x -> bf16 with pad 500->512 (streaming) ----------------
__global__ __launch_bounds__(256) void cvtx_kernel(
    const float* __restrict__ X, unsigned short* __restrict__ Xb, int N)
{
    long long total = (long long)N * 64;
    long long idx = (long long)blockIdx.x * blockDim.x + threadIdx.x;
    const long long stride = (long long)gridDim.x * blockDim.x;
    for (; idx < total; idx += stride) {
        long long row = idx >> 6;
        int g = (int)(idx & 63);
        int k0 = g * 8;
        float v[8];
        if (k0 + 8 <= 500) {
            float4 q0 = *reinterpret_cast<const float4*>(X + row * 500 + k0);
            float4 q1 = *reinterpret_cast<const float4*>(X + row * 500 + k0 + 4);
            v[0] = q0.x; v[1] = q0.y; v[2] = q0.z; v[3] = q0.w;
            v[4] = q1.x; v[5] = q1.y; v[6] = q1.z; v[7] = q1.w;
        } else {
#pragma unroll
            for (int j = 0; j < 8; ++j) v[j] = (k0 + j < 500) ? X[row * 500 + k0 + j] : 0.f;
        }
        u16x8 o;
#pragma unroll
        for (int j = 0; j < 8; ++j) o[j] = f2bf(v[j]);
        *reinterpret_cast<u16x8*>(Xb + row * 512 + k0) = o;
    }
}

// ---------------- CSR build ----------------
__global__ __launch_bounds__(256) void hist_kernel(
    const int* __restrict__ edst, int* __restrict__ cnt, int n_edges)
{
    int idx = blockIdx.x * blockDim.x + threadIdx.x;
    const int stride = gridDim.x * blockDim.x;
    for (; idx < n_edges; idx += stride) atomicAdd(&cnt[edst[idx]], 1);
}

__global__ __launch_bounds__(256) void scan1_kernel(
    const int* __restrict__ cnt, int* __restrict__ excl,
    int* __restrict__ blocksums, int n)
{
    __shared__ int s[256];
    const int tid = threadIdx.x;
    const int i = blockIdx.x * 256 + tid;
    int v = (i < n) ? cnt[i] : 0;
    s[tid] = v;
    __syncthreads();
#pragma unroll
    for (int off = 1; off < 256; off <<= 1) {
        int t = s[tid];
        if (tid >= off) t += s[tid - off];
        __syncthreads();
        s[tid] = t;
        __syncthreads();
    }
    if (i < n) excl[i] = s[tid] - v;
    if (tid == 255) blocksums[blockIdx.x] = s[255];
}

__global__ __launch_bounds__(512) void scan2_kernel(int* __restrict__ blocksums, int nb)
{
    __shared__ int s[512];
    const int tid = threadIdx.x;
    int v = (tid < nb) ? blocksums[tid] : 0;
    s[tid] = v;
    __syncthreads();
#pragma unroll
    for (int off = 1; off < 512; off <<= 1) {
        int t = s[tid];
        if (tid >= off) t += s[tid - off];
        __syncthreads();
        s[tid] = t;
        __syncthreads();
    }
    if (tid < nb) blocksums[tid] = s[tid] - v;
}

__global__ __launch_bounds__(256) void scan3_kernel(
    const int* __restrict__ excl, const int* __restrict__ blocksums,
    int* __restrict__ row_ptr, int* __restrict__ heads, int n, int n_edges)
{
    const int i = blockIdx.x * 256 + threadIdx.x;
    if (i < n) {
        int v = excl[i] + blocksums[i >> 8];
        row_ptr[i] = v;
        heads[i] = v;
    }
    if (i == 0) row_ptr[n] = n_edges;
}

__global__ __launch_bounds__(256) void scatter_kernel(
    const int* __restrict__ esrc, const int* __restrict__ edst,
    const float* __restrict__ ew, int* __restrict__ heads,
    int2* __restrict__ meta, int n_edges)
{
    int idx = blockIdx.x * blockDim.x + threadIdx.x;
    const int stride = gridDim.x * blockDim.x;
    for (; idx < n_edges; idx += stride) {
        int d = edst[idx];
        int pos = atomicAdd(&heads[d], 1);
        meta[pos] = make_int2(esrc[idx], __float_as_int(ew[idx]));
    }
}

// ---------------- SpMM 256-wide with on-the-fly BN+ReLU on source rows ----------------
// O[dst] = sum_e w * relu(s[c]*S[src][c] + t[c]); kp = (scale[256], shift[256])
__global__ __launch_bounds__(256) void spmm256bn_kernel(
    const int* __restrict__ row_ptr, const int2* __restrict__ meta,
    const unsigned short* __restrict__ S, const float* __restrict__ kp,
    unsigned short* __restrict__ O, int N)
{
    const int wave = threadIdx.x >> 6;
    const int lane = threadIdx.x & 63;
    int node = blockIdx.x * 4 + wave;
    if (node >= N) return;
    node = __builtin_amdgcn_readfirstlane(node);
    const int beg = row_ptr[node];
    const int end = row_ptr[node + 1];
    const f32x4 sc = *reinterpret_cast<const f32x4*>(kp + lane * 4);
    const f32x4 sh = *reinterpret_cast<const f32x4*>(kp + 256 + lane * 4);
    float a0 = 0.f, a1 = 0.f, a2 = 0.f, a3 = 0.f;

    int e = beg;
    for (; e + 12 <= end; e += 12) {
        int2 m[12];
#pragma unroll
        for (int j = 0; j < 12; ++j) m[j] = meta[e + j];
        u16x4 v[12];
#pragma unroll
        for (int j = 0; j < 12; ++j)
            v[j] = *reinterpret_cast<const u16x4*>(S + (size_t)m[j].x * 256 + lane * 4);
#pragma unroll
        for (int j = 0; j < 12; ++j) {
            float w = __int_as_float(m[j].y);
            a0 = fmaf(w, fmaxf(fmaf(bf2f(v[j][0]), sc[0], sh[0]), 0.f), a0);
            a1 = fmaf(w, fmaxf(fmaf(bf2f(v[j][1]), sc[1], sh[1]), 0.f), a1);
            a2 = fmaf(w, fmaxf(fmaf(bf2f(v[j][2]), sc[2], sh[2]), 0.f), a2);
            a3 = fmaf(w, fmaxf(fmaf(bf2f(v[j][3]), sc[3], sh[3]), 0.f), a3);
        }
    }
    for (; e < end; ++e) {
        int2 m = meta[e];
        float w = __int_as_float(m.y);
        u16x4 v = *reinterpret_cast<const u16x4*>(S + (size_t)m.x * 256 + lane * 4);
        a0 = fmaf(w, fmaxf(fmaf(bf2f(v[0]), sc[0], sh[0]), 0.f), a0);
        a1 = fmaf(w, fmaxf(fmaf(bf2f(v[1]), sc[1], sh[1]), 0.f), a1);
        a2 = fmaf(w, fmaxf(fmaf(bf2f(v[2]), sc[2], sh[2]), 0.f), a2);
        a3 = fmaf(w, fmaxf(fmaf(bf2f(v[3]), sc[3], sh[3]), 0.f), a3);
    }
    u16x4 o;
    o[0] = f2bf(a0); o[1] = f2bf(a1); o[2] = f2bf(a2); o[3] = f2bf(a3);
    *reinterpret_cast<u16x4*>(O + (size_t)node * 256 + lane * 4) = o;
}

// ---------------- SpMM 512-wide: TWO waves per node (half-row each), 8-deep ----------------
__global__ __launch_bounds__(512) void spmm512_kernel(
    const int* __restrict__ row_ptr, const int2* __restrict__ meta,
    const unsigned short* __restrict__ S, unsigned short* __restrict__ O, int N)
{
    const int wv = threadIdx.x >> 6;
    const int lane = threadIdx.x & 63;
    const int half = wv & 1;
    int node = blockIdx.x * 4 + (wv >> 1);
    if (node >= N) return;
    node = __builtin_amdgcn_readfirstlane(node);
    const int beg = row_ptr[node];
    const int end = row_ptr[node + 1];
    const int coff = half * 256 + lane * 4;
    float a0 = 0.f, a1 = 0.f, a2 = 0.f, a3 = 0.f;

    int e = beg;
    for (; e + 8 <= end; e += 8) {
        int2 m[8];
#pragma unroll
        for (int j = 0; j < 8; ++j) m[j] = meta[e + j];
        u16x4 v[8];
#pragma unroll
        for (int j = 0; j < 8; ++j)
            v[j] = *reinterpret_cast<const u16x4*>(S + (size_t)m[j].x * 512 + coff);
#pragma unroll
        for (int j = 0; j < 8; ++j) {
            float w = __int_as_float(m[j].y);
            a0 = fmaf(w, bf2f(v[j][0]), a0);
            a1 = fmaf(w, bf2f(v[j][1]), a1);
            a2 = fmaf(w, bf2f(v[j][2]), a2);
            a3 = fmaf(w, bf2f(v[j][3]), a3);
        }
    }
    for (; e < end; ++e) {
        int2 m = meta[e];
        float w = __int_as_float(m.y);
        u16x4 v = *reinterpret_cast<const u16x4*>(S + (size_t)m.x * 512 + coff);
        a0 = fmaf(w, bf2f(v[0]), a0);
        a1 = fmaf(w, bf2f(v[1]), a1);
        a2 = fmaf(w, bf2f(v[2]), a2);
        a3 = fmaf(w, bf2f(v[3]), a3);
    }
    u16x4 o;
    o[0] = f2bf(a0); o[1] = f2bf(a1); o[2] = f2bf(a2); o[3] = f2bf(a3);
    *reinterpret_cast<u16x4*>(O + (size_t)node * 512 + coff) = o;
}

// ---------------- gemm512x3: three input-layer GEMMs in one kernel ----------------
// For l in 0..2: C_l[N,256] = [Xa | x_bf] @ Wf[l]^T + b[l], + BN stats into stats[l*1024].
__global__ __launch_bounds__(256) void gemm512x3_kernel(
    const unsigned short* __restrict__ A1, const unsigned short* __restrict__ A2,
    const unsigned short* __restrict__ Wf, const float* __restrict__ bias,
    unsigned short* __restrict__ C0, unsigned short* __restrict__ C1,
    unsigned short* __restrict__ C2, float* __restrict__ stats, int N)
{
    const int lane = threadIdx.x & 63;
    const int wave = threadIdx.x >> 6;
    const int l16 = lane & 15;
    const int khi = lane >> 4;
    const long long bm = (long long)blockIdx.x * 128;
    const int col0 = wave * 64;

    const unsigned short* ap1[2][4];
    const unsigned short* ap2[2][4];
#pragma unroll
    for (int t = 0; t < 2; ++t)
#pragma unroll
        for (int m = 0; m < 4; ++m) {
            long long r = bm + t * 64 + m * 16 + l16;
            if (r >= N) r = 0;
            ap1[t][m] = A1 + (size_t)r * 512 + khi * 8;
            ap2[t][m] = A2 + (size_t)r * 512 + khi * 8;
        }

    unsigned short* const Couts[3] = {C0, C1, C2};

    for (int l = 0; l < 3; ++l) {
        f32x4 acc[2][4][4];
#pragma unroll
        for (int t = 0; t < 2; ++t)
#pragma unroll
            for (int m = 0; m < 4; ++m)
#pragma unroll
                for (int n = 0; n < 4; ++n) acc[t][m][n] = (f32x4){0.f, 0.f, 0.f, 0.f};

        const unsigned short* bp[4];
#pragma unroll
        for (int n = 0; n < 4; ++n)
            bp[n] = Wf + (size_t)l * 256 * 1024 + (size_t)(col0 + n * 16 + l16) * 1024 + khi * 8;

        // segment 1: A1 (Xa), k in [0,512)
        for (int k0 = 0; k0 < 512; k0 += 32) {
            bf16x8 b[4];
#pragma unroll
            for (int n = 0; n < 4; ++n) b[n] = *reinterpret_cast<const bf16x8*>(bp[n] + k0);
            bf16x8 a[2][4];
#pragma unroll
            for (int t = 0; t < 2; ++t)
#pragma unroll
                for (int m = 0; m < 4; ++m) a[t][m] = *reinterpret_cast<const bf16x8*>(ap1[t][m] + k0);
#pragma unroll
            for (int t = 0; t < 2; ++t)
#pragma unroll
                for (int m = 0; m < 4; ++m)
#pragma unroll
                    for (int n = 0; n < 4; ++n)
                        acc[t][m][n] = __builtin_amdgcn_mfma_f32_16x16x32_bf16(a[t][m], b[n], acc[t][m][n], 0, 0, 0);
        }
        // segment 2: A2 (x_bf), k in [512,1024)
        for (int k0 = 0; k0 < 512; k0 += 32) {
            bf16x8 b[4];
#pragma unroll
            for (int n = 0; n < 4; ++n) b[n] = *reinterpret_cast<const bf16x8*>(bp[n] + 512 + k0);
            bf16x8 a[2][4];
#pragma unroll
            for (int t = 0; t < 2; ++t)
#pragma unroll
                for (int m = 0; m < 4; ++m) a[t][m] = *reinterpret_cast<const bf16x8*>(ap2[t][m] + k0);
#pragma unroll
            for (int t = 0; t < 2; ++t)
#pragma unroll
                for (int m = 0; m < 4; ++m)
#pragma unroll
                    for (int n = 0; n < 4; ++n)
                        acc[t][m][n] = __builtin_amdgcn_mfma_f32_16x16x32_bf16(a[t][m], b[n], acc[t][m][n], 0, 0, 0);
        }

        float bs[4];
#pragma unroll
        for (int n = 0; n < 4; ++n) bs[n] = bias[l * 256 + col0 + n * 16 + l16];

        float s[4], s2[4];
#pragma unroll
        for (int n = 0; n < 4; ++n) { s[n] = 0.f; s2[n] = 0.f; }

        unsigned short* Cout = Couts[l];
#pragma unroll
        for (int t = 0; t < 2; ++t)
#pragma unroll
            for (int m = 0; m < 4; ++m)
#pragma unroll
                for (int r = 0; r < 4; ++r) {
                    long long grow = bm + t * 64 + m * 16 + khi * 4 + r;
                    if (grow >= N) continue;
#pragma unroll
                    for (int n = 0; n < 4; ++n) {
                        int gcol = col0 + n * 16 + l16;
                        float v = acc[t][m][n][r] + bs[n];
                        Cout[grow * 256 + gcol] = f2bf(v);
                        s[n] += v;
                        s2[n] = fmaf(v, v, s2[n]);
                    }
                }

        float* st = stats + l * 1024;
#pragma unroll
        for (int n = 0; n < 4; ++n) {
            float a = s[n], b2 = s2[n];
            a += __shfl_xor(a, 16); a += __shfl_xor(a, 32);
            b2 += __shfl_xor(b2, 16); b2 += __shfl_xor(b2, 32);
            if (khi == 0) {
                int c = col0 + n * 16 + l16;
                atomicAdd(&st[c], a);
                atomicAdd(&st[256 + c], b2);
            }
        }
    }
}

// ---------------- gemm256bn: C = [Ha | bnrelu(G)] @ Wf^T + bias, + BN stats ----------------
__global__ __launch_bounds__(256) void gemm256bn_kernel(
    const unsigned short* __restrict__ A1, const unsigned short* __restrict__ A2,
    const float* __restrict__ kp, const unsigned short* __restrict__ Btf,
    const float* __restrict__ bias, unsigned short* __restrict__ Cout,
    float* __restrict__ stats, int N)
{
    const int lane = threadIdx.x & 63;
    const int wave = threadIdx.x >> 6;
    const int l16 = lane & 15;
    const int khi = lane >> 4;
    const long long bm = (long long)blockIdx.x * 128;
    const int col0 = wave * 64;

    f32x4 acc[2][4][4];
#pragma unroll
    for (int t = 0; t < 2; ++t)
#pragma unroll
        for (int m = 0; m < 4; ++m)
#pragma unroll
            for (int n = 0; n < 4; ++n) acc[t][m][n] = (f32x4){0.f, 0.f, 0.f, 0.f};

    const unsigned short* bp[4];
#pragma unroll
    for (int n = 0; n < 4; ++n)
        bp[n] = Btf + (size_t)(col0 + n * 16 + l16) * 512 + khi * 8;

    // segment 1: A1 (Ha), no BN
    {
        const unsigned short* ap[2][4];
#pragma unroll
        for (int t = 0; t < 2; ++t)
#pragma unroll
            for (int m = 0; m < 4; ++m) {
                long long r = bm + t * 64 + m * 16 + l16;
                if (r >= N) r = 0;
                ap[t][m] = A1 + (size_t)r * 256 + khi * 8;
            }
        for (int k0 = 0; k0 < 256; k0 += 32) {
            bf16x8 b[4];
#pragma unroll
            for (int n = 0; n < 4; ++n) b[n] = *reinterpret_cast<const bf16x8*>(bp[n] + k0);
            bf16x8 a[2][4];
#pragma unroll
            for (int t = 0; t < 2; ++t)
#pragma unroll
                for (int m = 0; m < 4; ++m) a[t][m] = *reinterpret_cast<const bf16x8*>(ap[t][m] + k0);
#pragma unroll
            for (int t = 0; t < 2; ++t)
#pragma unroll
                for (int m = 0; m < 4; ++m)
#pragma unroll
                    for (int n = 0; n < 4; ++n)
                        acc[t][m][n] = __builtin_amdgcn_mfma_f32_16x16x32_bf16(a[t][m], b[n], acc[t][m][n], 0, 0, 0);
        }
    }
    // segment 2: A2 (G, pre-BN) with on-the-fly bn+relu
    {
        const unsigned short* ap[2][4];
#pragma unroll
        for (int t = 0; t < 2; ++t)
#pragma unroll
            for (int m = 0; m < 4; ++m) {
                long long r = bm + t * 64 + m * 16 + l16;
                if (r >= N) r = 0;
                ap[t][m] = A2 + (size_t)r * 256 + khi * 8;
            }
        for (int k0 = 0; k0 < 256; k0 += 32) {
            int ch0 = k0 + khi * 8;
            f32x4 s0 = *reinterpret_cast<const f32x4*>(kp + ch0);
            f32x4 s1 = *reinterpret_cast<const f32x4*>(kp + ch0 + 4);
            f32x4 t0 = *reinterpret_cast<const f32x4*>(kp + 256 + ch0);
            f32x4 t1 = *reinterpret_cast<const f32x4*>(kp + 256 + ch0 + 4);
            bf16x8 b[4];
#pragma unroll
            for (int n = 0; n < 4; ++n) b[n] = *reinterpret_cast<const bf16x8*>(bp[n] + 256 + k0);
            bf16x8 a[2][4];
#pragma unroll
            for (int t = 0; t < 2; ++t)
#pragma unroll
                for (int m = 0; m < 4; ++m) {
                    u16x8 raw = *reinterpret_cast<const u16x8*>(ap[t][m] + k0);
                    u16x8 ov;
#pragma unroll
                    for (int j = 0; j < 4; ++j) {
                        ov[j]     = f2bf(fmaxf(fmaf(bf2f(raw[j]),     s0[j], t0[j]), 0.f));
                        ov[4 + j] = f2bf(fmaxf(fmaf(bf2f(raw[4 + j]), s1[j], t1[j]), 0.f));
                    }
                    __builtin_memcpy(&a[t][m], &ov, 16);
                }
#pragma unroll
            for (int t = 0; t < 2; ++t)
#pragma unroll
                for (int m = 0; m < 4; ++m)
#pragma unroll
                    for (int n = 0; n < 4; ++n)
                        acc[t][m][n] = __builtin_amdgcn_mfma_f32_16x16x32_bf16(a[t][m], b[n], acc[t][m][n], 0, 0, 0);
        }
    }

    float bs[4];
#pragma unroll
    for (int n = 0; n < 4; ++n) bs[n] = bias[col0 + n * 16 + l16];

    float s[4], s2[4];
#pragma unroll
    for (int n = 0; n < 4; ++n) { s[n] = 0.f; s2[n] = 0.f; }

#pragma unroll
    for (int t = 0; t < 2; ++t)
#pragma unroll
        for (int m = 0; m < 4; ++m)
#pragma unroll
            for (int r = 0; r < 4; ++r) {
                long long grow = bm + t * 64 + m * 16 + khi * 4 + r;
                if (grow >= N) continue;
#pragma unroll
                for (int n = 0; n < 4; ++n) {
                    int gcol = col0 + n * 16 + l16;
                    float v = acc[t][m][n][r] + bs[n];
                    Cout[grow * 256 + gcol] = f2bf(v);
                    s[n] += v;
                    s2[n] = fmaf(v, v, s2[n]);
                }
            }

#pragma unroll
    for (int n = 0; n < 4; ++n) {
        float a = s[n], b2 = s2[n];
        a += __shfl_xor(a, 16); a += __shfl_xor(a, 32);
        b2 += __shfl_xor(b2, 16); b2 += __shfl_xor(b2, 32);
        if (khi == 0) {
            int c = col0 + n * 16 + l16;
            atomicAdd(&stats[c], a);
            atomicAdd(&stats[256 + c], b2);
        }
    }
}

// ---------------- BN finalize (single slot) ----------------
__global__ __launch_bounds__(256) void bn_finalize_kernel(
    const float* __restrict__ sums, const float* __restrict__ g,
    const float* __restrict__ be, float* __restrict__ kp, int N)
{
    const int c = threadIdx.x;
    float invN = 1.f / (float)N;
    float mean = sums[c] * invN;
    float var = sums[256 + c] * invN - mean * mean;
    float inv = rsqrtf(var + 1e-5f);
    float sc = g[c] * inv;
    kp[c] = sc;
    kp[256 + c] = be[c] - sc * mean;
}

// ---------------- BN finalize x3 (slots 0..2 with g/be [3][256]) ----------------
__global__ __launch_bounds__(256) void bn_finalize3_kernel(
    float* __restrict__ stats, const float* __restrict__ g,
    const float* __restrict__ be, int N)
{
    const int l = blockIdx.x;
    const int c = threadIdx.x;
    float* st = stats + (size_t)l * 1024;
    float invN = 1.f / (float)N;
    float mean = st[c] * invN;
    float var = st[256 + c] * invN - mean * mean;
    float inv = rsqrtf(var + 1e-5f);
    float sc = g[l * 256 + c] * inv;
    st[512 + c] = sc;
    st[768 + c] = be[l * 256 + c] - sc * mean;
}

// ---------------- final MFMA outproj ----------------
template<int KS, bool BN>
__device__ __forceinline__ void outproj_seg(
    const unsigned short* __restrict__ seg, const float* __restrict__ kp,
    const unsigned short* __restrict__ Wcb, int bOff,
    long long r0, long long r1, int l16, int khi, f32x4 acc[2][3])
{
    const unsigned short* a0p = seg + (size_t)r0 * KS + khi * 8;
    const unsigned short* a1p = seg + (size_t)r1 * KS + khi * 8;
#pragma unroll
    for (int k0 = 0; k0 < KS; k0 += 32) {
        bf16x8 a[2];
        a[0] = *reinterpret_cast<const bf16x8*>(a0p + k0);
        a[1] = *reinterpret_cast<const bf16x8*>(a1p + k0);
        if (BN) {
            int ch0 = k0 + khi * 8;
            f32x4 s0 = *reinterpret_cast<const f32x4*>(kp + ch0);
            f32x4 s1 = *reinterpret_cast<const f32x4*>(kp + ch0 + 4);
            f32x4 t0 = *reinterpret_cast<const f32x4*>(kp + 256 + ch0);
            f32x4 t1 = *reinterpret_cast<const f32x4*>(kp + 256 + ch0 + 4);
#pragma unroll
            for (int m = 0; m < 2; ++m) {
                u16x8 raw;
                __builtin_memcpy(&raw, &a[m], 16);
                u16x8 ov;
#pragma unroll
                for (int j = 0; j < 4; ++j) {
                    ov[j]     = f2bf(fmaxf(fmaf(bf2f(raw[j]),     s0[j], t0[j]), 0.f));
                    ov[4 + j] = f2bf(fmaxf(fmaf(bf2f(raw[4 + j]), s1[j], t1[j]), 0.f));
                }
                __builtin_memcpy(&a[m], &ov, 16);
            }
        }
        bf16x8 b[3];
#pragma unroll
        for (int nt = 0; nt < 3; ++nt)
            b[nt] = *reinterpret_cast<const bf16x8*>(Wcb + (size_t)(nt * 16 + l16) * 1280 + bOff + k0 + khi * 8);
#pragma unroll
        for (int m = 0; m < 2; ++m)
#pragma unroll
            for (int nt = 0; nt < 3; ++nt)
                acc[m][nt] = __builtin_amdgcn_mfma_f32_16x16x32_bf16(a[m], b[nt], acc[m][nt], 0, 0, 0);
    }
}

__global__ __launch_bounds__(256) void outproj_mfma_kernel(
    const unsigned short* __restrict__ x_bf,
    const unsigned short* __restrict__ F0, const float* __restrict__ kp0,
    const unsigned short* __restrict__ F1, const float* __restrict__ kp1,
    const unsigned short* __restrict__ F2, const float* __restrict__ kp2,
    const unsigned short* __restrict__ Wcb, const float* __restrict__ bc,
    float* __restrict__ out, int N)
{
    const int lane = threadIdx.x & 63;
    const int wave = threadIdx.x >> 6;
    const int l16 = lane & 15;
    const int khi = lane >> 4;
    const long long bm = (long long)blockIdx.x * 128 + wave * 32;

    long long r0 = bm + l16;        if (r0 >= N) r0 = 0;
    long long r1 = bm + 16 + l16;   if (r1 >= N) r1 = 0;

    f32x4 acc[2][3];
#pragma unroll
    for (int m = 0; m < 2; ++m)
#pragma unroll
        for (int nt = 0; nt < 3; ++nt) acc[m][nt] = (f32x4){0.f, 0.f, 0.f, 0.f};

    outproj_seg<512, false>(x_bf, nullptr, Wcb, 0,    r0, r1, l16, khi, acc);
    outproj_seg<256, true >(F0,   kp0,     Wcb, 512,  r0, r1, l16, khi, acc);
    outproj_seg<256, true >(F1,   kp1,     Wcb, 768,  r0, r1, l16, khi, acc);
    outproj_seg<256, true >(F2,   kp2,     Wcb, 1024, r0, r1, l16, khi, acc);

#pragma unroll
    for (int m = 0; m < 2; ++m)
#pragma unroll
        for (int nt = 0; nt < 3; ++nt)
#pragma unroll
            for (int r = 0; r < 4; ++r) {
                long long grow = bm + m * 16 + khi * 4 + r;
                int gcol = nt * 16 + l16;
                if (grow < N && gcol < 40)
                    out[grow * 40 + gcol] = acc[m][nt][r] + bc[gcol];
            }
}

// ---------------- host-side orchestration ----------------
extern "C" void kernel_launch(void* const* d_in, const int* in_sizes, int n_in,
                              void* d_out, int out_size, void* d_ws, size_t ws_size,
                              hipStream_t stream)
{
    const float* x      = (const float*)d_in[0];
    const int*   esrc   = (const int*)d_in[1];
    const int*   edst   = (const int*)d_in[2];
    const float* ew     = (const float*)d_in[3];
    const float* W_in   = (const float*)d_in[4];
    const float* SW_in  = (const float*)d_in[5];
    const float* b_in   = (const float*)d_in[6];
    const float* g_in   = (const float*)d_in[7];
    const float* be_in  = (const float*)d_in[8];
    const float* W_h    = (const float*)d_in[9];
    const float* SW_h   = (const float*)d_in[10];
    const float* b_h    = (const float*)d_in[11];
    const float* g_h    = (const float*)d_in[12];
    const float* be_h   = (const float*)d_in[13];
    const float* Wc     = (const float*)d_in[14];
    const float* bc     = (const float*)d_in[15];
    float* out = (float*)d_out;

    const int N = in_sizes[0] / 500;      // 100000
    const int n_edges = in_sizes[1];      // 3200000
    const int nb = (N + 255) / 256;

    // ---- workspace layout ----
    char* p = (char*)d_ws;
    unsigned short* x_bf = (unsigned short*)p; p += (size_t)N * 512 * 2;
    unsigned short* Xa   = (unsigned short*)p; p += (size_t)N * 512 * 2;   // F2 aliases
    unsigned short* Ha   = (unsigned short*)p; p += (size_t)N * 256 * 2;
    unsigned short* G1   = (unsigned short*)p; p += (size_t)N * 256 * 2;   // H2 aliases (G1 dead after j=1)
    unsigned short* G2   = (unsigned short*)p; p += (size_t)N * 256 * 2;
    unsigned short* F0   = (unsigned short*)p; p += (size_t)N * 256 * 2;
    unsigned short* F1   = (unsigned short*)p; p += (size_t)N * 256 * 2;
    unsigned short* H2   = G1;
    unsigned short* F2   = Xa;
    unsigned short* Wf_in = (unsigned short*)p; p += (size_t)3 * 256 * 1024 * 2;
    unsigned short* Wf_h  = (unsigned short*)p; p += (size_t)3 * 256 * 512 * 2;
    unsigned short* Wcb   = (unsigned short*)p; p += (size_t)48 * 1280 * 2;
    float* stats = (float*)p; p += (size_t)6 * 1024 * 4;
    int* cnt     = (int*)p; p += (size_t)N * 4;
    int* excl    = (int*)p; p += (size_t)N * 4;
    int* blocksums = (int*)p; p += 2048 * 4;
    int* row_ptr = (int*)p; p += (size_t)(N + 1) * 4 + 4;
    int* heads   = (int*)p; p += (size_t)N * 4;
    int2* meta   = (int2*)p;

    // ---- preprocessing ----
    hipMemsetAsync(stats, 0, (size_t)6 * 1024 * sizeof(float) + (size_t)N * sizeof(int), stream);
    hipLaunchKernelGGL(transpose_fused_kernel, dim3(2048), dim3(256), 0, stream,
                       W_in, SW_in, Wf_in, 500, 512, 3);
    hipLaunchKernelGGL(transpose_fused_kernel, dim3(1024), dim3(256), 0, stream,
                       W_h, SW_h, Wf_h, 256, 256, 3);
    hipLaunchKernelGGL(transpose_wc_kernel, dim3(240), dim3(256), 0, stream, Wc, Wcb);

    hipLaunchKernelGGL(hist_kernel, dim3(4096), dim3(256), 0, stream, edst, cnt, n_edges);
    hipLaunchKernelGGL(scan1_kernel, dim3(nb), dim3(256), 0, stream, cnt, excl, blocksums, N);
    hipLaunchKernelGGL(scan2_kernel, dim3(1), dim3(512), 0, stream, blocksums, nb);
    hipLaunchKernelGGL(scan3_kernel, dim3(nb), dim3(256), 0, stream,
                       excl, blocksums, row_ptr, heads, N, n_edges);
    hipLaunchKernelGGL(scatter_kernel, dim3(4096), dim3(256), 0, stream,
                       esrc, edst, ew, heads, meta, n_edges);

    hipLaunchKernelGGL(cvtx_kernel, dim3(4096), dim3(256), 0, stream, x, x_bf, N);

    hipLaunchKernelGGL(spmm512_kernel, dim3((N + 3) / 4), dim3(512), 0, stream,
                       row_ptr, meta, x_bf, Xa, N);

    dim3 blk(256);
    dim3 ggrid((N + 127) / 128);
    dim3 sgrid((N + 3) / 4);

    // ---- all three input-layer GEMMs fused: F0, G1, G2 + stats slots 0,1,2 ----
    hipLaunchKernelGGL(gemm512x3_kernel, ggrid, blk, 0, stream,
                       Xa, x_bf, Wf_in, b_in, F0, G1, G2, stats, N);
    hipLaunchKernelGGL(bn_finalize3_kernel, dim3(3), dim3(256), 0, stream,
                       stats, g_in, be_in, N);

    float* kp0 = stats + 0 * 1024 + 512;
    float* kp1 = stats + 1 * 1024 + 512;
    float* kp2 = stats + 2 * 1024 + 512;
    float* st3 = stats + 3 * 1024;
    float* st4 = stats + 4 * 1024;
    float* st5 = stats + 5 * 1024;

    // ---- j = 1: hidden GC on bn(G1) -> F1 ----
    hipLaunchKernelGGL(spmm256bn_kernel, sgrid, blk, 0, stream, row_ptr, meta, G1, kp1, Ha, N);
    hipLaunchKernelGGL(gemm256bn_kernel, ggrid, blk, 0, stream,
                       Ha, G1, kp1, Wf_h, b_h, F1, st3, N);
    hipLaunchKernelGGL(bn_finalize_kernel, dim3(1), dim3(256), 0, stream, st3, g_h, be_h, st3 + 512, N);

    // ---- j = 2: two hidden GCs on bn(G2) ----
    hipLaunchKernelGGL(spmm256bn_kernel, sgrid, blk, 0, stream, row_ptr, meta, G2, kp2, Ha, N);
    hipLaunchKernelGGL(gemm256bn_kernel, ggrid, blk, 0, stream,
                       Ha, G2, kp2, Wf_h + (size_t)1 * 256 * 512, b_h + 256, H2, st4, N);
    hipLaunchKernelGGL(bn_finalize_kernel, dim3(1), dim3(256), 0, stream, st4, g_h + 256, be_h + 256, st4 + 512, N);

    hipLaunchKernelGGL(spmm256bn_kernel, sgrid, blk, 0, stream, row_ptr, meta, H2, st4 + 512, Ha, N);
    hipLaunchKernelGGL(gemm256bn_kernel, ggrid, blk, 0, stream,
                       Ha, H2, st4 + 512, Wf_h + (size_t)2 * 256 * 512, b_h + 512, F2, st5, N);
    hipLaunchKernelGGL(bn_finalize_kernel, dim3(1), dim3(256), 0, stream, st5, g_h + 512, be_h + 512, st5 + 512, N);

    // ---- final: out = [x | bn(F0) | bn(F1) | bn(F2)] @ Wcb^T + bc ----
    hipLaunchKernelGGL(outproj_mfma_kernel, ggrid, blk, 0, stream,
                       x_bf, F0, kp0, F1, st3 + 512, F2, st5 + 512,
                       Wcb, bc, out, N);
}

// Round 9
// 2366.228 us; speedup vs baseline: 31.6095x; 1.2254x over previous
//
#include <hip/hip_runtime.h>

typedef __attribute__((ext_vector_type(8))) short bf16x8;
typedef __attribute__((ext_vector_type(4))) float f32x4;
typedef __attribute__((ext_vector_type(4))) unsigned short u16x4;
typedef __attribute__((ext_vector_type(8))) unsigned short u16x8;

__device__ __forceinline__ float bf2f(unsigned short u) {
    union { unsigned int i; float f; } v; v.i = ((unsigned int)u) << 16; return v.f;
}
__device__ __forceinline__ unsigned short f2bf(float f) {
    union { float f; unsigned int i; } v; v.f = f;
    unsigned int b = v.i;
    b += 0x7FFFu + ((b >> 16) & 1u);   // round-to-nearest-even
    return (unsigned short)(b >> 16);
}

// ---------------- fused weight transpose: W,SW [L][K][256] -> Wf[L][256][2*Kp] bf16 ----------------
__global__ __launch_bounds__(256) void transpose_fused_kernel(
    const float* __restrict__ W, const float* __restrict__ SW,
    unsigned short* __restrict__ Wf, int K, int Kp, int L)
{
    long long total = (long long)L * 256 * 2 * Kp;
    long long idx = (long long)blockIdx.x * blockDim.x + threadIdx.x;
    const long long stride = (long long)gridDim.x * blockDim.x;
    for (; idx < total; idx += stride) {
        int l = (int)(idx / ((long long)256 * 2 * Kp));
        long long rem = idx - (long long)l * 256 * 2 * Kp;
        int c = (int)(rem / (2 * Kp));
        int kk = (int)(rem - (long long)c * 2 * Kp);
        const float* src = (kk < Kp) ? W : SW;
        int k = (kk < Kp) ? kk : kk - Kp;
        float v = (k < K) ? src[((size_t)l * K + k) * 256 + c] : 0.f;
        Wf[idx] = f2bf(v);
    }
}

// ---------------- Wc[1268][40] fp32 -> Wcb[48][1280] bf16 (segment-mapped, padded) ----------------
__global__ __launch_bounds__(256) void transpose_wc_kernel(
    const float* __restrict__ Wc, unsigned short* __restrict__ Wcb)
{
    int idx = blockIdx.x * blockDim.x + threadIdx.x;
    if (idx >= 48 * 1280) return;
    int c = idx / 1280;
    int kk = idx - c * 1280;
    int src = -1;
    if (kk < 512)       { if (kk < 500) src = kk; }
    else if (kk < 768)  src = 500 + (kk - 512);
    else if (kk < 1024) src = 756 + (kk - 768);
    else                src = 1012 + (kk - 1024);
    float v = (c < 40 && src >= 0) ? Wc[(size_t)src * 40 + c] : 0.f;
    Wcb[idx] = f2bf(v);
}

// ---------------- x -> bf16 with pad 500->512 (streaming) ----------------
__global__ __launch_bounds__(256) void cvtx_kernel(
    const float* __restrict__ X, unsigned short* __restrict__ Xb, int N)
{
    long long total = (long long)N * 64;
    long long idx = (long long)blockIdx.x * blockDim.x + threadIdx.x;
    const long long stride = (long long)gridDim.x * blockDim.x;
    for (; idx < total; idx += stride) {
        long long row = idx >> 6;
        int g = (int)(idx & 63);
        int k0 = g * 8;
        float v[8];
        if (k0 + 8 <= 500) {
            float4 q0 = *reinterpret_cast<const float4*>(X + row * 500 + k0);
            float4 q1 = *reinterpret_cast<const float4*>(X + row * 500 + k0 + 4);
            v[0] = q0.x; v[1] = q0.y; v[2] = q0.z; v[3] = q0.w;
            v[4] = q1.x; v[5] = q1.y; v[6] = q1.z; v[7] = q1.w;
        } else {
#pragma unroll
            for (int j = 0; j < 8; ++j) v[j] = (k0 + j < 500) ? X[row * 500 + k0 + j] : 0.f;
        }
        u16x8 o;
#pragma unroll
        for (int j = 0; j < 8; ++j) o[j] = f2bf(v[j]);
        *reinterpret_cast<u16x8*>(Xb + row * 512 + k0) = o;
    }
}

// ---------------- CSR build ----------------
__global__ __launch_bounds__(256) void hist_kernel(
    const int* __restrict__ edst, int* __restrict__ cnt, int n_edges)
{
    int idx = blockIdx.x * blockDim.x + threadIdx.x;
    const int stride = gridDim.x * blockDim.x;
    for (; idx < n_edges; idx += stride) atomicAdd(&cnt[edst[idx]], 1);
}

__global__ __launch_bounds__(256) void scan1_kernel(
    const int* __restrict__ cnt, int* __restrict__ excl,
    int* __restrict__ blocksums, int n)
{
    __shared__ int s[256];
    const int tid = threadIdx.x;
    const int i = blockIdx.x * 256 + tid;
    int v = (i < n) ? cnt[i] : 0;
    s[tid] = v;
    __syncthreads();
#pragma unroll
    for (int off = 1; off < 256; off <<= 1) {
        int t = s[tid];
        if (tid >= off) t += s[tid - off];
        __syncthreads();
        s[tid] = t;
        __syncthreads();
    }
    if (i < n) excl[i] = s[tid] - v;
    if (tid == 255) blocksums[blockIdx.x] = s[255];
}

__global__ __launch_bounds__(512) void scan2_kernel(int* __restrict__ blocksums, int nb)
{
    __shared__ int s[512];
    const int tid = threadIdx.x;
    int v = (tid < nb) ? blocksums[tid] : 0;
    s[tid] = v;
    __syncthreads();
#pragma unroll
    for (int off = 1; off < 512; off <<= 1) {
        int t = s[tid];
        if (tid >= off) t += s[tid - off];
        __syncthreads();
        s[tid] = t;
        __syncthreads();
    }
    if (tid < nb) blocksums[tid] = s[tid] - v;
}

__global__ __launch_bounds__(256) void scan3_kernel(
    const int* __restrict__ excl, const int* __restrict__ blocksums,
    int* __restrict__ row_ptr, int* __restrict__ heads, int n, int n_edges)
{
    const int i = blockIdx.x * 256 + threadIdx.x;
    if (i < n) {
        int v = excl[i] + blocksums[i >> 8];
        row_ptr[i] = v;
        heads[i] = v;
    }
    if (i == 0) row_ptr[n] = n_edges;
}

__global__ __launch_bounds__(256) void scatter_kernel(
    const int* __restrict__ esrc, const int* __restrict__ edst,
    const float* __restrict__ ew, int* __restrict__ heads,
    int2* __restrict__ meta, int n_edges)
{
    int idx = blockIdx.x * blockDim.x + threadIdx.x;
    const int stride = gridDim.x * blockDim.x;
    for (; idx < n_edges; idx += stride) {
        int d = edst[idx];
        int pos = atomicAdd(&heads[d], 1);
        meta[pos] = make_int2(esrc[idx], __float_as_int(ew[idx]));
    }
}

// ---------------- SpMM 256-wide with on-the-fly BN+ReLU on source rows ----------------
__global__ __launch_bounds__(256) void spmm256bn_kernel(
    const int* __restrict__ row_ptr, const int2* __restrict__ meta,
    const unsigned short* __restrict__ S, const float* __restrict__ kp,
    unsigned short* __restrict__ O, int N)
{
    const int wave = threadIdx.x >> 6;
    const int lane = threadIdx.x & 63;
    int node = blockIdx.x * 4 + wave;
    if (node >= N) return;
    node = __builtin_amdgcn_readfirstlane(node);
    const int beg = row_ptr[node];
    const int end = row_ptr[node + 1];
    const f32x4 sc = *reinterpret_cast<const f32x4*>(kp + lane * 4);
    const f32x4 sh = *reinterpret_cast<const f32x4*>(kp + 256 + lane * 4);
    float a0 = 0.f, a1 = 0.f, a2 = 0.f, a3 = 0.f;

    int e = beg;
    for (; e + 12 <= end; e += 12) {
        int2 m[12];
#pragma unroll
        for (int j = 0; j < 12; ++j) m[j] = meta[e + j];
        u16x4 v[12];
#pragma unroll
        for (int j = 0; j < 12; ++j)
            v[j] = *reinterpret_cast<const u16x4*>(S + (size_t)m[j].x * 256 + lane * 4);
#pragma unroll
        for (int j = 0; j < 12; ++j) {
            float w = __int_as_float(m[j].y);
            a0 = fmaf(w, fmaxf(fmaf(bf2f(v[j][0]), sc[0], sh[0]), 0.f), a0);
            a1 = fmaf(w, fmaxf(fmaf(bf2f(v[j][1]), sc[1], sh[1]), 0.f), a1);
            a2 = fmaf(w, fmaxf(fmaf(bf2f(v[j][2]), sc[2], sh[2]), 0.f), a2);
            a3 = fmaf(w, fmaxf(fmaf(bf2f(v[j][3]), sc[3], sh[3]), 0.f), a3);
        }
    }
    for (; e < end; ++e) {
        int2 m = meta[e];
        float w = __int_as_float(m.y);
        u16x4 v = *reinterpret_cast<const u16x4*>(S + (size_t)m.x * 256 + lane * 4);
        a0 = fmaf(w, fmaxf(fmaf(bf2f(v[0]), sc[0], sh[0]), 0.f), a0);
        a1 = fmaf(w, fmaxf(fmaf(bf2f(v[1]), sc[1], sh[1]), 0.f), a1);
        a2 = fmaf(w, fmaxf(fmaf(bf2f(v[2]), sc[2], sh[2]), 0.f), a2);
        a3 = fmaf(w, fmaxf(fmaf(bf2f(v[3]), sc[3], sh[3]), 0.f), a3);
    }
    u16x4 o;
    o[0] = f2bf(a0); o[1] = f2bf(a1); o[2] = f2bf(a2); o[3] = f2bf(a3);
    *reinterpret_cast<u16x4*>(O + (size_t)node * 256 + lane * 4) = o;
}

// ---------------- SpMM 512-wide: TWO waves per node (half-row each), 8-deep ----------------
__global__ __launch_bounds__(512) void spmm512_kernel(
    const int* __restrict__ row_ptr, const int2* __restrict__ meta,
    const unsigned short* __restrict__ S, unsigned short* __restrict__ O, int N)
{
    const int wv = threadIdx.x >> 6;
    const int lane = threadIdx.x & 63;
    const int half = wv & 1;
    int node = blockIdx.x * 4 + (wv >> 1);
    if (node >= N) return;
    node = __builtin_amdgcn_readfirstlane(node);
    const int beg = row_ptr[node];
    const int end = row_ptr[node + 1];
    const int coff = half * 256 + lane * 4;
    float a0 = 0.f, a1 = 0.f, a2 = 0.f, a3 = 0.f;

    int e = beg;
    for (; e + 8 <= end; e += 8) {
        int2 m[8];
#pragma unroll
        for (int j = 0; j < 8; ++j) m[j] = meta[e + j];
        u16x4 v[8];
#pragma unroll
        for (int j = 0; j < 8; ++j)
            v[j] = *reinterpret_cast<const u16x4*>(S + (size_t)m[j].x * 512 + coff);
#pragma unroll
        for (int j = 0; j < 8; ++j) {
            float w = __int_as_float(m[j].y);
            a0 = fmaf(w, bf2f(v[j][0]), a0);
            a1 = fmaf(w, bf2f(v[j][1]), a1);
            a2 = fmaf(w, bf2f(v[j][2]), a2);
            a3 = fmaf(w, bf2f(v[j][3]), a3);
        }
    }
    for (; e < end; ++e) {
        int2 m = meta[e];
        float w = __int_as_float(m.y);
        u16x4 v = *reinterpret_cast<const u16x4*>(S + (size_t)m.x * 512 + coff);
        a0 = fmaf(w, bf2f(v[0]), a0);
        a1 = fmaf(w, bf2f(v[1]), a1);
        a2 = fmaf(w, bf2f(v[2]), a2);
        a3 = fmaf(w, bf2f(v[3]), a3);
    }
    u16x4 o;
    o[0] = f2bf(a0); o[1] = f2bf(a1); o[2] = f2bf(a2); o[3] = f2bf(a3);
    *reinterpret_cast<u16x4*>(O + (size_t)node * 512 + coff) = o;
}

// ---------------- LDS-staged MFMA GEMM: C[N,256] = [A1|A2] @ Btf^T + bias, + BN stats ----------------
// Tile 128 (M) x 128 (N-cols), 4 waves (2x2), each wave 64x64 (acc[4][4]).
// BK=64; A-tile/B-tile in LDS, XOR-swizzled (chunk ^= row&7) against stride-128B bank conflicts.
// BN2: apply BN+ReLU to A2 fragments (pre-BN hidden state) on the fly.
template<int K1, int K2, bool BN2>
__global__ __launch_bounds__(256) void gemm_lds_kernel(
    const unsigned short* __restrict__ A1, const unsigned short* __restrict__ A2,
    const float* __restrict__ kp, const unsigned short* __restrict__ Btf,
    const float* __restrict__ bias, unsigned short* __restrict__ Cout,
    float* __restrict__ stats, int N)
{
    constexpr int KT = K1 + K2;
    __shared__ unsigned short Atile[128 * 64];
    __shared__ unsigned short Btile[128 * 64];

    const int lane = threadIdx.x & 63;
    const int wave = threadIdx.x >> 6;
    const int l16 = lane & 15;
    const int khi = lane >> 4;
    const int wm = wave >> 1;           // row half (0/1)
    const int wn = wave & 1;            // col half (0/1)
    const long long bm = (long long)blockIdx.x * 128;
    const int col0 = blockIdx.y * 128;

    const int srow8 = lane >> 3;        // 0..7 (row within 8-row staging group)
    const int sc16 = lane & 7;          // 0..7 (16B chunk within 128B row)

    f32x4 acc[4][4];
#pragma unroll
    for (int m = 0; m < 4; ++m)
#pragma unroll
        for (int n = 0; n < 4; ++n) acc[m][n] = (f32x4){0.f, 0.f, 0.f, 0.f};

    for (int k0 = 0; k0 < KT; k0 += 64) {
        const unsigned short* Aseg;
        int koff, astr;
        if (k0 < K1) { Aseg = A1; koff = k0; astr = K1; }
        else         { Aseg = A2; koff = k0 - K1; astr = K2; }
        const bool bnseg = BN2 && (k0 >= K1);

        // ---- global -> regs (overlaps previous compute) ----
        u16x8 av[4], bv[4];
        int rloc[4];
#pragma unroll
        for (int i = 0; i < 4; ++i) {
            int r = wave * 32 + i * 8 + srow8;
            rloc[i] = r;
            long long gr = bm + r;
            if (gr >= N) gr = N - 1;
            av[i] = *reinterpret_cast<const u16x8*>(Aseg + (size_t)gr * astr + koff + sc16 * 8);
            bv[i] = *reinterpret_cast<const u16x8*>(Btf + (size_t)(col0 + r) * KT + k0 + sc16 * 8);
        }
        __syncthreads();   // previous iteration's LDS reads complete
        // ---- regs -> LDS, swizzled ----
#pragma unroll
        for (int i = 0; i < 4; ++i) {
            int r = rloc[i];
            int cw = (sc16 ^ (r & 7)) * 8;
            *reinterpret_cast<u16x8*>(&Atile[r * 64 + cw]) = av[i];
            *reinterpret_cast<u16x8*>(&Btile[r * 64 + cw]) = bv[i];
        }
        __syncthreads();

        // ---- compute: two k-chunks of 32 ----
#pragma unroll
        for (int kk = 0; kk < 2; ++kk) {
            const int kc = kk * 4 + khi;   // 16B chunk index 0..7
            bf16x8 a[4], b[4];
#pragma unroll
            for (int m = 0; m < 4; ++m) {
                int ra = wm * 64 + m * 16 + l16;
                a[m] = *reinterpret_cast<const bf16x8*>(&Atile[ra * 64 + ((kc ^ (ra & 7)) * 8)]);
            }
            if (bnseg) {
                int ch = (k0 - K1) + kk * 32 + khi * 8;
                f32x4 s0 = *reinterpret_cast<const f32x4*>(kp + ch);
                f32x4 s1 = *reinterpret_cast<const f32x4*>(kp + ch + 4);
                f32x4 t0 = *reinterpret_cast<const f32x4*>(kp + 256 + ch);
                f32x4 t1 = *reinterpret_cast<const f32x4*>(kp + 256 + ch + 4);
#pragma unroll
                for (int m = 0; m < 4; ++m) {
                    u16x8 raw;
                    __builtin_memcpy(&raw, &a[m], 16);
                    u16x8 ov;
#pragma unroll
                    for (int j = 0; j < 4; ++j) {
                        ov[j]     = f2bf(fmaxf(fmaf(bf2f(raw[j]),     s0[j], t0[j]), 0.f));
                        ov[4 + j] = f2bf(fmaxf(fmaf(bf2f(raw[4 + j]), s1[j], t1[j]), 0.f));
                    }
                    __builtin_memcpy(&a[m], &ov, 16);
                }
            }
#pragma unroll
            for (int n = 0; n < 4; ++n) {
                int rb = wn * 64 + n * 16 + l16;
                b[n] = *reinterpret_cast<const bf16x8*>(&Btile[rb * 64 + ((kc ^ (rb & 7)) * 8)]);
            }
#pragma unroll
            for (int m = 0; m < 4; ++m)
#pragma unroll
                for (int n = 0; n < 4; ++n)
                    acc[m][n] = __builtin_amdgcn_mfma_f32_16x16x32_bf16(a[m], b[n], acc[m][n], 0, 0, 0);
        }
    }

    float bs[4];
#pragma unroll
    for (int n = 0; n < 4; ++n) bs[n] = bias[col0 + wn * 64 + n * 16 + l16];

    float s[4], s2[4];
#pragma unroll
    for (int n = 0; n < 4; ++n) { s[n] = 0.f; s2[n] = 0.f; }

#pragma unroll
    for (int m = 0; m < 4; ++m)
#pragma unroll
        for (int r = 0; r < 4; ++r) {
            long long grow = bm + wm * 64 + m * 16 + khi * 4 + r;
            if (grow >= N) continue;
#pragma unroll
            for (int n = 0; n < 4; ++n) {
                int gcol = col0 + wn * 64 + n * 16 + l16;
                float v = acc[m][n][r] + bs[n];
                Cout[grow * 256 + gcol] = f2bf(v);
                s[n] += v;
                s2[n] = fmaf(v, v, s2[n]);
            }
        }

#pragma unroll
    for (int n = 0; n < 4; ++n) {
        float a = s[n], b2 = s2[n];
        a += __shfl_xor(a, 16); a += __shfl_xor(a, 32);
        b2 += __shfl_xor(b2, 16); b2 += __shfl_xor(b2, 32);
        if (khi == 0) {
            int c = col0 + wn * 64 + n * 16 + l16;
            atomicAdd(&stats[c], a);
            atomicAdd(&stats[256 + c], b2);
        }
    }
}

// ---------------- BN finalize (single slot) ----------------
__global__ __launch_bounds__(256) void bn_finalize_kernel(
    const float* __restrict__ sums, const float* __restrict__ g,
    const float* __restrict__ be, float* __restrict__ kp, int N)
{
    const int c = threadIdx.x;
    float invN = 1.f / (float)N;
    float mean = sums[c] * invN;
    float var = sums[256 + c] * invN - mean * mean;
    float inv = rsqrtf(var + 1e-5f);
    float sc = g[c] * inv;
    kp[c] = sc;
    kp[256 + c] = be[c] - sc * mean;
}

// ---------------- BN finalize x3 (slots 0..2 with g/be [3][256]) ----------------
__global__ __launch_bounds__(256) void bn_finalize3_kernel(
    float* __restrict__ stats, const float* __restrict__ g,
    const float* __restrict__ be, int N)
{
    const int l = blockIdx.x;
    const int c = threadIdx.x;
    float* st = stats + (size_t)l * 1024;
    float invN = 1.f / (float)N;
    float mean = st[c] * invN;
    float var = st[256 + c] * invN - mean * mean;
    float inv = rsqrtf(var + 1e-5f);
    float sc = g[l * 256 + c] * inv;
    st[512 + c] = sc;
    st[768 + c] = be[l * 256 + c] - sc * mean;
}

// ---------------- final MFMA outproj ----------------
template<int KS, bool BN>
__device__ __forceinline__ void outproj_seg(
    const unsigned short* __restrict__ seg, const float* __restrict__ kp,
    const unsigned short* __restrict__ Wcb, int bOff,
    long long r0, long long r1, int l16, int khi, f32x4 acc[2][3])
{
    const unsigned short* a0p = seg + (size_t)r0 * KS + khi * 8;
    const unsigned short* a1p = seg + (size_t)r1 * KS + khi * 8;
#pragma unroll
    for (int k0 = 0; k0 < KS; k0 += 32) {
        bf16x8 a[2];
        a[0] = *reinterpret_cast<const bf16x8*>(a0p + k0);
        a[1] = *reinterpret_cast<const bf16x8*>(a1p + k0);
        if (BN) {
            int ch0 = k0 + khi * 8;
            f32x4 s0 = *reinterpret_cast<const f32x4*>(kp + ch0);
            f32x4 s1 = *reinterpret_cast<const f32x4*>(kp + ch0 + 4);
            f32x4 t0 = *reinterpret_cast<const f32x4*>(kp + 256 + ch0);
            f32x4 t1 = *reinterpret_cast<const f32x4*>(kp + 256 + ch0 + 4);
#pragma unroll
            for (int m = 0; m < 2; ++m) {
                u16x8 raw;
                __builtin_memcpy(&raw, &a[m], 16);
                u16x8 ov;
#pragma unroll
                for (int j = 0; j < 4; ++j) {
                    ov[j]     = f2bf(fmaxf(fmaf(bf2f(raw[j]),     s0[j], t0[j]), 0.f));
                    ov[4 + j] = f2bf(fmaxf(fmaf(bf2f(raw[4 + j]), s1[j], t1[j]), 0.f));
                }
                __builtin_memcpy(&a[m], &ov, 16);
            }
        }
        bf16x8 b[3];
#pragma unroll
        for (int nt = 0; nt < 3; ++nt)
            b[nt] = *reinterpret_cast<const bf16x8*>(Wcb + (size_t)(nt * 16 + l16) * 1280 + bOff + k0 + khi * 8);
#pragma unroll
        for (int m = 0; m < 2; ++m)
#pragma unroll
            for (int nt = 0; nt < 3; ++nt)
                acc[m][nt] = __builtin_amdgcn_mfma_f32_16x16x32_bf16(a[m], b[nt], acc[m][nt], 0, 0, 0);
    }
}

__global__ __launch_bounds__(256) void outproj_mfma_kernel(
    const unsigned short* __restrict__ x_bf,
    const unsigned short* __restrict__ F0, const float* __restrict__ kp0,
    const unsigned short* __restrict__ F1, const float* __restrict__ kp1,
    const unsigned short* __restrict__ F2, const float* __restrict__ kp2,
    const unsigned short* __restrict__ Wcb, const float* __restrict__ bc,
    float* __restrict__ out, int N)
{
    const int lane = threadIdx.x & 63;
    const int wave = threadIdx.x >> 6;
    const int l16 = lane & 15;
    const int khi = lane >> 4;
    const long long bm = (long long)blockIdx.x * 128 + wave * 32;

    long long r0 = bm + l16;        if (r0 >= N) r0 = 0;
    long long r1 = bm + 16 + l16;   if (r1 >= N) r1 = 0;

    f32x4 acc[2][3];
#pragma unroll
    for (int m = 0; m < 2; ++m)
#pragma unroll
        for (int nt = 0; nt < 3; ++nt) acc[m][nt] = (f32x4){0.f, 0.f, 0.f, 0.f};

    outproj_seg<512, false>(x_bf, nullptr, Wcb, 0,    r0, r1, l16, khi, acc);
    outproj_seg<256, true >(F0,   kp0,     Wcb, 512,  r0, r1, l16, khi, acc);
    outproj_seg<256, true >(F1,   kp1,     Wcb, 768,  r0, r1, l16, khi, acc);
    outproj_seg<256, true >(F2,   kp2,     Wcb, 1024, r0, r1, l16, khi, acc);

#pragma unroll
    for (int m = 0; m < 2; ++m)
#pragma unroll
        for (int nt = 0; nt < 3; ++nt)
#pragma unroll
            for (int r = 0; r < 4; ++r) {
                long long grow = bm + m * 16 + khi * 4 + r;
                int gcol = nt * 16 + l16;
                if (grow < N && gcol < 40)
                    out[grow * 40 + gcol] = acc[m][nt][r] + bc[gcol];
            }
}

// ---------------- host-side orchestration ----------------
extern "C" void kernel_launch(void* const* d_in, const int* in_sizes, int n_in,
                              void* d_out, int out_size, void* d_ws, size_t ws_size,
                              hipStream_t stream)
{
    const float* x      = (const float*)d_in[0];
    const int*   esrc   = (const int*)d_in[1];
    const int*   edst   = (const int*)d_in[2];
    const float* ew     = (const float*)d_in[3];
    const float* W_in   = (const float*)d_in[4];
    const float* SW_in  = (const float*)d_in[5];
    const float* b_in   = (const float*)d_in[6];
    const float* g_in   = (const float*)d_in[7];
    const float* be_in  = (const float*)d_in[8];
    const float* W_h    = (const float*)d_in[9];
    const float* SW_h   = (const float*)d_in[10];
    const float* b_h    = (const float*)d_in[11];
    const float* g_h    = (const float*)d_in[12];
    const float* be_h   = (const float*)d_in[13];
    const float* Wc     = (const float*)d_in[14];
    const float* bc     = (const float*)d_in[15];
    float* out = (float*)d_out;

    const int N = in_sizes[0] / 500;      // 100000
    const int n_edges = in_sizes[1];      // 3200000
    const int nb = (N + 255) / 256;

    // ---- workspace layout ----
    char* p = (char*)d_ws;
    unsigned short* x_bf = (unsigned short*)p; p += (size_t)N * 512 * 2;
    unsigned short* Xa   = (unsigned short*)p; p += (size_t)N * 512 * 2;   // F2 aliases
    unsigned short* Ha   = (unsigned short*)p; p += (size_t)N * 256 * 2;
    unsigned short* G1   = (unsigned short*)p; p += (size_t)N * 256 * 2;   // H2 aliases
    unsigned short* G2   = (unsigned short*)p; p += (size_t)N * 256 * 2;
    unsigned short* F0   = (unsigned short*)p; p += (size_t)N * 256 * 2;
    unsigned short* F1   = (unsigned short*)p; p += (size_t)N * 256 * 2;
    unsigned short* H2   = G1;
    unsigned short* F2   = Xa;
    unsigned short* Wf_in = (unsigned short*)p; p += (size_t)3 * 256 * 1024 * 2;
    unsigned short* Wf_h  = (unsigned short*)p; p += (size_t)3 * 256 * 512 * 2;
    unsigned short* Wcb   = (unsigned short*)p; p += (size_t)48 * 1280 * 2;
    float* stats = (float*)p; p += (size_t)6 * 1024 * 4;
    int* cnt     = (int*)p; p += (size_t)N * 4;
    int* excl    = (int*)p; p += (size_t)N * 4;
    int* blocksums = (int*)p; p += 2048 * 4;
    int* row_ptr = (int*)p; p += (size_t)(N + 1) * 4 + 4;
    int* heads   = (int*)p; p += (size_t)N * 4;
    int2* meta   = (int2*)p;

    // ---- preprocessing ----
    hipMemsetAsync(stats, 0, (size_t)6 * 1024 * sizeof(float) + (size_t)N * sizeof(int), stream);
    hipLaunchKernelGGL(transpose_fused_kernel, dim3(2048), dim3(256), 0, stream,
                       W_in, SW_in, Wf_in, 500, 512, 3);
    hipLaunchKernelGGL(transpose_fused_kernel, dim3(1024), dim3(256), 0, stream,
                       W_h, SW_h, Wf_h, 256, 256, 3);
    hipLaunchKernelGGL(transpose_wc_kernel, dim3(240), dim3(256), 0, stream, Wc, Wcb);

    hipLaunchKernelGGL(hist_kernel, dim3(4096), dim3(256), 0, stream, edst, cnt, n_edges);
    hipLaunchKernelGGL(scan1_kernel, dim3(nb), dim3(256), 0, stream, cnt, excl, blocksums, N);
    hipLaunchKernelGGL(scan2_kernel, dim3(1), dim3(512), 0, stream, blocksums, nb);
    hipLaunchKernelGGL(scan3_kernel, dim3(nb), dim3(256), 0, stream,
                       excl, blocksums, row_ptr, heads, N, n_edges);
    hipLaunchKernelGGL(scatter_kernel, dim3(4096), dim3(256), 0, stream,
                       esrc, edst, ew, heads, meta, n_edges);

    hipLaunchKernelGGL(cvtx_kernel, dim3(4096), dim3(256), 0, stream, x, x_bf, N);

    hipLaunchKernelGGL(spmm512_kernel, dim3((N + 3) / 4), dim3(512), 0, stream,
                       row_ptr, meta, x_bf, Xa, N);

    dim3 blk(256);
    dim3 ggrid2((N + 127) / 128, 2);       // LDS GEMM: 128-row x 128-col tiles
    dim3 ogrid((N + 127) / 128);
    dim3 sgrid((N + 3) / 4);

    // ---- three input-layer GEMMs (LDS-staged; Xa/x_bf stay L3-resident across them) ----
    hipLaunchKernelGGL((gemm_lds_kernel<512, 512, false>), ggrid2, blk, 0, stream,
                       Xa, x_bf, (const float*)nullptr, Wf_in, b_in, F0, stats + 0 * 1024, N);
    hipLaunchKernelGGL((gemm_lds_kernel<512, 512, false>), ggrid2, blk, 0, stream,
                       Xa, x_bf, (const float*)nullptr, Wf_in + (size_t)1 * 256 * 1024, b_in + 256, G1, stats + 1 * 1024, N);
    hipLaunchKernelGGL((gemm_lds_kernel<512, 512, false>), ggrid2, blk, 0, stream,
                       Xa, x_bf, (const float*)nullptr, Wf_in + (size_t)2 * 256 * 1024, b_in + 512, G2, stats + 2 * 1024, N);
    hipLaunchKernelGGL(bn_finalize3_kernel, dim3(3), dim3(256), 0, stream,
                       stats, g_in, be_in, N);

    float* kp0 = stats + 0 * 1024 + 512;
    float* kp1 = stats + 1 * 1024 + 512;
    float* kp2 = stats + 2 * 1024 + 512;
    float* st3 = stats + 3 * 1024;
    float* st4 = stats + 4 * 1024;
    float* st5 = stats + 5 * 1024;

    // ---- j = 1: hidden GC on bn(G1) -> F1 ----
    hipLaunchKernelGGL(spmm256bn_kernel, sgrid, blk, 0, stream, row_ptr, meta, G1, kp1, Ha, N);
    hipLaunchKernelGGL((gemm_lds_kernel<256, 256, true>), ggrid2, blk, 0, stream,
                       Ha, G1, kp1, Wf_h, b_h, F1, st3, N);
    hipLaunchKernelGGL(bn_finalize_kernel, dim3(1), dim3(256), 0, stream, st3, g_h, be_h, st3 + 512, N);

    // ---- j = 2: two hidden GCs on bn(G2) ----
    hipLaunchKernelGGL(spmm256bn_kernel, sgrid, blk, 0, stream, row_ptr, meta, G2, kp2, Ha, N);
    hipLaunchKernelGGL((gemm_lds_kernel<256, 256, true>), ggrid2, blk, 0, stream,
                       Ha, G2, kp2, Wf_h + (size_t)1 * 256 * 512, b_h + 256, H2, st4, N);
    hipLaunchKernelGGL(bn_finalize_kernel, dim3(1), dim3(256), 0, stream, st4, g_h + 256, be_h + 256, st4 + 512, N);

    hipLaunchKernelGGL(spmm256bn_kernel, sgrid, blk, 0, stream, row_ptr, meta, H2, st4 + 512, Ha, N);
    hipLaunchKernelGGL((gemm_lds_kernel<256, 256, true>), ggrid2, blk, 0, stream,
                       Ha, H2, st4 + 512, Wf_h + (size_t)2 * 256 * 512, b_h + 512, F2, st5, N);
    hipLaunchKernelGGL(bn_finalize_kernel, dim3(1), dim3(256), 0, stream, st5, g_h + 512, be_h + 512, st5 + 512, N);

    // ---- final: out = [x | bn(F0) | bn(F1) | bn(F2)] @ Wcb^T + bc ----
    hipLaunchKernelGGL(outproj_mfma_kernel, ogrid, blk, 0, stream,
                       x_bf, F0, kp0, F1, st3 + 512, F2, st5 + 512,
                       Wcb, bc, out, N);
}

// Round 10
// 1955.285 us; speedup vs baseline: 38.2529x; 1.2102x over previous
//
#include <hip/hip_runtime.h>

typedef __attribute__((ext_vector_type(8))) short bf16x8;
typedef __attribute__((ext_vector_type(2))) float f32x2;
typedef __attribute__((ext_vector_type(4))) float f32x4;
typedef __attribute__((ext_vector_type(4))) unsigned short u16x4;
typedef __attribute__((ext_vector_type(8))) unsigned short u16x8;

__device__ __forceinline__ float bf2f(unsigned short u) {
    union { unsigned int i; float f; } v; v.i = ((unsigned int)u) << 16; return v.f;
}
__device__ __forceinline__ unsigned short f2bf(float f) {
    union { float f; unsigned int i; } v; v.f = f;
    unsigned int b = v.i;
    b += 0x7FFFu + ((b >> 16) & 1u);   // round-to-nearest-even
    return (unsigned short)(b >> 16);
}
// fp8 encode (single value -> byte) and packed decode via gfx950 HW converts.
__device__ __forceinline__ unsigned char f2f8(float f) {
    int p = __builtin_amdgcn_cvt_pk_fp8_f32(f, f, 0, false);
    return (unsigned char)(p & 0xFF);
}

// ---------------- fused weight transpose: W,SW [L][K][256] -> Wf[L][256][2*Kp] bf16 ----------------
__global__ __launch_bounds__(256) void transpose_fused_kernel(
    const float* __restrict__ W, const float* __restrict__ SW,
    unsigned short* __restrict__ Wf, int K, int Kp, int L)
{
    long long total = (long long)L * 256 * 2 * Kp;
    long long idx = (long long)blockIdx.x * blockDim.x + threadIdx.x;
    const long long stride = (long long)gridDim.x * blockDim.x;
    for (; idx < total; idx += stride) {
        int l = (int)(idx / ((long long)256 * 2 * Kp));
        long long rem = idx - (long long)l * 256 * 2 * Kp;
        int c = (int)(rem / (2 * Kp));
        int kk = (int)(rem - (long long)c * 2 * Kp);
        const float* src = (kk < Kp) ? W : SW;
        int k = (kk < Kp) ? kk : kk - Kp;
        float v = (k < K) ? src[((size_t)l * K + k) * 256 + c] : 0.f;
        Wf[idx] = f2bf(v);
    }
}

// ---------------- Wc[1268][40] fp32 -> Wcb[48][1280] bf16 (segment-mapped, padded) ----------------
__global__ __launch_bounds__(256) void transpose_wc_kernel(
    const float* __restrict__ Wc, unsigned short* __restrict__ Wcb)
{
    int idx = blockIdx.x * blockDim.x + threadIdx.x;
    if (idx >= 48 * 1280) return;
    int c = idx / 1280;
    int kk = idx - c * 1280;
    int src = -1;
    if (kk < 512)       { if (kk < 500) src = kk; }
    else if (kk < 768)  src = 500 + (kk - 512);
    else if (kk < 1024) src = 756 + (kk - 768);
    else                src = 1012 + (kk - 1024);
    float v = (c < 40 && src >= 0) ? Wc[(size_t)src * 40 + c] : 0.f;
    Wcb[idx] = f2bf(v);
}

// ---------------- x -> bf16 [N][512] AND fp8 [N][512] (pad 500->512) ----------------
__global__ __launch_bounds__(256) void cvtx_kernel(
    const float* __restrict__ X, unsigned short* __restrict__ Xb,
    unsigned char* __restrict__ X8, int N)
{
    long long total = (long long)N * 64;
    long long idx = (long long)blockIdx.x * blockDim.x + threadIdx.x;
    const long long stride = (long long)gridDim.x * blockDim.x;
    for (; idx < total; idx += stride) {
        long long row = idx >> 6;
        int g = (int)(idx & 63);
        int k0 = g * 8;
        float v[8];
        if (k0 + 8 <= 500) {
            float4 q0 = *reinterpret_cast<const float4*>(X + row * 500 + k0);
            float4 q1 = *reinterpret_cast<const float4*>(X + row * 500 + k0 + 4);
            v[0] = q0.x; v[1] = q0.y; v[2] = q0.z; v[3] = q0.w;
            v[4] = q1.x; v[5] = q1.y; v[6] = q1.z; v[7] = q1.w;
        } else {
#pragma unroll
            for (int j = 0; j < 8; ++j) v[j] = (k0 + j < 500) ? X[row * 500 + k0 + j] : 0.f;
        }
        u16x8 o;
#pragma unroll
        for (int j = 0; j < 8; ++j) o[j] = f2bf(v[j]);
        *reinterpret_cast<u16x8*>(Xb + row * 512 + k0) = o;
        int p0 = 0, p1 = 0;
        p0 = __builtin_amdgcn_cvt_pk_fp8_f32(v[0], v[1], p0, false);
        p0 = __builtin_amdgcn_cvt_pk_fp8_f32(v[2], v[3], p0, true);
        p1 = __builtin_amdgcn_cvt_pk_fp8_f32(v[4], v[5], p1, false);
        p1 = __builtin_amdgcn_cvt_pk_fp8_f32(v[6], v[7], p1, true);
        uint2 pk = make_uint2((unsigned int)p0, (unsigned int)p1);
        *reinterpret_cast<uint2*>(X8 + row * 512 + k0) = pk;
    }
}

// ---------------- CSR build ----------------
__global__ __launch_bounds__(256) void hist_kernel(
    const int* __restrict__ edst, int* __restrict__ cnt, int n_edges)
{
    int idx = blockIdx.x * blockDim.x + threadIdx.x;
    const int stride = gridDim.x * blockDim.x;
    for (; idx < n_edges; idx += stride) atomicAdd(&cnt[edst[idx]], 1);
}

__global__ __launch_bounds__(256) void scan1_kernel(
    const int* __restrict__ cnt, int* __restrict__ excl,
    int* __restrict__ blocksums, int n)
{
    __shared__ int s[256];
    const int tid = threadIdx.x;
    const int i = blockIdx.x * 256 + tid;
    int v = (i < n) ? cnt[i] : 0;
    s[tid] = v;
    __syncthreads();
#pragma unroll
    for (int off = 1; off < 256; off <<= 1) {
        int t = s[tid];
        if (tid >= off) t += s[tid - off];
        __syncthreads();
        s[tid] = t;
        __syncthreads();
    }
    if (i < n) excl[i] = s[tid] - v;
    if (tid == 255) blocksums[blockIdx.x] = s[255];
}

__global__ __launch_bounds__(512) void scan2_kernel(int* __restrict__ blocksums, int nb)
{
    __shared__ int s[512];
    const int tid = threadIdx.x;
    int v = (tid < nb) ? blocksums[tid] : 0;
    s[tid] = v;
    __syncthreads();
#pragma unroll
    for (int off = 1; off < 512; off <<= 1) {
        int t = s[tid];
        if (tid >= off) t += s[tid - off];
        __syncthreads();
        s[tid] = t;
        __syncthreads();
    }
    if (tid < nb) blocksums[tid] = s[tid] - v;
}

__global__ __launch_bounds__(256) void scan3_kernel(
    const int* __restrict__ excl, const int* __restrict__ blocksums,
    int* __restrict__ row_ptr, int* __restrict__ heads, int n, int n_edges)
{
    const int i = blockIdx.x * 256 + threadIdx.x;
    if (i < n) {
        int v = excl[i] + blocksums[i >> 8];
        row_ptr[i] = v;
        heads[i] = v;
    }
    if (i == 0) row_ptr[n] = n_edges;
}

__global__ __launch_bounds__(256) void scatter_kernel(
    const int* __restrict__ esrc, const int* __restrict__ edst,
    const float* __restrict__ ew, int* __restrict__ heads,
    int2* __restrict__ meta, int n_edges)
{
    int idx = blockIdx.x * blockDim.x + threadIdx.x;
    const int stride = gridDim.x * blockDim.x;
    for (; idx < n_edges; idx += stride) {
        int d = edst[idx];
        int pos = atomicAdd(&heads[d], 1);
        meta[pos] = make_int2(esrc[idx], __float_as_int(ew[idx]));
    }
}

// ---------------- SpMM 256-wide, fp8 source, on-the-fly BN+ReLU ----------------
// O[dst] = sum_e w * relu(sc[c]*dq(S8[src][c]) + sh[c]); output bf16.
__global__ __launch_bounds__(256) void spmm256bn_kernel(
    const int* __restrict__ row_ptr, const int2* __restrict__ meta,
    const unsigned char* __restrict__ S8, const float* __restrict__ kp,
    unsigned short* __restrict__ O, int N)
{
    const int wave = threadIdx.x >> 6;
    const int lane = threadIdx.x & 63;
    int node = blockIdx.x * 4 + wave;
    if (node >= N) return;
    node = __builtin_amdgcn_readfirstlane(node);
    const int beg = row_ptr[node];
    const int end = row_ptr[node + 1];
    const f32x4 sc = *reinterpret_cast<const f32x4*>(kp + lane * 4);
    const f32x4 sh = *reinterpret_cast<const f32x4*>(kp + 256 + lane * 4);
    float a0 = 0.f, a1 = 0.f, a2 = 0.f, a3 = 0.f;

    int e = beg;
    for (; e + 12 <= end; e += 12) {
        int2 m[12];
#pragma unroll
        for (int j = 0; j < 12; ++j) m[j] = meta[e + j];
        unsigned int v[12];
#pragma unroll
        for (int j = 0; j < 12; ++j)
            v[j] = *reinterpret_cast<const unsigned int*>(S8 + (size_t)m[j].x * 256 + lane * 4);
#pragma unroll
        for (int j = 0; j < 12; ++j) {
            float w = __int_as_float(m[j].y);
            f32x2 lo = __builtin_amdgcn_cvt_pk_f32_fp8(v[j], false);
            f32x2 hi = __builtin_amdgcn_cvt_pk_f32_fp8(v[j], true);
            a0 = fmaf(w, fmaxf(fmaf(lo[0], sc[0], sh[0]), 0.f), a0);
            a1 = fmaf(w, fmaxf(fmaf(lo[1], sc[1], sh[1]), 0.f), a1);
            a2 = fmaf(w, fmaxf(fmaf(hi[0], sc[2], sh[2]), 0.f), a2);
            a3 = fmaf(w, fmaxf(fmaf(hi[1], sc[3], sh[3]), 0.f), a3);
        }
    }
    for (; e < end; ++e) {
        int2 m = meta[e];
        float w = __int_as_float(m.y);
        unsigned int v = *reinterpret_cast<const unsigned int*>(S8 + (size_t)m.x * 256 + lane * 4);
        f32x2 lo = __builtin_amdgcn_cvt_pk_f32_fp8(v, false);
        f32x2 hi = __builtin_amdgcn_cvt_pk_f32_fp8(v, true);
        a0 = fmaf(w, fmaxf(fmaf(lo[0], sc[0], sh[0]), 0.f), a0);
        a1 = fmaf(w, fmaxf(fmaf(lo[1], sc[1], sh[1]), 0.f), a1);
        a2 = fmaf(w, fmaxf(fmaf(hi[0], sc[2], sh[2]), 0.f), a2);
        a3 = fmaf(w, fmaxf(fmaf(hi[1], sc[3], sh[3]), 0.f), a3);
    }
    u16x4 o;
    o[0] = f2bf(a0); o[1] = f2bf(a1); o[2] = f2bf(a2); o[3] = f2bf(a3);
    *reinterpret_cast<u16x4*>(O + (size_t)node * 256 + lane * 4) = o;
}

// ---------------- SpMM 512-wide, fp8 source: TWO waves per node, 8-deep ----------------
__global__ __launch_bounds__(512) void spmm512_kernel(
    const int* __restrict__ row_ptr, const int2* __restrict__ meta,
    const unsigned char* __restrict__ S8, unsigned short* __restrict__ O, int N)
{
    const int wv = threadIdx.x >> 6;
    const int lane = threadIdx.x & 63;
    const int half = wv & 1;
    int node = blockIdx.x * 4 + (wv >> 1);
    if (node >= N) return;
    node = __builtin_amdgcn_readfirstlane(node);
    const int beg = row_ptr[node];
    const int end = row_ptr[node + 1];
    const int coff = half * 256 + lane * 4;   // channel (byte) offset into 512-wide fp8 row
    float a0 = 0.f, a1 = 0.f, a2 = 0.f, a3 = 0.f;

    int e = beg;
    for (; e + 8 <= end; e += 8) {
        int2 m[8];
#pragma unroll
        for (int j = 0; j < 8; ++j) m[j] = meta[e + j];
        unsigned int v[8];
#pragma unroll
        for (int j = 0; j < 8; ++j)
            v[j] = *reinterpret_cast<const unsigned int*>(S8 + (size_t)m[j].x * 512 + coff);
#pragma unroll
        for (int j = 0; j < 8; ++j) {
            float w = __int_as_float(m[j].y);
            f32x2 lo = __builtin_amdgcn_cvt_pk_f32_fp8(v[j], false);
            f32x2 hi = __builtin_amdgcn_cvt_pk_f32_fp8(v[j], true);
            a0 = fmaf(w, lo[0], a0);
            a1 = fmaf(w, lo[1], a1);
            a2 = fmaf(w, hi[0], a2);
            a3 = fmaf(w, hi[1], a3);
        }
    }
    for (; e < end; ++e) {
        int2 m = meta[e];
        float w = __int_as_float(m.y);
        unsigned int v = *reinterpret_cast<const unsigned int*>(S8 + (size_t)m.x * 512 + coff);
        f32x2 lo = __builtin_amdgcn_cvt_pk_f32_fp8(v, false);
        f32x2 hi = __builtin_amdgcn_cvt_pk_f32_fp8(v, true);
        a0 = fmaf(w, lo[0], a0);
        a1 = fmaf(w, lo[1], a1);
        a2 = fmaf(w, hi[0], a2);
        a3 = fmaf(w, hi[1], a3);
    }
    u16x4 o;
    o[0] = f2bf(a0); o[1] = f2bf(a1); o[2] = f2bf(a2); o[3] = f2bf(a3);
    *reinterpret_cast<u16x4*>(O + (size_t)node * 512 + coff) = o;
}

// ---------------- LDS-staged MFMA GEMM: C[N,256] = [A1|A2] @ Btf^T + bias, + BN stats ----------------
// Optional fp8 side-copy of C (for SpMM gather). BN2: bn+relu on A2 fragments on the fly.
template<int K1, int K2, bool BN2>
__global__ __launch_bounds__(256) void gemm_lds_kernel(
    const unsigned short* __restrict__ A1, const unsigned short* __restrict__ A2,
    const float* __restrict__ kp, const unsigned short* __restrict__ Btf,
    const float* __restrict__ bias, unsigned short* __restrict__ Cout,
    unsigned char* __restrict__ C8, float* __restrict__ stats, int N)
{
    constexpr int KT = K1 + K2;
    __shared__ unsigned short Atile[128 * 64];
    __shared__ unsigned short Btile[128 * 64];

    const int lane = threadIdx.x & 63;
    const int wave = threadIdx.x >> 6;
    const int l16 = lane & 15;
    const int khi = lane >> 4;
    const int wm = wave >> 1;
    const int wn = wave & 1;
    const long long bm = (long long)blockIdx.x * 128;
    const int col0 = blockIdx.y * 128;

    const int srow8 = lane >> 3;
    const int sc16 = lane & 7;

    f32x4 acc[4][4];
#pragma unroll
    for (int m = 0; m < 4; ++m)
#pragma unroll
        for (int n = 0; n < 4; ++n) acc[m][n] = (f32x4){0.f, 0.f, 0.f, 0.f};

    for (int k0 = 0; k0 < KT; k0 += 64) {
        const unsigned short* Aseg;
        int koff, astr;
        if (k0 < K1) { Aseg = A1; koff = k0; astr = K1; }
        else         { Aseg = A2; koff = k0 - K1; astr = K2; }
        const bool bnseg = BN2 && (k0 >= K1);

        u16x8 av[4], bv[4];
        int rloc[4];
#pragma unroll
        for (int i = 0; i < 4; ++i) {
            int r = wave * 32 + i * 8 + srow8;
            rloc[i] = r;
            long long gr = bm + r;
            if (gr >= N) gr = N - 1;
            av[i] = *reinterpret_cast<const u16x8*>(Aseg + (size_t)gr * astr + koff + sc16 * 8);
            bv[i] = *reinterpret_cast<const u16x8*>(Btf + (size_t)(col0 + r) * KT + k0 + sc16 * 8);
        }
        __syncthreads();
#pragma unroll
        for (int i = 0; i < 4; ++i) {
            int r = rloc[i];
            int cw = (sc16 ^ (r & 7)) * 8;
            *reinterpret_cast<u16x8*>(&Atile[r * 64 + cw]) = av[i];
            *reinterpret_cast<u16x8*>(&Btile[r * 64 + cw]) = bv[i];
        }
        __syncthreads();

#pragma unroll
        for (int kk = 0; kk < 2; ++kk) {
            const int kc = kk * 4 + khi;
            bf16x8 a[4], b[4];
#pragma unroll
            for (int m = 0; m < 4; ++m) {
                int ra = wm * 64 + m * 16 + l16;
                a[m] = *reinterpret_cast<const bf16x8*>(&Atile[ra * 64 + ((kc ^ (ra & 7)) * 8)]);
            }
            if (bnseg) {
                int ch = (k0 - K1) + kk * 32 + khi * 8;
                f32x4 s0 = *reinterpret_cast<const f32x4*>(kp + ch);
                f32x4 s1 = *reinterpret_cast<const f32x4*>(kp + ch + 4);
                f32x4 t0 = *reinterpret_cast<const f32x4*>(kp + 256 + ch);
                f32x4 t1 = *reinterpret_cast<const f32x4*>(kp + 256 + ch + 4);
#pragma unroll
                for (int m = 0; m < 4; ++m) {
                    u16x8 raw;
                    __builtin_memcpy(&raw, &a[m], 16);
                    u16x8 ov;
#pragma unroll
                    for (int j = 0; j < 4; ++j) {
                        ov[j]     = f2bf(fmaxf(fmaf(bf2f(raw[j]),     s0[j], t0[j]), 0.f));
                        ov[4 + j] = f2bf(fmaxf(fmaf(bf2f(raw[4 + j]), s1[j], t1[j]), 0.f));
                    }
                    __builtin_memcpy(&a[m], &ov, 16);
                }
            }
#pragma unroll
            for (int n = 0; n < 4; ++n) {
                int rb = wn * 64 + n * 16 + l16;
                b[n] = *reinterpret_cast<const bf16x8*>(&Btile[rb * 64 + ((kc ^ (rb & 7)) * 8)]);
            }
#pragma unroll
            for (int m = 0; m < 4; ++m)
#pragma unroll
                for (int n = 0; n < 4; ++n)
                    acc[m][n] = __builtin_amdgcn_mfma_f32_16x16x32_bf16(a[m], b[n], acc[m][n], 0, 0, 0);
        }
    }

    float bs[4];
#pragma unroll
    for (int n = 0; n < 4; ++n) bs[n] = bias[col0 + wn * 64 + n * 16 + l16];

    float s[4], s2[4];
#pragma unroll
    for (int n = 0; n < 4; ++n) { s[n] = 0.f; s2[n] = 0.f; }

#pragma unroll
    for (int m = 0; m < 4; ++m)
#pragma unroll
        for (int r = 0; r < 4; ++r) {
            long long grow = bm + wm * 64 + m * 16 + khi * 4 + r;
            if (grow >= N) continue;
#pragma unroll
            for (int n = 0; n < 4; ++n) {
                int gcol = col0 + wn * 64 + n * 16 + l16;
                float v = acc[m][n][r] + bs[n];
                Cout[grow * 256 + gcol] = f2bf(v);
                if (C8) C8[grow * 256 + gcol] = f2f8(v);
                s[n] += v;
                s2[n] = fmaf(v, v, s2[n]);
            }
        }

#pragma unroll
    for (int n = 0; n < 4; ++n) {
        float a = s[n], b2 = s2[n];
        a += __shfl_xor(a, 16); a += __shfl_xor(a, 32);
        b2 += __shfl_xor(b2, 16); b2 += __shfl_xor(b2, 32);
        if (khi == 0) {
            int c = col0 + wn * 64 + n * 16 + l16;
            atomicAdd(&stats[c], a);
            atomicAdd(&stats[256 + c], b2);
        }
    }
}

// ---------------- BN finalize (single slot) ----------------
__global__ __launch_bounds__(256) void bn_finalize_kernel(
    const float* __restrict__ sums, const float* __restrict__ g,
    const float* __restrict__ be, float* __restrict__ kp, int N)
{
    const int c = threadIdx.x;
    float invN = 1.f / (float)N;
    float mean = sums[c] * invN;
    float var = sums[256 + c] * invN - mean * mean;
    float inv = rsqrtf(var + 1e-5f);
    float sc = g[c] * inv;
    kp[c] = sc;
    kp[256 + c] = be[c] - sc * mean;
}

// ---------------- BN finalize x3 ----------------
__global__ __launch_bounds__(256) void bn_finalize3_kernel(
    float* __restrict__ stats, const float* __restrict__ g,
    const float* __restrict__ be, int N)
{
    const int l = blockIdx.x;
    const int c = threadIdx.x;
    float* st = stats + (size_t)l * 1024;
    float invN = 1.f / (float)N;
    float mean = st[c] * invN;
    float var = st[256 + c] * invN - mean * mean;
    float inv = rsqrtf(var + 1e-5f);
    float sc = g[l * 256 + c] * inv;
    st[512 + c] = sc;
    st[768 + c] = be[l * 256 + c] - sc * mean;
}

// ---------------- final MFMA outproj ----------------
template<int KS, bool BN>
__device__ __forceinline__ void outproj_seg(
    const unsigned short* __restrict__ seg, const float* __restrict__ kp,
    const unsigned short* __restrict__ Wcb, int bOff,
    long long r0, long long r1, int l16, int khi, f32x4 acc[2][3])
{
    const unsigned short* a0p = seg + (size_t)r0 * KS + khi * 8;
    const unsigned short* a1p = seg + (size_t)r1 * KS + khi * 8;
#pragma unroll
    for (int k0 = 0; k0 < KS; k0 += 32) {
        bf16x8 a[2];
        a[0] = *reinterpret_cast<const bf16x8*>(a0p + k0);
        a[1] = *reinterpret_cast<const bf16x8*>(a1p + k0);
        if (BN) {
            int ch0 = k0 + khi * 8;
            f32x4 s0 = *reinterpret_cast<const f32x4*>(kp + ch0);
            f32x4 s1 = *reinterpret_cast<const f32x4*>(kp + ch0 + 4);
            f32x4 t0 = *reinterpret_cast<const f32x4*>(kp + 256 + ch0);
            f32x4 t1 = *reinterpret_cast<const f32x4*>(kp + 256 + ch0 + 4);
#pragma unroll
            for (int m = 0; m < 2; ++m) {
                u16x8 raw;
                __builtin_memcpy(&raw, &a[m], 16);
                u16x8 ov;
#pragma unroll
                for (int j = 0; j < 4; ++j) {
                    ov[j]     = f2bf(fmaxf(fmaf(bf2f(raw[j]),     s0[j], t0[j]), 0.f));
                    ov[4 + j] = f2bf(fmaxf(fmaf(bf2f(raw[4 + j]), s1[j], t1[j]), 0.f));
                }
                __builtin_memcpy(&a[m], &ov, 16);
            }
        }
        bf16x8 b[3];
#pragma unroll
        for (int nt = 0; nt < 3; ++nt)
            b[nt] = *reinterpret_cast<const bf16x8*>(Wcb + (size_t)(nt * 16 + l16) * 1280 + bOff + k0 + khi * 8);
#pragma unroll
        for (int m = 0; m < 2; ++m)
#pragma unroll
            for (int nt = 0; nt < 3; ++nt)
                acc[m][nt] = __builtin_amdgcn_mfma_f32_16x16x32_bf16(a[m], b[nt], acc[m][nt], 0, 0, 0);
    }
}

__global__ __launch_bounds__(256) void outproj_mfma_kernel(
    const unsigned short* __restrict__ x_bf,
    const unsigned short* __restrict__ F0, const float* __restrict__ kp0,
    const unsigned short* __restrict__ F1, const float* __restrict__ kp1,
    const unsigned short* __restrict__ F2, const float* __restrict__ kp2,
    const unsigned short* __restrict__ Wcb, const float* __restrict__ bc,
    float* __restrict__ out, int N)
{
    const int lane = threadIdx.x & 63;
    const int wave = threadIdx.x >> 6;
    const int l16 = lane & 15;
    const int khi = lane >> 4;
    const long long bm = (long long)blockIdx.x * 128 + wave * 32;

    long long r0 = bm + l16;        if (r0 >= N) r0 = 0;
    long long r1 = bm + 16 + l16;   if (r1 >= N) r1 = 0;

    f32x4 acc[2][3];
#pragma unroll
    for (int m = 0; m < 2; ++m)
#pragma unroll
        for (int nt = 0; nt < 3; ++nt) acc[m][nt] = (f32x4){0.f, 0.f, 0.f, 0.f};

    outproj_seg<512, false>(x_bf, nullptr, Wcb, 0,    r0, r1, l16, khi, acc);
    outproj_seg<256, true >(F0,   kp0,     Wcb, 512,  r0, r1, l16, khi, acc);
    outproj_seg<256, true >(F1,   kp1,     Wcb, 768,  r0, r1, l16, khi, acc);
    outproj_seg<256, true >(F2,   kp2,     Wcb, 1024, r0, r1, l16, khi, acc);

#pragma unroll
    for (int m = 0; m < 2; ++m)
#pragma unroll
        for (int nt = 0; nt < 3; ++nt)
#pragma unroll
            for (int r = 0; r < 4; ++r) {
                long long grow = bm + m * 16 + khi * 4 + r;
                int gcol = nt * 16 + l16;
                if (grow < N && gcol < 40)
                    out[grow * 40 + gcol] = acc[m][nt][r] + bc[gcol];
            }
}

// ---------------- host-side orchestration ----------------
extern "C" void kernel_launch(void* const* d_in, const int* in_sizes, int n_in,
                              void* d_out, int out_size, void* d_ws, size_t ws_size,
                              hipStream_t stream)
{
    const float* x      = (const float*)d_in[0];
    const int*   esrc   = (const int*)d_in[1];
    const int*   edst   = (const int*)d_in[2];
    const float* ew     = (const float*)d_in[3];
    const float* W_in   = (const float*)d_in[4];
    const float* SW_in  = (const float*)d_in[5];
    const float* b_in   = (const float*)d_in[6];
    const float* g_in   = (const float*)d_in[7];
    const float* be_in  = (const float*)d_in[8];
    const float* W_h    = (const float*)d_in[9];
    const float* SW_h   = (const float*)d_in[10];
    const float* b_h    = (const float*)d_in[11];
    const float* g_h    = (const float*)d_in[12];
    const float* be_h   = (const float*)d_in[13];
    const float* Wc     = (const float*)d_in[14];
    const float* bc     = (const float*)d_in[15];
    float* out = (float*)d_out;

    const int N = in_sizes[0] / 500;      // 100000
    const int n_edges = in_sizes[1];      // 3200000
    const int nb = (N + 255) / 256;

    // ---- workspace layout ----
    char* p = (char*)d_ws;
    unsigned short* x_bf = (unsigned short*)p; p += (size_t)N * 512 * 2;
    unsigned short* Xa   = (unsigned short*)p; p += (size_t)N * 512 * 2;   // F2 aliases
    unsigned short* Ha   = (unsigned short*)p; p += (size_t)N * 256 * 2;
    unsigned short* G1   = (unsigned short*)p; p += (size_t)N * 256 * 2;   // H2 aliases
    unsigned short* G2   = (unsigned short*)p; p += (size_t)N * 256 * 2;
    unsigned short* F0   = (unsigned short*)p; p += (size_t)N * 256 * 2;
    unsigned short* F1   = (unsigned short*)p; p += (size_t)N * 256 * 2;
    unsigned short* H2   = G1;
    unsigned short* F2   = Xa;
    unsigned char* x_f8  = (unsigned char*)p; p += (size_t)N * 512;       // fp8 gather copies
    unsigned char* G1_f8 = (unsigned char*)p; p += (size_t)N * 256;
    unsigned char* G2_f8 = (unsigned char*)p; p += (size_t)N * 256;
    unsigned char* H2_f8 = G1_f8;   // alias: G1_f8 dead after j=1 spmm
    unsigned short* Wf_in = (unsigned short*)p; p += (size_t)3 * 256 * 1024 * 2;
    unsigned short* Wf_h  = (unsigned short*)p; p += (size_t)3 * 256 * 512 * 2;
    unsigned short* Wcb   = (unsigned short*)p; p += (size_t)48 * 1280 * 2;
    float* stats = (float*)p; p += (size_t)6 * 1024 * 4;
    int* cnt     = (int*)p; p += (size_t)N * 4;
    int* excl    = (int*)p; p += (size_t)N * 4;
    int* blocksums = (int*)p; p += 2048 * 4;
    int* row_ptr = (int*)p; p += (size_t)(N + 1) * 4 + 4;
    int* heads   = (int*)p; p += (size_t)N * 4;
    int2* meta   = (int2*)p;

    // ---- preprocessing ----
    hipMemsetAsync(stats, 0, (size_t)6 * 1024 * sizeof(float) + (size_t)N * sizeof(int), stream);
    hipLaunchKernelGGL(transpose_fused_kernel, dim3(2048), dim3(256), 0, stream,
                       W_in, SW_in, Wf_in, 500, 512, 3);
    hipLaunchKernelGGL(transpose_fused_kernel, dim3(1024), dim3(256), 0, stream,
                       W_h, SW_h, Wf_h, 256, 256, 3);
    hipLaunchKernelGGL(transpose_wc_kernel, dim3(240), dim3(256), 0, stream, Wc, Wcb);

    hipLaunchKernelGGL(hist_kernel, dim3(4096), dim3(256), 0, stream, edst, cnt, n_edges);
    hipLaunchKernelGGL(scan1_kernel, dim3(nb), dim3(256), 0, stream, cnt, excl, blocksums, N);
    hipLaunchKernelGGL(scan2_kernel, dim3(1), dim3(512), 0, stream, blocksums, nb);
    hipLaunchKernelGGL(scan3_kernel, dim3(nb), dim3(256), 0, stream,
                       excl, blocksums, row_ptr, heads, N, n_edges);
    hipLaunchKernelGGL(scatter_kernel, dim3(4096), dim3(256), 0, stream,
                       esrc, edst, ew, heads, meta, n_edges);

    hipLaunchKernelGGL(cvtx_kernel, dim3(4096), dim3(256), 0, stream, x, x_bf, x_f8, N);

    hipLaunchKernelGGL(spmm512_kernel, dim3((N + 3) / 4), dim3(512), 0, stream,
                       row_ptr, meta, x_f8, Xa, N);

    dim3 blk(256);
    dim3 ggrid2((N + 127) / 128, 2);
    dim3 ogrid((N + 127) / 128);
    dim3 sgrid((N + 3) / 4);

    // ---- three input-layer GEMMs (LDS-staged) ----
    hipLaunchKernelGGL((gemm_lds_kernel<512, 512, false>), ggrid2, blk, 0, stream,
                       Xa, x_bf, (const float*)nullptr, Wf_in, b_in,
                       F0, (unsigned char*)nullptr, stats + 0 * 1024, N);
    hipLaunchKernelGGL((gemm_lds_kernel<512, 512, false>), ggrid2, blk, 0, stream,
                       Xa, x_bf, (const float*)nullptr, Wf_in + (size_t)1 * 256 * 1024, b_in + 256,
                       G1, G1_f8, stats + 1 * 1024, N);
    hipLaunchKernelGGL((gemm_lds_kernel<512, 512, false>), ggrid2, blk, 0, stream,
                       Xa, x_bf, (const float*)nullptr, Wf_in + (size_t)2 * 256 * 1024, b_in + 512,
                       G2, G2_f8, stats + 2 * 1024, N);
    hipLaunchKernelGGL(bn_finalize3_kernel, dim3(3), dim3(256), 0, stream,
                       stats, g_in, be_in, N);

    float* kp0 = stats + 0 * 1024 + 512;
    float* kp1 = stats + 1 * 1024 + 512;
    float* kp2 = stats + 2 * 1024 + 512;
    float* st3 = stats + 3 * 1024;
    float* st4 = stats + 4 * 1024;
    float* st5 = stats + 5 * 1024;

    // ---- j = 1: hidden GC on bn(G1) -> F1 ----
    hipLaunchKernelGGL(spmm256bn_kernel, sgrid, blk, 0, stream, row_ptr, meta, G1_f8, kp1, Ha, N);
    hipLaunchKernelGGL((gemm_lds_kernel<256, 256, true>), ggrid2, blk, 0, stream,
                       Ha, G1, kp1, Wf_h, b_h, F1, (unsigned char*)nullptr, st3, N);
    hipLaunchKernelGGL(bn_finalize_kernel, dim3(1), dim3(256), 0, stream, st3, g_h, be_h, st3 + 512, N);

    // ---- j = 2: two hidden GCs on bn(G2) ----
    hipLaunchKernelGGL(spmm256bn_kernel, sgrid, blk, 0, stream, row_ptr, meta, G2_f8, kp2, Ha, N);
    hipLaunchKernelGGL((gemm_lds_kernel<256, 256, true>), ggrid2, blk, 0, stream,
                       Ha, G2, kp2, Wf_h + (size_t)1 * 256 * 512, b_h + 256,
                       H2, H2_f8, st4, N);
    hipLaunchKernelGGL(bn_finalize_kernel, dim3(1), dim3(256), 0, stream, st4, g_h + 256, be_h + 256, st4 + 512, N);

    hipLaunchKernelGGL(spmm256bn_kernel, sgrid, blk, 0, stream, row_ptr, meta, H2_f8, st4 + 512, Ha, N);
    hipLaunchKernelGGL((gemm_lds_kernel<256, 256, true>), ggrid2, blk, 0, stream,
                       Ha, H2, st4 + 512, Wf_h + (size_t)2 * 256 * 512, b_h + 512,
                       F2, (unsigned char*)nullptr, st5, N);
    hipLaunchKernelGGL(bn_finalize_kernel, dim3(1), dim3(256), 0, stream, st5, g_h + 512, be_h + 512, st5 + 512, N);

    // ---- final: out = [x | bn(F0) | bn(F1) | bn(F2)] @ Wcb^T + bc ----
    hipLaunchKernelGGL(outproj_mfma_kernel, ogrid, blk, 0, stream,
                       x_bf, F0, kp0, F1, st3 + 512, F2, st5 + 512,
                       Wcb, bc, out, N);
}

// Round 11
// 1918.500 us; speedup vs baseline: 38.9863x; 1.0192x over previous
//
#include <hip/hip_runtime.h>

typedef __attribute__((ext_vector_type(8))) short bf16x8;
typedef __attribute__((ext_vector_type(2))) float f32x2;
typedef __attribute__((ext_vector_type(4))) float f32x4;
typedef __attribute__((ext_vector_type(4))) unsigned short u16x4;
typedef __attribute__((ext_vector_type(8))) unsigned short u16x8;

__device__ __forceinline__ float bf2f(unsigned short u) {
    union { unsigned int i; float f; } v; v.i = ((unsigned int)u) << 16; return v.f;
}
__device__ __forceinline__ unsigned short f2bf(float f) {
    union { float f; unsigned int i; } v; v.f = f;
    unsigned int b = v.i;
    b += 0x7FFFu + ((b >> 16) & 1u);   // round-to-nearest-even
    return (unsigned short)(b >> 16);
}
__device__ __forceinline__ unsigned char f2f8(float f) {
    int p = __builtin_amdgcn_cvt_pk_fp8_f32(f, f, 0, false);
    return (unsigned char)(p & 0xFF);
}
// decode meta word: src = m >> 8, w = fp8(m & 0xFF) * 2^-5
__device__ __forceinline__ float meta_w(unsigned int m) {
    f32x2 lo = __builtin_amdgcn_cvt_pk_f32_fp8(m & 0xFFu, false);
    return lo[0] * 0.03125f;
}

// ---------------- fused weight transpose: W,SW [L][K][256] -> Wf[L][256][2*Kp] bf16 ----------------
__global__ __launch_bounds__(256) void transpose_fused_kernel(
    const float* __restrict__ W, const float* __restrict__ SW,
    unsigned short* __restrict__ Wf, int K, int Kp, int L)
{
    long long total = (long long)L * 256 * 2 * Kp;
    long long idx = (long long)blockIdx.x * blockDim.x + threadIdx.x;
    const long long stride = (long long)gridDim.x * blockDim.x;
    for (; idx < total; idx += stride) {
        int l = (int)(idx / ((long long)256 * 2 * Kp));
        long long rem = idx - (long long)l * 256 * 2 * Kp;
        int c = (int)(rem / (2 * Kp));
        int kk = (int)(rem - (long long)c * 2 * Kp);
        const float* src = (kk < Kp) ? W : SW;
        int k = (kk < Kp) ? kk : kk - Kp;
        float v = (k < K) ? src[((size_t)l * K + k) * 256 + c] : 0.f;
        Wf[idx] = f2bf(v);
    }
}

// ---------------- Wc[1268][40] fp32 -> Wcb[48][1280] bf16 ----------------
__global__ __launch_bounds__(256) void transpose_wc_kernel(
    const float* __restrict__ Wc, unsigned short* __restrict__ Wcb)
{
    int idx = blockIdx.x * blockDim.x + threadIdx.x;
    if (idx >= 48 * 1280) return;
    int c = idx / 1280;
    int kk = idx - c * 1280;
    int src = -1;
    if (kk < 512)       { if (kk < 500) src = kk; }
    else if (kk < 768)  src = 500 + (kk - 512);
    else if (kk < 1024) src = 756 + (kk - 768);
    else                src = 1012 + (kk - 1024);
    float v = (c < 40 && src >= 0) ? Wc[(size_t)src * 40 + c] : 0.f;
    Wcb[idx] = f2bf(v);
}

// ---------------- x -> bf16 [N][512] AND fp8 [N][512] ----------------
__global__ __launch_bounds__(256) void cvtx_kernel(
    const float* __restrict__ X, unsigned short* __restrict__ Xb,
    unsigned char* __restrict__ X8, int N)
{
    long long total = (long long)N * 64;
    long long idx = (long long)blockIdx.x * blockDim.x + threadIdx.x;
    const long long stride = (long long)gridDim.x * blockDim.x;
    for (; idx < total; idx += stride) {
        long long row = idx >> 6;
        int g = (int)(idx & 63);
        int k0 = g * 8;
        float v[8];
        if (k0 + 8 <= 500) {
            float4 q0 = *reinterpret_cast<const float4*>(X + row * 500 + k0);
            float4 q1 = *reinterpret_cast<const float4*>(X + row * 500 + k0 + 4);
            v[0] = q0.x; v[1] = q0.y; v[2] = q0.z; v[3] = q0.w;
            v[4] = q1.x; v[5] = q1.y; v[6] = q1.z; v[7] = q1.w;
        } else {
#pragma unroll
            for (int j = 0; j < 8; ++j) v[j] = (k0 + j < 500) ? X[row * 500 + k0 + j] : 0.f;
        }
        u16x8 o;
#pragma unroll
        for (int j = 0; j < 8; ++j) o[j] = f2bf(v[j]);
        *reinterpret_cast<u16x8*>(Xb + row * 512 + k0) = o;
        int p0 = 0, p1 = 0;
        p0 = __builtin_amdgcn_cvt_pk_fp8_f32(v[0], v[1], p0, false);
        p0 = __builtin_amdgcn_cvt_pk_fp8_f32(v[2], v[3], p0, true);
        p1 = __builtin_amdgcn_cvt_pk_fp8_f32(v[4], v[5], p1, false);
        p1 = __builtin_amdgcn_cvt_pk_fp8_f32(v[6], v[7], p1, true);
        uint2 pk = make_uint2((unsigned int)p0, (unsigned int)p1);
        *reinterpret_cast<uint2*>(X8 + row * 512 + k0) = pk;
    }
}

// ---------------- CSR build ----------------
__global__ __launch_bounds__(256) void hist_kernel(
    const int* __restrict__ edst, int* __restrict__ cnt, int n_edges)
{
    int idx = blockIdx.x * blockDim.x + threadIdx.x;
    const int stride = gridDim.x * blockDim.x;
    for (; idx < n_edges; idx += stride) atomicAdd(&cnt[edst[idx]], 1);
}

__global__ __launch_bounds__(256) void scan1_kernel(
    const int* __restrict__ cnt, int* __restrict__ excl,
    int* __restrict__ blocksums, int n)
{
    __shared__ int s[256];
    const int tid = threadIdx.x;
    const int i = blockIdx.x * 256 + tid;
    int v = (i < n) ? cnt[i] : 0;
    s[tid] = v;
    __syncthreads();
#pragma unroll
    for (int off = 1; off < 256; off <<= 1) {
        int t = s[tid];
        if (tid >= off) t += s[tid - off];
        __syncthreads();
        s[tid] = t;
        __syncthreads();
    }
    if (i < n) excl[i] = s[tid] - v;
    if (tid == 255) blocksums[blockIdx.x] = s[255];
}

__global__ __launch_bounds__(512) void scan2_kernel(int* __restrict__ blocksums, int nb)
{
    __shared__ int s[512];
    const int tid = threadIdx.x;
    int v = (tid < nb) ? blocksums[tid] : 0;
    s[tid] = v;
    __syncthreads();
#pragma unroll
    for (int off = 1; off < 512; off <<= 1) {
        int t = s[tid];
        if (tid >= off) t += s[tid - off];
        __syncthreads();
        s[tid] = t;
        __syncthreads();
    }
    if (tid < nb) blocksums[tid] = s[tid] - v;
}

__global__ __launch_bounds__(256) void scan3_kernel(
    const int* __restrict__ excl, const int* __restrict__ blocksums,
    int* __restrict__ row_ptr, int* __restrict__ heads, int n, int n_edges)
{
    const int i = blockIdx.x * 256 + threadIdx.x;
    if (i < n) {
        int v = excl[i] + blocksums[i >> 8];
        row_ptr[i] = v;
        heads[i] = v;
    }
    if (i == 0) row_ptr[n] = n_edges;
}

// scatter: pack (src<<8) | fp8(w*32) into one 4B word
__global__ __launch_bounds__(256) void scatter_kernel(
    const int* __restrict__ esrc, const int* __restrict__ edst,
    const float* __restrict__ ew, int* __restrict__ heads,
    unsigned int* __restrict__ meta, int n_edges)
{
    int idx = blockIdx.x * blockDim.x + threadIdx.x;
    const int stride = gridDim.x * blockDim.x;
    for (; idx < n_edges; idx += stride) {
        int d = edst[idx];
        int pos = atomicAdd(&heads[d], 1);
        unsigned int m = ((unsigned int)esrc[idx] << 8) | f2f8(ew[idx] * 32.0f);
        meta[pos] = m;
    }
}

// ---------------- SpMM 256-wide, fp8 source, on-the-fly BN+ReLU ----------------
__global__ __launch_bounds__(256) void spmm256bn_kernel(
    const int* __restrict__ row_ptr, const unsigned int* __restrict__ meta,
    const unsigned char* __restrict__ S8, const float* __restrict__ kp,
    unsigned short* __restrict__ O, int N)
{
    const int wave = threadIdx.x >> 6;
    const int lane = threadIdx.x & 63;
    int node = blockIdx.x * 4 + wave;
    if (node >= N) return;
    node = __builtin_amdgcn_readfirstlane(node);
    const int beg = row_ptr[node];
    const int end = row_ptr[node + 1];
    const f32x4 sc = *reinterpret_cast<const f32x4*>(kp + lane * 4);
    const f32x4 sh = *reinterpret_cast<const f32x4*>(kp + 256 + lane * 4);
    float a0 = 0.f, a1 = 0.f, a2 = 0.f, a3 = 0.f;

    int e = beg;
    for (; e + 12 <= end; e += 12) {
        unsigned int m[12];
#pragma unroll
        for (int j = 0; j < 12; ++j) m[j] = meta[e + j];
        unsigned int v[12];
#pragma unroll
        for (int j = 0; j < 12; ++j)
            v[j] = *reinterpret_cast<const unsigned int*>(S8 + (size_t)(m[j] >> 8) * 256 + lane * 4);
#pragma unroll
        for (int j = 0; j < 12; ++j) {
            float w = meta_w(m[j]);
            f32x2 lo = __builtin_amdgcn_cvt_pk_f32_fp8(v[j], false);
            f32x2 hi = __builtin_amdgcn_cvt_pk_f32_fp8(v[j], true);
            a0 = fmaf(w, fmaxf(fmaf(lo[0], sc[0], sh[0]), 0.f), a0);
            a1 = fmaf(w, fmaxf(fmaf(lo[1], sc[1], sh[1]), 0.f), a1);
            a2 = fmaf(w, fmaxf(fmaf(hi[0], sc[2], sh[2]), 0.f), a2);
            a3 = fmaf(w, fmaxf(fmaf(hi[1], sc[3], sh[3]), 0.f), a3);
        }
    }
    for (; e < end; ++e) {
        unsigned int m = meta[e];
        float w = meta_w(m);
        unsigned int v = *reinterpret_cast<const unsigned int*>(S8 + (size_t)(m >> 8) * 256 + lane * 4);
        f32x2 lo = __builtin_amdgcn_cvt_pk_f32_fp8(v, false);
        f32x2 hi = __builtin_amdgcn_cvt_pk_f32_fp8(v, true);
        a0 = fmaf(w, fmaxf(fmaf(lo[0], sc[0], sh[0]), 0.f), a0);
        a1 = fmaf(w, fmaxf(fmaf(lo[1], sc[1], sh[1]), 0.f), a1);
        a2 = fmaf(w, fmaxf(fmaf(hi[0], sc[2], sh[2]), 0.f), a2);
        a3 = fmaf(w, fmaxf(fmaf(hi[1], sc[3], sh[3]), 0.f), a3);
    }
    u16x4 o;
    o[0] = f2bf(a0); o[1] = f2bf(a1); o[2] = f2bf(a2); o[3] = f2bf(a3);
    *reinterpret_cast<u16x4*>(O + (size_t)node * 256 + lane * 4) = o;
}

// ---------------- fused dual SpMM 256-wide: one edge walk, two fp8 sources ----------------
__global__ __launch_bounds__(256) void spmm256x2bn_kernel(
    const int* __restrict__ row_ptr, const unsigned int* __restrict__ meta,
    const unsigned char* __restrict__ S8a, const float* __restrict__ kpa,
    const unsigned char* __restrict__ S8b, const float* __restrict__ kpb,
    unsigned short* __restrict__ Oa, unsigned short* __restrict__ Ob, int N)
{
    const int wave = threadIdx.x >> 6;
    const int lane = threadIdx.x & 63;
    int node = blockIdx.x * 4 + wave;
    if (node >= N) return;
    node = __builtin_amdgcn_readfirstlane(node);
    const int beg = row_ptr[node];
    const int end = row_ptr[node + 1];
    const f32x4 sca = *reinterpret_cast<const f32x4*>(kpa + lane * 4);
    const f32x4 sha = *reinterpret_cast<const f32x4*>(kpa + 256 + lane * 4);
    const f32x4 scb = *reinterpret_cast<const f32x4*>(kpb + lane * 4);
    const f32x4 shb = *reinterpret_cast<const f32x4*>(kpb + 256 + lane * 4);
    float a0 = 0.f, a1 = 0.f, a2 = 0.f, a3 = 0.f;
    float b0 = 0.f, b1 = 0.f, b2 = 0.f, b3 = 0.f;

    int e = beg;
    for (; e + 8 <= end; e += 8) {
        unsigned int m[8];
#pragma unroll
        for (int j = 0; j < 8; ++j) m[j] = meta[e + j];
        unsigned int va[8], vb[8];
#pragma unroll
        for (int j = 0; j < 8; ++j) {
            size_t off = (size_t)(m[j] >> 8) * 256 + lane * 4;
            va[j] = *reinterpret_cast<const unsigned int*>(S8a + off);
            vb[j] = *reinterpret_cast<const unsigned int*>(S8b + off);
        }
#pragma unroll
        for (int j = 0; j < 8; ++j) {
            float w = meta_w(m[j]);
            f32x2 alo = __builtin_amdgcn_cvt_pk_f32_fp8(va[j], false);
            f32x2 ahi = __builtin_amdgcn_cvt_pk_f32_fp8(va[j], true);
            f32x2 blo = __builtin_amdgcn_cvt_pk_f32_fp8(vb[j], false);
            f32x2 bhi = __builtin_amdgcn_cvt_pk_f32_fp8(vb[j], true);
            a0 = fmaf(w, fmaxf(fmaf(alo[0], sca[0], sha[0]), 0.f), a0);
            a1 = fmaf(w, fmaxf(fmaf(alo[1], sca[1], sha[1]), 0.f), a1);
            a2 = fmaf(w, fmaxf(fmaf(ahi[0], sca[2], sha[2]), 0.f), a2);
            a3 = fmaf(w, fmaxf(fmaf(ahi[1], sca[3], sha[3]), 0.f), a3);
            b0 = fmaf(w, fmaxf(fmaf(blo[0], scb[0], shb[0]), 0.f), b0);
            b1 = fmaf(w, fmaxf(fmaf(blo[1], scb[1], shb[1]), 0.f), b1);
            b2 = fmaf(w, fmaxf(fmaf(bhi[0], scb[2], shb[2]), 0.f), b2);
            b3 = fmaf(w, fmaxf(fmaf(bhi[1], scb[3], shb[3]), 0.f), b3);
        }
    }
    for (; e < end; ++e) {
        unsigned int m = meta[e];
        float w = meta_w(m);
        size_t off = (size_t)(m >> 8) * 256 + lane * 4;
        unsigned int va = *reinterpret_cast<const unsigned int*>(S8a + off);
        unsigned int vb = *reinterpret_cast<const unsigned int*>(S8b + off);
        f32x2 alo = __builtin_amdgcn_cvt_pk_f32_fp8(va, false);
        f32x2 ahi = __builtin_amdgcn_cvt_pk_f32_fp8(va, true);
        f32x2 blo = __builtin_amdgcn_cvt_pk_f32_fp8(vb, false);
        f32x2 bhi = __builtin_amdgcn_cvt_pk_f32_fp8(vb, true);
        a0 = fmaf(w, fmaxf(fmaf(alo[0], sca[0], sha[0]), 0.f), a0);
        a1 = fmaf(w, fmaxf(fmaf(alo[1], sca[1], sha[1]), 0.f), a1);
        a2 = fmaf(w, fmaxf(fmaf(ahi[0], sca[2], sha[2]), 0.f), a2);
        a3 = fmaf(w, fmaxf(fmaf(ahi[1], sca[3], sha[3]), 0.f), a3);
        b0 = fmaf(w, fmaxf(fmaf(blo[0], scb[0], shb[0]), 0.f), b0);
        b1 = fmaf(w, fmaxf(fmaf(blo[1], scb[1], shb[1]), 0.f), b1);
        b2 = fmaf(w, fmaxf(fmaf(bhi[0], scb[2], shb[2]), 0.f), b2);
        b3 = fmaf(w, fmaxf(fmaf(bhi[1], scb[3], shb[3]), 0.f), b3);
    }
    u16x4 oa, ob;
    oa[0] = f2bf(a0); oa[1] = f2bf(a1); oa[2] = f2bf(a2); oa[3] = f2bf(a3);
    ob[0] = f2bf(b0); ob[1] = f2bf(b1); ob[2] = f2bf(b2); ob[3] = f2bf(b3);
    *reinterpret_cast<u16x4*>(Oa + (size_t)node * 256 + lane * 4) = oa;
    *reinterpret_cast<u16x4*>(Ob + (size_t)node * 256 + lane * 4) = ob;
}

// ---------------- SpMM 512-wide, fp8 source: TWO waves per node, 8-deep ----------------
__global__ __launch_bounds__(512) void spmm512_kernel(
    const int* __restrict__ row_ptr, const unsigned int* __restrict__ meta,
    const unsigned char* __restrict__ S8, unsigned short* __restrict__ O, int N)
{
    const int wv = threadIdx.x >> 6;
    const int lane = threadIdx.x & 63;
    const int half = wv & 1;
    int node = blockIdx.x * 4 + (wv >> 1);
    if (node >= N) return;
    node = __builtin_amdgcn_readfirstlane(node);
    const int beg = row_ptr[node];
    const int end = row_ptr[node + 1];
    const int coff = half * 256 + lane * 4;
    float a0 = 0.f, a1 = 0.f, a2 = 0.f, a3 = 0.f;

    int e = beg;
    for (; e + 8 <= end; e += 8) {
        unsigned int m[8];
#pragma unroll
        for (int j = 0; j < 8; ++j) m[j] = meta[e + j];
        unsigned int v[8];
#pragma unroll
        for (int j = 0; j < 8; ++j)
            v[j] = *reinterpret_cast<const unsigned int*>(S8 + (size_t)(m[j] >> 8) * 512 + coff);
#pragma unroll
        for (int j = 0; j < 8; ++j) {
            float w = meta_w(m[j]);
            f32x2 lo = __builtin_amdgcn_cvt_pk_f32_fp8(v[j], false);
            f32x2 hi = __builtin_amdgcn_cvt_pk_f32_fp8(v[j], true);
            a0 = fmaf(w, lo[0], a0);
            a1 = fmaf(w, lo[1], a1);
            a2 = fmaf(w, hi[0], a2);
            a3 = fmaf(w, hi[1], a3);
        }
    }
    for (; e < end; ++e) {
        unsigned int m = meta[e];
        float w = meta_w(m);
        unsigned int v = *reinterpret_cast<const unsigned int*>(S8 + (size_t)(m >> 8) * 512 + coff);
        f32x2 lo = __builtin_amdgcn_cvt_pk_f32_fp8(v, false);
        f32x2 hi = __builtin_amdgcn_cvt_pk_f32_fp8(v, true);
        a0 = fmaf(w, lo[0], a0);
        a1 = fmaf(w, lo[1], a1);
        a2 = fmaf(w, hi[0], a2);
        a3 = fmaf(w, hi[1], a3);
    }
    u16x4 o;
    o[0] = f2bf(a0); o[1] = f2bf(a1); o[2] = f2bf(a2); o[3] = f2bf(a3);
    *reinterpret_cast<u16x4*>(O + (size_t)node * 512 + coff) = o;
}

// ---------------- LDS-staged MFMA GEMM ----------------
template<int K1, int K2, bool BN2>
__global__ __launch_bounds__(256) void gemm_lds_kernel(
    const unsigned short* __restrict__ A1, const unsigned short* __restrict__ A2,
    const float* __restrict__ kp, const unsigned short* __restrict__ Btf,
    const float* __restrict__ bias, unsigned short* __restrict__ Cout,
    unsigned char* __restrict__ C8, float* __restrict__ stats, int N)
{
    constexpr int KT = K1 + K2;
    __shared__ unsigned short Atile[128 * 64];
    __shared__ unsigned short Btile[128 * 64];

    const int lane = threadIdx.x & 63;
    const int wave = threadIdx.x >> 6;
    const int l16 = lane & 15;
    const int khi = lane >> 4;
    const int wm = wave >> 1;
    const int wn = wave & 1;
    const long long bm = (long long)blockIdx.x * 128;
    const int col0 = blockIdx.y * 128;

    const int srow8 = lane >> 3;
    const int sc16 = lane & 7;

    f32x4 acc[4][4];
#pragma unroll
    for (int m = 0; m < 4; ++m)
#pragma unroll
        for (int n = 0; n < 4; ++n) acc[m][n] = (f32x4){0.f, 0.f, 0.f, 0.f};

    for (int k0 = 0; k0 < KT; k0 += 64) {
        const unsigned short* Aseg;
        int koff, astr;
        if (k0 < K1) { Aseg = A1; koff = k0; astr = K1; }
        else         { Aseg = A2; koff = k0 - K1; astr = K2; }
        const bool bnseg = BN2 && (k0 >= K1);

        u16x8 av[4], bv[4];
        int rloc[4];
#pragma unroll
        for (int i = 0; i < 4; ++i) {
            int r = wave * 32 + i * 8 + srow8;
            rloc[i] = r;
            long long gr = bm + r;
            if (gr >= N) gr = N - 1;
            av[i] = *reinterpret_cast<const u16x8*>(Aseg + (size_t)gr * astr + koff + sc16 * 8);
            bv[i] = *reinterpret_cast<const u16x8*>(Btf + (size_t)(col0 + r) * KT + k0 + sc16 * 8);
        }
        __syncthreads();
#pragma unroll
        for (int i = 0; i < 4; ++i) {
            int r = rloc[i];
            int cw = (sc16 ^ (r & 7)) * 8;
            *reinterpret_cast<u16x8*>(&Atile[r * 64 + cw]) = av[i];
            *reinterpret_cast<u16x8*>(&Btile[r * 64 + cw]) = bv[i];
        }
        __syncthreads();

#pragma unroll
        for (int kk = 0; kk < 2; ++kk) {
            const int kc = kk * 4 + khi;
            bf16x8 a[4], b[4];
#pragma unroll
            for (int m = 0; m < 4; ++m) {
                int ra = wm * 64 + m * 16 + l16;
                a[m] = *reinterpret_cast<const bf16x8*>(&Atile[ra * 64 + ((kc ^ (ra & 7)) * 8)]);
            }
            if (bnseg) {
                int ch = (k0 - K1) + kk * 32 + khi * 8;
                f32x4 s0 = *reinterpret_cast<const f32x4*>(kp + ch);
                f32x4 s1 = *reinterpret_cast<const f32x4*>(kp + ch + 4);
                f32x4 t0 = *reinterpret_cast<const f32x4*>(kp + 256 + ch);
                f32x4 t1 = *reinterpret_cast<const f32x4*>(kp + 256 + ch + 4);
#pragma unroll
                for (int m = 0; m < 4; ++m) {
                    u16x8 raw;
                    __builtin_memcpy(&raw, &a[m], 16);
                    u16x8 ov;
#pragma unroll
                    for (int j = 0; j < 4; ++j) {
                        ov[j]     = f2bf(fmaxf(fmaf(bf2f(raw[j]),     s0[j], t0[j]), 0.f));
                        ov[4 + j] = f2bf(fmaxf(fmaf(bf2f(raw[4 + j]), s1[j], t1[j]), 0.f));
                    }
                    __builtin_memcpy(&a[m], &ov, 16);
                }
            }
#pragma unroll
            for (int n = 0; n < 4; ++n) {
                int rb = wn * 64 + n * 16 + l16;
                b[n] = *reinterpret_cast<const bf16x8*>(&Btile[rb * 64 + ((kc ^ (rb & 7)) * 8)]);
            }
#pragma unroll
            for (int m = 0; m < 4; ++m)
#pragma unroll
                for (int n = 0; n < 4; ++n)
                    acc[m][n] = __builtin_amdgcn_mfma_f32_16x16x32_bf16(a[m], b[n], acc[m][n], 0, 0, 0);
        }
    }

    float bs[4];
#pragma unroll
    for (int n = 0; n < 4; ++n) bs[n] = bias[col0 + wn * 64 + n * 16 + l16];

    float s[4], s2[4];
#pragma unroll
    for (int n = 0; n < 4; ++n) { s[n] = 0.f; s2[n] = 0.f; }

#pragma unroll
    for (int m = 0; m < 4; ++m)
#pragma unroll
        for (int r = 0; r < 4; ++r) {
            long long grow = bm + wm * 64 + m * 16 + khi * 4 + r;
            if (grow >= N) continue;
#pragma unroll
            for (int n = 0; n < 4; ++n) {
                int gcol = col0 + wn * 64 + n * 16 + l16;
                float v = acc[m][n][r] + bs[n];
                Cout[grow * 256 + gcol] = f2bf(v);
                if (C8) C8[grow * 256 + gcol] = f2f8(v);
                s[n] += v;
                s2[n] = fmaf(v, v, s2[n]);
            }
        }

#pragma unroll
    for (int n = 0; n < 4; ++n) {
        float a = s[n], b2 = s2[n];
        a += __shfl_xor(a, 16); a += __shfl_xor(a, 32);
        b2 += __shfl_xor(b2, 16); b2 += __shfl_xor(b2, 32);
        if (khi == 0) {
            int c = col0 + wn * 64 + n * 16 + l16;
            atomicAdd(&stats[c], a);
            atomicAdd(&stats[256 + c], b2);
        }
    }
}

// ---------------- BN finalize ----------------
__global__ __launch_bounds__(256) void bn_finalize_kernel(
    const float* __restrict__ sums, const float* __restrict__ g,
    const float* __restrict__ be, float* __restrict__ kp, int N)
{
    const int c = threadIdx.x;
    float invN = 1.f / (float)N;
    float mean = sums[c] * invN;
    float var = sums[256 + c] * invN - mean * mean;
    float inv = rsqrtf(var + 1e-5f);
    float sc = g[c] * inv;
    kp[c] = sc;
    kp[256 + c] = be[c] - sc * mean;
}

__global__ __launch_bounds__(256) void bn_finalize3_kernel(
    float* __restrict__ stats, const float* __restrict__ g,
    const float* __restrict__ be, int N)
{
    const int l = blockIdx.x;
    const int c = threadIdx.x;
    float* st = stats + (size_t)l * 1024;
    float invN = 1.f / (float)N;
    float mean = st[c] * invN;
    float var = st[256 + c] * invN - mean * mean;
    float inv = rsqrtf(var + 1e-5f);
    float sc = g[l * 256 + c] * inv;
    st[512 + c] = sc;
    st[768 + c] = be[l * 256 + c] - sc * mean;
}

// ---------------- final MFMA outproj ----------------
template<int KS, bool BN>
__device__ __forceinline__ void outproj_seg(
    const unsigned short* __restrict__ seg, const float* __restrict__ kp,
    const unsigned short* __restrict__ Wcb, int bOff,
    long long r0, long long r1, int l16, int khi, f32x4 acc[2][3])
{
    const unsigned short* a0p = seg + (size_t)r0 * KS + khi * 8;
    const unsigned short* a1p = seg + (size_t)r1 * KS + khi * 8;
#pragma unroll
    for (int k0 = 0; k0 < KS; k0 += 32) {
        bf16x8 a[2];
        a[0] = *reinterpret_cast<const bf16x8*>(a0p + k0);
        a[1] = *reinterpret_cast<const bf16x8*>(a1p + k0);
        if (BN) {
            int ch0 = k0 + khi * 8;
            f32x4 s0 = *reinterpret_cast<const f32x4*>(kp + ch0);
            f32x4 s1 = *reinterpret_cast<const f32x4*>(kp + ch0 + 4);
            f32x4 t0 = *reinterpret_cast<const f32x4*>(kp + 256 + ch0);
            f32x4 t1 = *reinterpret_cast<const f32x4*>(kp + 256 + ch0 + 4);
#pragma unroll
            for (int m = 0; m < 2; ++m) {
                u16x8 raw;
                __builtin_memcpy(&raw, &a[m], 16);
                u16x8 ov;
#pragma unroll
                for (int j = 0; j < 4; ++j) {
                    ov[j]     = f2bf(fmaxf(fmaf(bf2f(raw[j]),     s0[j], t0[j]), 0.f));
                    ov[4 + j] = f2bf(fmaxf(fmaf(bf2f(raw[4 + j]), s1[j], t1[j]), 0.f));
                }
                __builtin_memcpy(&a[m], &ov, 16);
            }
        }
        bf16x8 b[3];
#pragma unroll
        for (int nt = 0; nt < 3; ++nt)
            b[nt] = *reinterpret_cast<const bf16x8*>(Wcb + (size_t)(nt * 16 + l16) * 1280 + bOff + k0 + khi * 8);
#pragma unroll
        for (int m = 0; m < 2; ++m)
#pragma unroll
            for (int nt = 0; nt < 3; ++nt)
                acc[m][nt] = __builtin_amdgcn_mfma_f32_16x16x32_bf16(a[m], b[nt], acc[m][nt], 0, 0, 0);
    }
}

__global__ __launch_bounds__(256) void outproj_mfma_kernel(
    const unsigned short* __restrict__ x_bf,
    const unsigned short* __restrict__ F0, const float* __restrict__ kp0,
    const unsigned short* __restrict__ F1, const float* __restrict__ kp1,
    const unsigned short* __restrict__ F2, const float* __restrict__ kp2,
    const unsigned short* __restrict__ Wcb, const float* __restrict__ bc,
    float* __restrict__ out, int N)
{
    const int lane = threadIdx.x & 63;
    const int wave = threadIdx.x >> 6;
    const int l16 = lane & 15;
    const int khi = lane >> 4;
    const long long bm = (long long)blockIdx.x * 128 + wave * 32;

    long long r0 = bm + l16;        if (r0 >= N) r0 = 0;
    long long r1 = bm + 16 + l16;   if (r1 >= N) r1 = 0;

    f32x4 acc[2][3];
#pragma unroll
    for (int m = 0; m < 2; ++m)
#pragma unroll
        for (int nt = 0; nt < 3; ++nt) acc[m][nt] = (f32x4){0.f, 0.f, 0.f, 0.f};

    outproj_seg<512, false>(x_bf, nullptr, Wcb, 0,    r0, r1, l16, khi, acc);
    outproj_seg<256, true >(F0,   kp0,     Wcb, 512,  r0, r1, l16, khi, acc);
    outproj_seg<256, true >(F1,   kp1,     Wcb, 768,  r0, r1, l16, khi, acc);
    outproj_seg<256, true >(F2,   kp2,     Wcb, 1024, r0, r1, l16, khi, acc);

#pragma unroll
    for (int m = 0; m < 2; ++m)
#pragma unroll
        for (int nt = 0; nt < 3; ++nt)
#pragma unroll
            for (int r = 0; r < 4; ++r) {
                long long grow = bm + m * 16 + khi * 4 + r;
                int gcol = nt * 16 + l16;
                if (grow < N && gcol < 40)
                    out[grow * 40 + gcol] = acc[m][nt][r] + bc[gcol];
            }
}

// ---------------- host-side orchestration ----------------
extern "C" void kernel_launch(void* const* d_in, const int* in_sizes, int n_in,
                              void* d_out, int out_size, void* d_ws, size_t ws_size,
                              hipStream_t stream)
{
    const float* x      = (const float*)d_in[0];
    const int*   esrc   = (const int*)d_in[1];
    const int*   edst   = (const int*)d_in[2];
    const float* ew     = (const float*)d_in[3];
    const float* W_in   = (const float*)d_in[4];
    const float* SW_in  = (const float*)d_in[5];
    const float* b_in   = (const float*)d_in[6];
    const float* g_in   = (const float*)d_in[7];
    const float* be_in  = (const float*)d_in[8];
    const float* W_h    = (const float*)d_in[9];
    const float* SW_h   = (const float*)d_in[10];
    const float* b_h    = (const float*)d_in[11];
    const float* g_h    = (const float*)d_in[12];
    const float* be_h   = (const float*)d_in[13];
    const float* Wc     = (const float*)d_in[14];
    const float* bc     = (const float*)d_in[15];
    float* out = (float*)d_out;

    const int N = in_sizes[0] / 500;      // 100000
    const int n_edges = in_sizes[1];      // 3200000
    const int nb = (N + 255) / 256;

    // ---- workspace layout ----
    char* p = (char*)d_ws;
    unsigned short* x_bf = (unsigned short*)p; p += (size_t)N * 512 * 2;
    unsigned short* Xa   = (unsigned short*)p; p += (size_t)N * 512 * 2;   // F2 aliases
    unsigned short* Ha   = (unsigned short*)p; p += (size_t)N * 256 * 2;
    unsigned short* Ha2  = (unsigned short*)p; p += (size_t)N * 256 * 2;
    unsigned short* G1   = (unsigned short*)p; p += (size_t)N * 256 * 2;   // H2 aliases
    unsigned short* G2   = (unsigned short*)p; p += (size_t)N * 256 * 2;
    unsigned short* F0   = (unsigned short*)p; p += (size_t)N * 256 * 2;
    unsigned short* F1   = (unsigned short*)p; p += (size_t)N * 256 * 2;
    unsigned short* H2   = G1;
    unsigned short* F2   = Xa;
    unsigned char* x_f8  = (unsigned char*)p; p += (size_t)N * 512;
    unsigned char* G1_f8 = (unsigned char*)p; p += (size_t)N * 256;
    unsigned char* G2_f8 = (unsigned char*)p; p += (size_t)N * 256;
    unsigned char* H2_f8 = G1_f8;   // alias: G1_f8 dead after dual spmm
    unsigned short* Wf_in = (unsigned short*)p; p += (size_t)3 * 256 * 1024 * 2;
    unsigned short* Wf_h  = (unsigned short*)p; p += (size_t)3 * 256 * 512 * 2;
    unsigned short* Wcb   = (unsigned short*)p; p += (size_t)48 * 1280 * 2;
    float* stats = (float*)p; p += (size_t)6 * 1024 * 4;
    int* cnt     = (int*)p; p += (size_t)N * 4;
    int* excl    = (int*)p; p += (size_t)N * 4;
    int* blocksums = (int*)p; p += 2048 * 4;
    int* row_ptr = (int*)p; p += (size_t)(N + 1) * 4 + 4;
    int* heads   = (int*)p; p += (size_t)N * 4;
    unsigned int* meta = (unsigned int*)p;

    // ---- preprocessing ----
    hipMemsetAsync(stats, 0, (size_t)6 * 1024 * sizeof(float) + (size_t)N * sizeof(int), stream);
    hipLaunchKernelGGL(transpose_fused_kernel, dim3(2048), dim3(256), 0, stream,
                       W_in, SW_in, Wf_in, 500, 512, 3);
    hipLaunchKernelGGL(transpose_fused_kernel, dim3(1024), dim3(256), 0, stream,
                       W_h, SW_h, Wf_h, 256, 256, 3);
    hipLaunchKernelGGL(transpose_wc_kernel, dim3(240), dim3(256), 0, stream, Wc, Wcb);

    hipLaunchKernelGGL(hist_kernel, dim3(4096), dim3(256), 0, stream, edst, cnt, n_edges);
    hipLaunchKernelGGL(scan1_kernel, dim3(nb), dim3(256), 0, stream, cnt, excl, blocksums, N);
    hipLaunchKernelGGL(scan2_kernel, dim3(1), dim3(512), 0, stream, blocksums, nb);
    hipLaunchKernelGGL(scan3_kernel, dim3(nb), dim3(256), 0, stream,
                       excl, blocksums, row_ptr, heads, N, n_edges);
    hipLaunchKernelGGL(scatter_kernel, dim3(4096), dim3(256), 0, stream,
                       esrc, edst, ew, heads, meta, n_edges);

    hipLaunchKernelGGL(cvtx_kernel, dim3(4096), dim3(256), 0, stream, x, x_bf, x_f8, N);

    hipLaunchKernelGGL(spmm512_kernel, dim3((N + 3) / 4), dim3(512), 0, stream,
                       row_ptr, meta, x_f8, Xa, N);

    dim3 blk(256);
    dim3 ggrid2((N + 127) / 128, 2);
    dim3 ogrid((N + 127) / 128);
    dim3 sgrid((N + 3) / 4);

    // ---- three input-layer GEMMs ----
    hipLaunchKernelGGL((gemm_lds_kernel<512, 512, false>), ggrid2, blk, 0, stream,
                       Xa, x_bf, (const float*)nullptr, Wf_in, b_in,
                       F0, (unsigned char*)nullptr, stats + 0 * 1024, N);
    hipLaunchKernelGGL((gemm_lds_kernel<512, 512, false>), ggrid2, blk, 0, stream,
                       Xa, x_bf, (const float*)nullptr, Wf_in + (size_t)1 * 256 * 1024, b_in + 256,
                       G1, G1_f8, stats + 1 * 1024, N);
    hipLaunchKernelGGL((gemm_lds_kernel<512, 512, false>), ggrid2, blk, 0, stream,
                       Xa, x_bf, (const float*)nullptr, Wf_in + (size_t)2 * 256 * 1024, b_in + 512,
                       G2, G2_f8, stats + 2 * 1024, N);
    hipLaunchKernelGGL(bn_finalize3_kernel, dim3(3), dim3(256), 0, stream,
                       stats, g_in, be_in, N);

    float* kp0 = stats + 0 * 1024 + 512;
    float* kp1 = stats + 1 * 1024 + 512;
    float* kp2 = stats + 2 * 1024 + 512;
    float* st3 = stats + 3 * 1024;
    float* st4 = stats + 4 * 1024;
    float* st5 = stats + 5 * 1024;

    // ---- fused dual gather: Ha = A@bn(G1), Ha2 = A@bn(G2) ----
    hipLaunchKernelGGL(spmm256x2bn_kernel, sgrid, blk, 0, stream,
                       row_ptr, meta, G1_f8, kp1, G2_f8, kp2, Ha, Ha2, N);

    // ---- j = 1: gemm -> F1 ----
    hipLaunchKernelGGL((gemm_lds_kernel<256, 256, true>), ggrid2, blk, 0, stream,
                       Ha, G1, kp1, Wf_h, b_h, F1, (unsigned char*)nullptr, st3, N);
    hipLaunchKernelGGL(bn_finalize_kernel, dim3(1), dim3(256), 0, stream, st3, g_h, be_h, st3 + 512, N);

    // ---- j = 2: two hidden GCs ----
    hipLaunchKernelGGL((gemm_lds_kernel<256, 256, true>), ggrid2, blk, 0, stream,
                       Ha2, G2, kp2, Wf_h + (size_t)1 * 256 * 512, b_h + 256,
                       H2, H2_f8, st4, N);
    hipLaunchKernelGGL(bn_finalize_kernel, dim3(1), dim3(256), 0, stream, st4, g_h + 256, be_h + 256, st4 + 512, N);

    hipLaunchKernelGGL(spmm256bn_kernel, sgrid, blk, 0, stream, row_ptr, meta, H2_f8, st4 + 512, Ha, N);
    hipLaunchKernelGGL((gemm_lds_kernel<256, 256, true>), ggrid2, blk, 0, stream,
                       Ha, H2, st4 + 512, Wf_h + (size_t)2 * 256 * 512, b_h + 512,
                       F2, (unsigned char*)nullptr, st5, N);
    hipLaunchKernelGGL(bn_finalize_kernel, dim3(1), dim3(256), 0, stream, st5, g_h + 512, be_h + 512, st5 + 512, N);

    // ---- final outproj ----
    hipLaunchKernelGGL(outproj_mfma_kernel, ogrid, blk, 0, stream,
                       x_bf, F0, kp0, F1, st3 + 512, F2, st5 + 512,
                       Wcb, bc, out, N);
}